// Round 3
// baseline (3515.957 us; speedup 1.0000x reference)
//
#include <hip/hip_runtime.h>
#include <hip/hip_bf16.h>
#include <math.h>

#define NNODES 30000
#define NEDGES 480000
#define NG     64
#define DIN    20
#define DD     512
#define NH     4
#define CH     128
#define NHID   128
#define BN_EPS 1e-5f

// ---------------------------------------------------------------- CSR build
__global__ __launch_bounds__(256) void k_hist(const int* __restrict__ dst,
                                              int* __restrict__ cnt, int E) {
    for (int e = blockIdx.x * blockDim.x + threadIdx.x; e < E;
         e += gridDim.x * blockDim.x)
        atomicAdd(&cnt[dst[e]], 1);
}

__global__ __launch_bounds__(1024) void k_scan(const int* __restrict__ cnt,
                                               int* __restrict__ rowptr,
                                               int* __restrict__ cursor, int n) {
    __shared__ int sd[1024];
    __shared__ int sbase;
    int t = threadIdx.x;
    if (t == 0) sbase = 0;
    __syncthreads();
    for (int start = 0; start < n; start += 1024) {
        int i = start + t;
        int v = (i < n) ? cnt[i] : 0;
        sd[t] = v;
        __syncthreads();
        for (int off = 1; off < 1024; off <<= 1) {
            int x = (t >= off) ? sd[t - off] : 0;
            __syncthreads();
            sd[t] += x;
            __syncthreads();
        }
        int excl = sd[t] - v;
        if (i < n) { rowptr[i] = sbase + excl; cursor[i] = sbase + excl; }
        int tot = sd[1023];
        __syncthreads();
        if (t == 0) sbase += tot;
        __syncthreads();
    }
    if (t == 0) rowptr[n] = sbase;
}

__global__ __launch_bounds__(256) void k_scatter(const int* __restrict__ src,
                                                 const int* __restrict__ dst,
                                                 int* __restrict__ cursor,
                                                 int* __restrict__ col, int E) {
    for (int e = blockIdx.x * blockDim.x + threadIdx.x; e < E;
         e += gridDim.x * blockDim.x) {
        int d = dst[e];
        int off = atomicAdd(&cursor[d], 1);
        col[off] = src[e];
    }
}

// ------------------------------------------------------------- GIN1 agg (20)
__global__ __launch_bounds__(256) void k_gin1_agg(const float* __restrict__ x,
                                                  const int* __restrict__ rowptr,
                                                  const int* __restrict__ col,
                                                  float* __restrict__ out) {
    int wave = threadIdx.x >> 6;
    int lane = threadIdx.x & 63;
    int node = blockIdx.x * 4 + wave;
    if (node >= NNODES) return;
    int p0 = rowptr[node], p1 = rowptr[node + 1];
    float acc = 0.f;
    if (lane < DIN) acc = x[(size_t)node * DIN + lane];
    for (int j = p0; j < p1; ++j) {
        int s = col[j];
        if (lane < DIN) acc += x[(size_t)s * DIN + lane];
    }
    if (lane < DIN) out[(size_t)node * DIN + lane] = acc;
}

// --------------------------------------------------- GEMM [N,20]@[20,512]+relu
__global__ __launch_bounds__(256) void k_gemm20(const float* __restrict__ A,
                                                const float* __restrict__ W,
                                                const float* __restrict__ bias,
                                                float* __restrict__ C) {
    __shared__ float Ws[DIN][128];
    __shared__ float As[64][DIN + 1];
    int t = threadIdx.x;
    int row0 = blockIdx.x * 64;
    int col0 = blockIdx.y * 128;
    for (int i = t; i < DIN * 128; i += 256) {
        int k = i >> 7, c = i & 127;
        Ws[k][c] = W[k * DD + col0 + c];
    }
    for (int i = t; i < 64 * DIN; i += 256) {
        int r = i / DIN, k = i % DIN;
        int rr = row0 + r;
        if (rr >= NNODES) rr = NNODES - 1;
        As[r][k] = A[(size_t)rr * DIN + k];
    }
    __syncthreads();
    int c4 = (t & 31) * 4;
    int r0 = (t >> 5) * 8;
    float acc[8][4];
#pragma unroll
    for (int i = 0; i < 8; i++)
#pragma unroll
        for (int j = 0; j < 4; j++) acc[i][j] = 0.f;
    for (int k = 0; k < DIN; k++) {
        float4 b = *(const float4*)&Ws[k][c4];
#pragma unroll
        for (int i = 0; i < 8; i++) {
            float a = As[r0 + i][k];
            acc[i][0] += a * b.x; acc[i][1] += a * b.y;
            acc[i][2] += a * b.z; acc[i][3] += a * b.w;
        }
    }
    float4 bb = *(const float4*)&bias[col0 + c4];
#pragma unroll
    for (int i = 0; i < 8; i++) {
        int r = row0 + r0 + i;
        if (r < NNODES) {
            float4 o;
            o.x = fmaxf(acc[i][0] + bb.x, 0.f);
            o.y = fmaxf(acc[i][1] + bb.y, 0.f);
            o.z = fmaxf(acc[i][2] + bb.z, 0.f);
            o.w = fmaxf(acc[i][3] + bb.w, 0.f);
            *(float4*)&C[(size_t)r * DD + col0 + c4] = o;
        }
    }
}

// ----------------------------------------------- GEMM [M,512]@[512,512] (+bias)
template <bool RELU, bool HASBIAS>
__global__ __launch_bounds__(256) void k_gemm512(const float* __restrict__ A,
                                                 const float* __restrict__ W,
                                                 const float* __restrict__ bias,
                                                 float* __restrict__ C, int M) {
    __shared__ float As[32][68];
    __shared__ float Bs[32][68];
    int t = threadIdx.x;
    int row0 = blockIdx.x * 64;
    int col0 = blockIdx.y * 64;
    float acc[4][4] = {};
    int tm = (t >> 4) * 4;
    int tn = (t & 15) * 4;
    int lr = t >> 3;
    int lk = (t & 7) * 4;
    int kb = t >> 4;
    int cb = (t & 15) * 4;
    for (int k0 = 0; k0 < DD; k0 += 32) {
#pragma unroll
        for (int p = 0; p < 2; p++) {
            int r = lr + p * 32;
            int rr = row0 + r;
            if (rr >= M) rr = M - 1;
            float4 v = *(const float4*)&A[(size_t)rr * DD + k0 + lk];
            As[lk + 0][r] = v.x; As[lk + 1][r] = v.y;
            As[lk + 2][r] = v.z; As[lk + 3][r] = v.w;
        }
#pragma unroll
        for (int p = 0; p < 2; p++) {
            int k = kb + p * 16;
            float4 v = *(const float4*)&W[(size_t)(k0 + k) * DD + col0 + cb];
            *(float4*)&Bs[k][cb] = v;
        }
        __syncthreads();
#pragma unroll
        for (int k = 0; k < 32; k++) {
            float4 av = *(const float4*)&As[k][tm];
            float4 bv = *(const float4*)&Bs[k][tn];
            acc[0][0] += av.x * bv.x; acc[0][1] += av.x * bv.y;
            acc[0][2] += av.x * bv.z; acc[0][3] += av.x * bv.w;
            acc[1][0] += av.y * bv.x; acc[1][1] += av.y * bv.y;
            acc[1][2] += av.y * bv.z; acc[1][3] += av.y * bv.w;
            acc[2][0] += av.z * bv.x; acc[2][1] += av.z * bv.y;
            acc[2][2] += av.z * bv.z; acc[2][3] += av.z * bv.w;
            acc[3][0] += av.w * bv.x; acc[3][1] += av.w * bv.y;
            acc[3][2] += av.w * bv.z; acc[3][3] += av.w * bv.w;
        }
        __syncthreads();
    }
    float4 bb = make_float4(0.f, 0.f, 0.f, 0.f);
    if (HASBIAS) bb = *(const float4*)&bias[col0 + tn];
#pragma unroll
    for (int i = 0; i < 4; i++) {
        int r = row0 + tm + i;
        if (r < M) {
            float4 o;
            o.x = acc[i][0] + bb.x; o.y = acc[i][1] + bb.y;
            o.z = acc[i][2] + bb.z; o.w = acc[i][3] + bb.w;
            if (RELU) {
                o.x = fmaxf(o.x, 0.f); o.y = fmaxf(o.y, 0.f);
                o.z = fmaxf(o.z, 0.f); o.w = fmaxf(o.w, 0.f);
            }
            *(float4*)&C[(size_t)r * DD + col0 + tn] = o;
        }
    }
}

// ------------------------------------------------------------------ BatchNorm
__global__ __launch_bounds__(512) void k_bn_stats(const float* __restrict__ h,
                                                  float* __restrict__ gsum,
                                                  float* __restrict__ gsq, int M) {
    int c = threadIdx.x;
    float s = 0.f, q = 0.f;
    for (int r = blockIdx.x; r < M; r += gridDim.x) {
        float v = h[(size_t)r * DD + c];
        s += v; q += v * v;
    }
    atomicAdd(&gsum[c], s);
    atomicAdd(&gsq[c], q);
}

__global__ __launch_bounds__(512) void k_bn_fin(const float* __restrict__ gsum,
                                                const float* __restrict__ gsq,
                                                const float* __restrict__ g,
                                                const float* __restrict__ b,
                                                float* __restrict__ scale,
                                                float* __restrict__ shift, int M) {
    int c = threadIdx.x;
    float mean = gsum[c] / (float)M;
    float var = gsq[c] / (float)M - mean * mean;
    float rs = rsqrtf(var + BN_EPS);
    float sc = g[c] * rs;
    scale[c] = sc;
    shift[c] = b[c] - mean * sc;
}

__global__ __launch_bounds__(256) void k_bn_apply(float* __restrict__ h,
                                                  const float* __restrict__ scale,
                                                  const float* __restrict__ shift,
                                                  int M) {
    int total = M * (DD / 4);
    for (int i = blockIdx.x * blockDim.x + threadIdx.x; i < total;
         i += gridDim.x * blockDim.x) {
        float4 v = ((float4*)h)[i];
        int c = (i & 127) * 4;
        v.x = fmaxf(v.x * scale[c + 0] + shift[c + 0], 0.f);
        v.y = fmaxf(v.y * scale[c + 1] + shift[c + 1], 0.f);
        v.z = fmaxf(v.z * scale[c + 2] + shift[c + 2], 0.f);
        v.w = fmaxf(v.w * scale[c + 3] + shift[c + 3], 0.f);
        ((float4*)h)[i] = v;
    }
}

// ------------------------------------------------------- D=512 neighborhood sum
__global__ __launch_bounds__(128) void k_agg512(const float* __restrict__ h,
                                                const int* __restrict__ rowptr,
                                                const int* __restrict__ col,
                                                float* __restrict__ out) {
    int node = blockIdx.x;
    int t = threadIdx.x;
    const float4* h4 = (const float4*)h;
    float4 acc = h4[(size_t)node * 128 + t];
    int p0 = rowptr[node], p1 = rowptr[node + 1];
    for (int j = p0; j < p1; ++j) {
        int s = col[j];
        float4 v = h4[(size_t)s * 128 + t];
        acc.x += v.x; acc.y += v.y; acc.z += v.z; acc.w += v.w;
    }
    ((float4*)out)[(size_t)node * 128 + t] = acc;
}

// ------------------------------------------------------------- GAT coefficients
__global__ __launch_bounds__(256) void k_attn_coef(const float* __restrict__ hh,
                                                   const float* __restrict__ as_,
                                                   const float* __restrict__ ad_,
                                                   float* __restrict__ a_s,
                                                   float* __restrict__ a_d) {
    int node = blockIdx.x;
    int h = threadIdx.x >> 6;
    int lane = threadIdx.x & 63;
    const float* row = hh + (size_t)node * DD + h * CH;
    float v0 = row[lane], v1 = row[lane + 64];
    float ps = v0 * as_[h * CH + lane] + v1 * as_[h * CH + lane + 64];
    float pd = v0 * ad_[h * CH + lane] + v1 * ad_[h * CH + lane + 64];
    for (int off = 32; off; off >>= 1) {
        ps += __shfl_down(ps, off);
        pd += __shfl_down(pd, off);
    }
    if (lane == 0) {
        a_s[node * NH + h] = ps;
        a_d[node * NH + h] = pd;
    }
}

// --------------------------------------------- GAT aggregate + bias + add-pool
__global__ __launch_bounds__(128) void k_gat_pool(const float* __restrict__ hh,
                                                  const float* __restrict__ a_s,
                                                  const float* __restrict__ a_d,
                                                  const float* __restrict__ bias,
                                                  const int* __restrict__ rowptr,
                                                  const int* __restrict__ col,
                                                  const int* __restrict__ batch,
                                                  float* __restrict__ pool) {
    int node = blockIdx.x;
    int t = threadIdx.x;
    int head = t >> 5;
    const float4* hh4 = (const float4*)hh;
    float adi = a_d[node * NH + head];
    // self loop
    float e = a_s[node * NH + head] + adi;
    e = (e > 0.f) ? e : 0.2f * e;
    float w = expf(e);
    float4 v = hh4[(size_t)node * 128 + t];
    float4 num;
    num.x = w * v.x; num.y = w * v.y; num.z = w * v.z; num.w = w * v.w;
    float den = w;
    int p0 = rowptr[node], p1 = rowptr[node + 1];
    for (int j = p0; j < p1; ++j) {
        int s = col[j];
        float e2 = a_s[s * NH + head] + adi;
        e2 = (e2 > 0.f) ? e2 : 0.2f * e2;
        float w2 = expf(e2);
        float4 u = hh4[(size_t)s * 128 + t];
        num.x += w2 * u.x; num.y += w2 * u.y;
        num.z += w2 * u.z; num.w += w2 * u.w;
        den += w2;
    }
    float inv = 1.f / den;
    int c4 = t * 4;
    int g = batch[node];
    atomicAdd(&pool[g * DD + c4 + 0], num.x * inv + bias[c4 + 0]);
    atomicAdd(&pool[g * DD + c4 + 1], num.y * inv + bias[c4 + 1]);
    atomicAdd(&pool[g * DD + c4 + 2], num.z * inv + bias[c4 + 2]);
    atomicAdd(&pool[g * DD + c4 + 3], num.w * inv + bias[c4 + 3]);
}

// ------------------------------------------------------------------- fc head
__global__ __launch_bounds__(256) void k_fc1(const float* __restrict__ gin,
                                             const float* __restrict__ W,
                                             const float* __restrict__ bias,
                                             float* __restrict__ out) {
    __shared__ float row[DD];
    int g = blockIdx.x;
    int t = threadIdx.x;
    row[t] = gin[g * DD + t];
    row[t + 256] = gin[g * DD + t + 256];
    __syncthreads();
    for (int cc = 0; cc < 2; ++cc) {
        int c = t + cc * 256;
        float acc = 0.f;
        for (int k = 0; k < DD; k++) acc += row[k] * W[k * DD + c];
        out[g * DD + c] = acc + bias[c];
    }
}

__global__ __launch_bounds__(512) void k_bn64(float* __restrict__ h,
                                              const float* __restrict__ g_,
                                              const float* __restrict__ b_) {
    int c = threadIdx.x;
    float s = 0.f, q = 0.f;
    for (int r = 0; r < NG; r++) {
        float v = h[r * DD + c];
        s += v; q += v * v;
    }
    float mean = s / (float)NG;
    float var = q / (float)NG - mean * mean;
    float rs = rsqrtf(var + BN_EPS);
    float sc = g_[c] * rs, sh = b_[c] - mean * sc;
    for (int r = 0; r < NG; r++) {
        float v = h[r * DD + c];
        h[r * DD + c] = fmaxf(v * sc + sh, 0.f);
    }
}

__global__ __launch_bounds__(128) void k_fc2(const float* __restrict__ h,
                                             const float* __restrict__ W,
                                             const float* __restrict__ bias,
                                             float* __restrict__ out) {
    __shared__ float row[DD];
    int g = blockIdx.x;
    int t = threadIdx.x;
    for (int i = t; i < DD; i += 128) row[i] = h[g * DD + i];
    __syncthreads();
    float acc = 0.f;
    for (int k = 0; k < DD; k++) acc += row[k] * W[k * NHID + t];
    out[g * NHID + t] = acc + bias[t];
}

// ------------------------------------------------------------------ regressor
__global__ __launch_bounds__(128) void k_reg(const float* __restrict__ gw,
                                             const float* __restrict__ gm,
                                             const float* __restrict__ W1,
                                             const float* __restrict__ b1,
                                             const float* __restrict__ W2,
                                             const float* __restrict__ b2,
                                             float* __restrict__ out) {
    __shared__ float x[256];
    __shared__ float red[128];
    int g = blockIdx.x;
    int t = threadIdx.x;
    x[t] = gw[g * NHID + t];
    x[t + 128] = gm[g * NHID + t];
    __syncthreads();
    float acc = b1[t];
    for (int k = 0; k < 256; k++) acc += x[k] * W1[k * NHID + t];
    acc = fmaxf(acc, 0.f);
    red[t] = acc * W2[t];
    __syncthreads();
    for (int off = 64; off; off >>= 1) {
        if (t < off) red[t] += red[t + off];
        __syncthreads();
    }
    if (t == 0) out[g] = red[0] + b2[0];
}

// ==================================================================== launch
extern "C" void kernel_launch(void* const* d_in, const int* in_sizes, int n_in,
                              void* d_out, int out_size, void* d_ws, size_t ws_size,
                              hipStream_t stream) {
    const float* wl_x = (const float*)d_in[0];
    const float* mt_x = (const float*)d_in[1];
    const int* wl_ei = (const int*)d_in[2];
    const int* mt_ei = (const int*)d_in[3];
    const int* wl_batch = (const int*)d_in[4];
    const int* mt_batch = (const int*)d_in[5];
    const float* gin1_W1 = (const float*)d_in[6];
    const float* gin1_b1 = (const float*)d_in[7];
    const float* gin1_W2 = (const float*)d_in[8];
    const float* gin1_b2 = (const float*)d_in[9];
    const float* bn1_g = (const float*)d_in[10];
    const float* bn1_b = (const float*)d_in[11];
    const float* gin2_W1 = (const float*)d_in[12];
    const float* gin2_b1 = (const float*)d_in[13];
    const float* gin2_W2 = (const float*)d_in[14];
    const float* gin2_b2 = (const float*)d_in[15];
    const float* bn2_g = (const float*)d_in[16];
    const float* bn2_b = (const float*)d_in[17];
    const float* gat_W = (const float*)d_in[18];
    const float* gat_as = (const float*)d_in[19];
    const float* gat_ad = (const float*)d_in[20];
    const float* gat_bias = (const float*)d_in[21];
    const float* fc_W1 = (const float*)d_in[22];
    const float* fc_b1 = (const float*)d_in[23];
    const float* fc_bn_g = (const float*)d_in[24];
    const float* fc_bn_b = (const float*)d_in[25];
    const float* fc_W2 = (const float*)d_in[26];
    const float* fc_b2 = (const float*)d_in[27];
    const float* reg_W1 = (const float*)d_in[28];
    const float* reg_b1 = (const float*)d_in[29];
    const float* reg_W2 = (const float*)d_in[30];
    const float* reg_b2 = (const float*)d_in[31];
    float* out = (float*)d_out;

    char* ws = (char*)d_ws;
    size_t o = 0;
    auto alloc = [&](size_t bytes) {
        size_t r = o;
        o = (o + bytes + 255) & ~(size_t)255;
        return r;
    };
    const size_t SZ_BUF = (size_t)NNODES * DD * 4;
    float* buf1 = (float*)(ws + alloc(SZ_BUF));
    float* buf2 = (float*)(ws + alloc(SZ_BUF));
    float* bufA = (float*)(ws + alloc((size_t)NNODES * DIN * 4));
    int* cnt = (int*)(ws + alloc((size_t)NNODES * 4));
    int* rowptr = (int*)(ws + alloc((size_t)(NNODES + 1) * 4));
    int* cursor = (int*)(ws + alloc((size_t)NNODES * 4));
    int* colidx = (int*)(ws + alloc((size_t)NEDGES * 4));
    float* a_s = (float*)(ws + alloc((size_t)NNODES * NH * 4));
    float* a_d = (float*)(ws + alloc((size_t)NNODES * NH * 4));
    float* bnsums = (float*)(ws + alloc(2 * DD * 4));   // gsum | gsq
    float* bnsc = (float*)(ws + alloc(2 * DD * 4));     // scale | shift
    float* pool = (float*)(ws + alloc((size_t)NG * DD * 4));
    float* fch = (float*)(ws + alloc((size_t)NG * DD * 4));
    float* gout = (float*)(ws + alloc((size_t)2 * NG * NHID * 4));
    (void)ws_size; (void)in_sizes; (void)n_in; (void)out_size;

    dim3 g512((NNODES + 63) / 64, 8);
    dim3 g20((NNODES + 63) / 64, 4);

    auto bnpass = [&](float* h, const float* g, const float* b) {
        hipMemsetAsync(bnsums, 0, 2 * DD * 4, stream);
        k_bn_stats<<<256, 512, 0, stream>>>(h, bnsums, bnsums + DD, NNODES);
        k_bn_fin<<<1, 512, 0, stream>>>(bnsums, bnsums + DD, g, b, bnsc, bnsc + DD,
                                        NNODES);
        k_bn_apply<<<2048, 256, 0, stream>>>(h, bnsc, bnsc + DD, NNODES);
    };

    for (int br = 0; br < 2; ++br) {
        const float* x = br ? mt_x : wl_x;
        const int* ei = br ? mt_ei : wl_ei;
        const int* batch = br ? mt_batch : wl_batch;
        const int* srcp = ei;
        const int* dstp = ei + NEDGES;

        // CSR by destination
        hipMemsetAsync(cnt, 0, (size_t)NNODES * 4, stream);
        k_hist<<<512, 256, 0, stream>>>(dstp, cnt, NEDGES);
        k_scan<<<1, 1024, 0, stream>>>(cnt, rowptr, cursor, NNODES);
        k_scatter<<<512, 256, 0, stream>>>(srcp, dstp, cursor, colidx, NEDGES);

        // GIN1
        k_gin1_agg<<<7500, 256, 0, stream>>>(x, rowptr, colidx, bufA);
        k_gemm20<<<g20, 256, 0, stream>>>(bufA, gin1_W1, gin1_b1, buf1);
        k_gemm512<false, true><<<g512, 256, 0, stream>>>(buf1, gin1_W2, gin1_b2,
                                                         buf2, NNODES);
        bnpass(buf2, bn1_g, bn1_b);

        // GIN2
        k_agg512<<<NNODES, 128, 0, stream>>>(buf2, rowptr, colidx, buf1);
        k_gemm512<true, true><<<g512, 256, 0, stream>>>(buf1, gin2_W1, gin2_b1,
                                                        buf2, NNODES);
        k_gemm512<false, true><<<g512, 256, 0, stream>>>(buf2, gin2_W2, gin2_b2,
                                                         buf1, NNODES);
        bnpass(buf1, bn2_g, bn2_b);

        // GAT
        k_gemm512<false, false><<<g512, 256, 0, stream>>>(buf1, gat_W, nullptr,
                                                          buf2, NNODES);
        k_attn_coef<<<NNODES, 256, 0, stream>>>(buf2, gat_as, gat_ad, a_s, a_d);
        hipMemsetAsync(pool, 0, (size_t)NG * DD * 4, stream);
        k_gat_pool<<<NNODES, 128, 0, stream>>>(buf2, a_s, a_d, gat_bias, rowptr,
                                               colidx, batch, pool);

        // fc head
        k_fc1<<<NG, 256, 0, stream>>>(pool, fc_W1, fc_b1, fch);
        k_bn64<<<1, 512, 0, stream>>>(fch, fc_bn_g, fc_bn_b);
        k_fc2<<<NG, 128, 0, stream>>>(fch, fc_W2, fc_b2, gout + br * NG * NHID);
    }

    k_reg<<<NG, 128, 0, stream>>>(gout, gout + NG * NHID, reg_W1, reg_b1, reg_W2,
                                  reg_b2, out);
}

// Round 4
// 2839.780 us; speedup vs baseline: 1.2381x; 1.2381x over previous
//
#include <hip/hip_runtime.h>
#include <hip/hip_bf16.h>
#include <math.h>

#define NNODES 30000
#define NEDGES 480000
#define NG     64
#define DIN    20
#define DD     512
#define NH     4
#define CH     128
#define NHID   128
#define BN_EPS 1e-5f

typedef __attribute__((ext_vector_type(8))) short bf16x8;
typedef __attribute__((ext_vector_type(4))) float f32x4;

__device__ inline unsigned short f2b(float f) {
    __hip_bfloat16 h = __float2bfloat16(f);
    return *(unsigned short*)&h;
}
__device__ inline float b2f(unsigned short u) {
    return __uint_as_float(((unsigned)u) << 16);
}

// ---------------------------------------------------------------- CSR build
__global__ __launch_bounds__(256) void k_hist(const int* __restrict__ dst,
                                              int* __restrict__ cnt, int E) {
    for (int e = blockIdx.x * blockDim.x + threadIdx.x; e < E;
         e += gridDim.x * blockDim.x)
        atomicAdd(&cnt[dst[e]], 1);
}

__global__ __launch_bounds__(512) void k_scan2(const int* __restrict__ cnt,
                                               int* __restrict__ rowptr,
                                               int* __restrict__ cursor, int n) {
    __shared__ int sd[512];
    int t = threadIdx.x;
    int per = (n + 511) / 512;
    int lo = t * per, hi = lo + per;
    if (hi > n) hi = n;
    int s = 0;
    for (int i = lo; i < hi; ++i) s += cnt[i];
    sd[t] = s;
    __syncthreads();
    // Hillis-Steele inclusive scan
    for (int off = 1; off < 512; off <<= 1) {
        int v = (t >= off) ? sd[t - off] : 0;
        __syncthreads();
        sd[t] += v;
        __syncthreads();
    }
    int run = sd[t] - s;  // exclusive prefix
    for (int i = lo; i < hi; ++i) {
        rowptr[i] = run;
        cursor[i] = run;
        run += cnt[i];
    }
    if (t == 511) rowptr[n] = sd[511];
}

__global__ __launch_bounds__(256) void k_scatter(const int* __restrict__ src,
                                                 const int* __restrict__ dst,
                                                 int* __restrict__ cursor,
                                                 int* __restrict__ col, int E) {
    for (int e = blockIdx.x * blockDim.x + threadIdx.x; e < E;
         e += gridDim.x * blockDim.x) {
        int d = dst[e];
        int off = atomicAdd(&cursor[d], 1);
        col[off] = src[e];
    }
}

// ---------------------------------------------------------- weight conv+transp
__global__ __launch_bounds__(256) void k_wconv(const float* __restrict__ W,
                                               unsigned short* __restrict__ Wt) {
    int n = blockIdx.x;
    for (int k = threadIdx.x; k < DD; k += 256)
        Wt[n * DD + k] = f2b(W[k * DD + n]);
}

// ------------------------------------------------------------- GIN1 agg (20)
__global__ __launch_bounds__(256) void k_gin1_agg(const float* __restrict__ x,
                                                  const int* __restrict__ rowptr,
                                                  const int* __restrict__ col,
                                                  float* __restrict__ out) {
    int wave = threadIdx.x >> 6;
    int lane = threadIdx.x & 63;
    int node = blockIdx.x * 4 + wave;
    if (node >= NNODES) return;
    int p0 = rowptr[node], p1 = rowptr[node + 1];
    float acc = 0.f;
    if (lane < DIN) acc = x[(size_t)node * DIN + lane];
    for (int j = p0; j < p1; ++j) {
        int s = col[j];
        if (lane < DIN) acc += x[(size_t)s * DIN + lane];
    }
    if (lane < DIN) out[(size_t)node * DIN + lane] = acc;
}

// ------------------------------------- GEMM [N,20]@[20,512]+relu -> bf16 out
__global__ __launch_bounds__(256) void k_gemm20(const float* __restrict__ A,
                                                const float* __restrict__ W,
                                                const float* __restrict__ bias,
                                                unsigned short* __restrict__ C) {
    __shared__ float Ws[DIN][128];
    __shared__ float As[64][DIN + 1];
    int t = threadIdx.x;
    int row0 = blockIdx.x * 64;
    int col0 = blockIdx.y * 128;
    for (int i = t; i < DIN * 128; i += 256) {
        int k = i >> 7, c = i & 127;
        Ws[k][c] = W[k * DD + col0 + c];
    }
    for (int i = t; i < 64 * DIN; i += 256) {
        int r = i / DIN, k = i % DIN;
        int rr = row0 + r;
        if (rr >= NNODES) rr = NNODES - 1;
        As[r][k] = A[(size_t)rr * DIN + k];
    }
    __syncthreads();
    int c4 = (t & 31) * 4;
    int r0 = (t >> 5) * 8;
    float acc[8][4];
#pragma unroll
    for (int i = 0; i < 8; i++)
#pragma unroll
        for (int j = 0; j < 4; j++) acc[i][j] = 0.f;
    for (int k = 0; k < DIN; k++) {
        float4 b = *(const float4*)&Ws[k][c4];
#pragma unroll
        for (int i = 0; i < 8; i++) {
            float a = As[r0 + i][k];
            acc[i][0] += a * b.x; acc[i][1] += a * b.y;
            acc[i][2] += a * b.z; acc[i][3] += a * b.w;
        }
    }
    float4 bb = *(const float4*)&bias[col0 + c4];
#pragma unroll
    for (int i = 0; i < 8; i++) {
        int r = row0 + r0 + i;
        if (r < NNODES) {
            short4 o;
            o.x = (short)f2b(fmaxf(acc[i][0] + bb.x, 0.f));
            o.y = (short)f2b(fmaxf(acc[i][1] + bb.y, 0.f));
            o.z = (short)f2b(fmaxf(acc[i][2] + bb.z, 0.f));
            o.w = (short)f2b(fmaxf(acc[i][3] + bb.w, 0.f));
            *(short4*)&C[(size_t)r * DD + col0 + c4] = o;
        }
    }
}

// ------------------------------- MFMA GEMM [M,512](bf16) @ Wt[512,512](bf16^T)
// MODE: 0 = fp32 out (+bias)          (pre-BN)
//       1 = bf16 out (+bias, relu)    (mid-MLP)
//       2 = fp32 + bf16 out, no bias  (GAT)
template <int MODE>
__global__ __launch_bounds__(256) void k_gemm_mfma(
    const unsigned short* __restrict__ A, const unsigned short* __restrict__ Wt,
    const float* __restrict__ bias, float* __restrict__ Cf,
    unsigned short* __restrict__ Cb, int M) {
    __shared__ char smem[2 * 128 * 144];  // A tile | B tile, 144B padded rows
    char* AsB = smem;
    char* BsB = smem + 128 * 144;

    int t = threadIdx.x;
    int lane = t & 63;
    int w = t >> 6;
    int wm = (w >> 1) * 64, wn = (w & 1) * 64;
    int row0 = blockIdx.x * 128;
    int col0 = blockIdx.y * 128;

    int srow = t >> 3;   // 0..31
    int slot = t & 7;    // 0..7

    const char* Ab = (const char*)A;
    const char* Bb = (const char*)Wt;

    f32x4 acc[4][4];
#pragma unroll
    for (int i = 0; i < 4; i++)
#pragma unroll
        for (int j = 0; j < 4; j++) acc[i][j] = (f32x4){0.f, 0.f, 0.f, 0.f};

    int4 ra[4], rb[4];
    auto load_tiles = [&](int k0) {
#pragma unroll
        for (int p = 0; p < 4; p++) {
            int rA = row0 + srow + 32 * p;
            if (rA >= M) rA = M - 1;
            ra[p] = *(const int4*)(Ab + (size_t)rA * 1024 + k0 * 2 + slot * 16);
            int rB = col0 + srow + 32 * p;
            rb[p] = *(const int4*)(Bb + (size_t)rB * 1024 + k0 * 2 + slot * 16);
        }
    };

    load_tiles(0);
    const char* Aw = AsB + (wm + (lane & 15)) * 144 + (lane >> 4) * 16;
    const char* Bw = BsB + (wn + (lane & 15)) * 144 + (lane >> 4) * 16;

    for (int step = 0; step < 8; ++step) {
        __syncthreads();
#pragma unroll
        for (int p = 0; p < 4; p++) {
            *(int4*)(AsB + (srow + 32 * p) * 144 + slot * 16) = ra[p];
            *(int4*)(BsB + (srow + 32 * p) * 144 + slot * 16) = rb[p];
        }
        __syncthreads();
        if (step < 7) load_tiles((step + 1) * 64);
#pragma unroll
        for (int kx = 0; kx < 2; ++kx) {
            int kb = kx * 64;  // byte offset within row (k=0 / k=32)
            bf16x8 am[4], bn[4];
#pragma unroll
            for (int i = 0; i < 4; i++)
                am[i] = *(const bf16x8*)(Aw + i * 16 * 144 + kb);
#pragma unroll
            for (int j = 0; j < 4; j++)
                bn[j] = *(const bf16x8*)(Bw + j * 16 * 144 + kb);
#pragma unroll
            for (int i = 0; i < 4; i++)
#pragma unroll
                for (int j = 0; j < 4; j++)
                    acc[i][j] = __builtin_amdgcn_mfma_f32_16x16x32_bf16(
                        am[i], bn[j], acc[i][j], 0, 0, 0);
        }
    }

    // epilogue: C row = row0+wm+i*16+(lane>>4)*4+r ; col = col0+wn+j*16+(lane&15)
    int crow = row0 + wm + (lane >> 4) * 4;
    int ccol = col0 + wn + (lane & 15);
#pragma unroll
    for (int j = 0; j < 4; j++) {
        int colj = ccol + j * 16;
        float bv = (MODE == 2) ? 0.f : bias[colj];
#pragma unroll
        for (int i = 0; i < 4; i++) {
#pragma unroll
            for (int r = 0; r < 4; r++) {
                int row = crow + i * 16 + r;
                if (row < M) {
                    float v = acc[i][j][r] + bv;
                    if (MODE == 1) v = fmaxf(v, 0.f);
                    if (MODE == 0 || MODE == 2) Cf[(size_t)row * DD + colj] = v;
                    if (MODE == 1 || MODE == 2)
                        Cb[(size_t)row * DD + colj] = f2b(v);
                }
            }
        }
    }
}

// ------------------------------------------------------------------ BatchNorm
__global__ __launch_bounds__(512) void k_bn_stats(const float* __restrict__ h,
                                                  float* __restrict__ gsum,
                                                  float* __restrict__ gsq, int M) {
    int c = threadIdx.x;
    float s = 0.f, q = 0.f;
    for (int r = blockIdx.x; r < M; r += gridDim.x) {
        float v = h[(size_t)r * DD + c];
        s += v; q += v * v;
    }
    atomicAdd(&gsum[c], s);
    atomicAdd(&gsq[c], q);
}

__global__ __launch_bounds__(512) void k_bn_fin(const float* __restrict__ gsum,
                                                const float* __restrict__ gsq,
                                                const float* __restrict__ g,
                                                const float* __restrict__ b,
                                                float* __restrict__ scale,
                                                float* __restrict__ shift, int M) {
    int c = threadIdx.x;
    float mean = gsum[c] / (float)M;
    float var = gsq[c] / (float)M - mean * mean;
    float rs = rsqrtf(var + BN_EPS);
    float sc = g[c] * rs;
    scale[c] = sc;
    shift[c] = b[c] - mean * sc;
}

// BN apply + relu, fp32 in -> bf16 out
__global__ __launch_bounds__(256) void k_bn_apply_b(const float* __restrict__ h,
                                                    const float* __restrict__ scale,
                                                    const float* __restrict__ shift,
                                                    unsigned short* __restrict__ out,
                                                    int M) {
    int total = M * (DD / 4);
    for (int i = blockIdx.x * blockDim.x + threadIdx.x; i < total;
         i += gridDim.x * blockDim.x) {
        float4 v = ((const float4*)h)[i];
        int c = (i & 127) * 4;
        short4 o;
        o.x = (short)f2b(fmaxf(v.x * scale[c + 0] + shift[c + 0], 0.f));
        o.y = (short)f2b(fmaxf(v.y * scale[c + 1] + shift[c + 1], 0.f));
        o.z = (short)f2b(fmaxf(v.z * scale[c + 2] + shift[c + 2], 0.f));
        o.w = (short)f2b(fmaxf(v.w * scale[c + 3] + shift[c + 3], 0.f));
        ((short4*)out)[i] = o;
    }
}

// ------------------------------------------- D=512 neighborhood sum (bf16 io)
__global__ __launch_bounds__(256) void k_agg512b(const unsigned short* __restrict__ h,
                                                 const int* __restrict__ rowptr,
                                                 const int* __restrict__ col,
                                                 unsigned short* __restrict__ out) {
    int node = blockIdx.x * 4 + (threadIdx.x >> 6);
    int lane = threadIdx.x & 63;
    if (node >= NNODES) return;
    size_t base = (size_t)node * DD + lane * 8;
    float acc[8];
    {
        int4 v = *(const int4*)&h[base];
        const unsigned short* u = (const unsigned short*)&v;
#pragma unroll
        for (int i = 0; i < 8; i++) acc[i] = b2f(u[i]);
    }
    int p0 = rowptr[node], p1 = rowptr[node + 1];
    int j = p0;
    for (; j + 1 < p1; j += 2) {
        int s0 = col[j], s1 = col[j + 1];
        int4 v0 = *(const int4*)&h[(size_t)s0 * DD + lane * 8];
        int4 v1 = *(const int4*)&h[(size_t)s1 * DD + lane * 8];
        const unsigned short* u0 = (const unsigned short*)&v0;
        const unsigned short* u1 = (const unsigned short*)&v1;
#pragma unroll
        for (int i = 0; i < 8; i++) acc[i] += b2f(u0[i]) + b2f(u1[i]);
    }
    if (j < p1) {
        int4 v0 = *(const int4*)&h[(size_t)col[j] * DD + lane * 8];
        const unsigned short* u0 = (const unsigned short*)&v0;
#pragma unroll
        for (int i = 0; i < 8; i++) acc[i] += b2f(u0[i]);
    }
    int4 o;
    unsigned short* uo = (unsigned short*)&o;
#pragma unroll
    for (int i = 0; i < 8; i++) uo[i] = f2b(acc[i]);
    *(int4*)&out[base] = o;
}

// ------------------------------------------------------------- GAT coefficients
__global__ __launch_bounds__(256) void k_attn_coef(const float* __restrict__ hh,
                                                   const float* __restrict__ as_,
                                                   const float* __restrict__ ad_,
                                                   float* __restrict__ a_s,
                                                   float* __restrict__ a_d) {
    int node = blockIdx.x;
    int h = threadIdx.x >> 6;
    int lane = threadIdx.x & 63;
    const float* row = hh + (size_t)node * DD + h * CH;
    float v0 = row[lane], v1 = row[lane + 64];
    float ps = v0 * as_[h * CH + lane] + v1 * as_[h * CH + lane + 64];
    float pd = v0 * ad_[h * CH + lane] + v1 * ad_[h * CH + lane + 64];
    for (int off = 32; off; off >>= 1) {
        ps += __shfl_down(ps, off);
        pd += __shfl_down(pd, off);
    }
    if (lane == 0) {
        a_s[node * NH + h] = ps;
        a_d[node * NH + h] = pd;
    }
}

// --------------------------------------- per-(edge,head) softmax weight precomp
__global__ __launch_bounds__(256) void k_gat_w(const float* __restrict__ a_s,
                                               const float* __restrict__ a_d,
                                               const int* __restrict__ rowptr,
                                               const int* __restrict__ col,
                                               float* __restrict__ wbuf,
                                               float* __restrict__ wself,
                                               float* __restrict__ dinv) {
    int total = NNODES * NH;
    for (int i = blockIdx.x * blockDim.x + threadIdx.x; i < total;
         i += gridDim.x * blockDim.x) {
        int n = i >> 2, h = i & 3;
        float adi = a_d[i];
        float e = a_s[i] + adi;
        e = (e > 0.f) ? e : 0.2f * e;
        float ws = __expf(e);
        float den = ws;
        int p0 = rowptr[n], p1 = rowptr[n + 1];
        for (int j = p0; j < p1; ++j) {
            int s = col[j];
            float e2 = a_s[s * NH + h] + adi;
            e2 = (e2 > 0.f) ? e2 : 0.2f * e2;
            float w2 = __expf(e2);
            wbuf[j * NH + h] = w2;
            den += w2;
        }
        wself[i] = ws;
        dinv[i] = 1.f / den;
    }
}

// --------------------------- GAT gather (bf16) + bias + add-pool (fp32 atomics)
__global__ __launch_bounds__(256) void k_gat_gather(
    const unsigned short* __restrict__ hh, const float* __restrict__ wbuf,
    const float* __restrict__ wself, const float* __restrict__ dinv,
    const float* __restrict__ bias, const int* __restrict__ rowptr,
    const int* __restrict__ col, const int* __restrict__ batch,
    float* __restrict__ pool) {
    int node = blockIdx.x * 4 + (threadIdx.x >> 6);
    int lane = threadIdx.x & 63;
    if (node >= NNODES) return;
    int h = lane >> 4;
    int idx4 = node * NH + h;
    float acc[8];
    {
        float ws = wself[idx4];
        int4 v = *(const int4*)&hh[(size_t)node * DD + lane * 8];
        const unsigned short* u = (const unsigned short*)&v;
#pragma unroll
        for (int i = 0; i < 8; i++) acc[i] = ws * b2f(u[i]);
    }
    int p0 = rowptr[node], p1 = rowptr[node + 1];
    int j = p0;
    for (; j + 1 < p1; j += 2) {
        int s0 = col[j], s1 = col[j + 1];
        float w0 = wbuf[j * NH + h], w1 = wbuf[(j + 1) * NH + h];
        int4 v0 = *(const int4*)&hh[(size_t)s0 * DD + lane * 8];
        int4 v1 = *(const int4*)&hh[(size_t)s1 * DD + lane * 8];
        const unsigned short* u0 = (const unsigned short*)&v0;
        const unsigned short* u1 = (const unsigned short*)&v1;
#pragma unroll
        for (int i = 0; i < 8; i++) acc[i] += w0 * b2f(u0[i]) + w1 * b2f(u1[i]);
    }
    if (j < p1) {
        float w0 = wbuf[j * NH + h];
        int4 v0 = *(const int4*)&hh[(size_t)col[j] * DD + lane * 8];
        const unsigned short* u0 = (const unsigned short*)&v0;
#pragma unroll
        for (int i = 0; i < 8; i++) acc[i] += w0 * b2f(u0[i]);
    }
    float dv = dinv[idx4];
    int g = batch[node];
    int cbase = lane * 8;
#pragma unroll
    for (int i = 0; i < 8; i++)
        atomicAdd(&pool[g * DD + cbase + i], acc[i] * dv + bias[cbase + i]);
}

// ------------------------------------------------------------------- fc head
__global__ __launch_bounds__(256) void k_fc1(const float* __restrict__ gin,
                                             const float* __restrict__ W,
                                             const float* __restrict__ bias,
                                             float* __restrict__ out) {
    __shared__ float row[DD];
    int g = blockIdx.x;
    int t = threadIdx.x;
    row[t] = gin[g * DD + t];
    row[t + 256] = gin[g * DD + t + 256];
    __syncthreads();
    for (int cc = 0; cc < 2; ++cc) {
        int c = t + cc * 256;
        float acc = 0.f;
        for (int k = 0; k < DD; k++) acc += row[k] * W[k * DD + c];
        out[g * DD + c] = acc + bias[c];
    }
}

__global__ __launch_bounds__(512) void k_bn64(float* __restrict__ h,
                                              const float* __restrict__ g_,
                                              const float* __restrict__ b_) {
    int c = threadIdx.x;
    float s = 0.f, q = 0.f;
    for (int r = 0; r < NG; r++) {
        float v = h[r * DD + c];
        s += v; q += v * v;
    }
    float mean = s / (float)NG;
    float var = q / (float)NG - mean * mean;
    float rs = rsqrtf(var + BN_EPS);
    float sc = g_[c] * rs, sh = b_[c] - mean * sc;
    for (int r = 0; r < NG; r++) {
        float v = h[r * DD + c];
        h[r * DD + c] = fmaxf(v * sc + sh, 0.f);
    }
}

__global__ __launch_bounds__(128) void k_fc2(const float* __restrict__ h,
                                             const float* __restrict__ W,
                                             const float* __restrict__ bias,
                                             float* __restrict__ out) {
    __shared__ float row[DD];
    int g = blockIdx.x;
    int t = threadIdx.x;
    for (int i = t; i < DD; i += 128) row[i] = h[g * DD + i];
    __syncthreads();
    float acc = 0.f;
    for (int k = 0; k < DD; k++) acc += row[k] * W[k * NHID + t];
    out[g * NHID + t] = acc + bias[t];
}

// ------------------------------------------------------------------ regressor
__global__ __launch_bounds__(128) void k_reg(const float* __restrict__ gw,
                                             const float* __restrict__ gm,
                                             const float* __restrict__ W1,
                                             const float* __restrict__ b1,
                                             const float* __restrict__ W2,
                                             const float* __restrict__ b2,
                                             float* __restrict__ out) {
    __shared__ float x[256];
    __shared__ float red[128];
    int g = blockIdx.x;
    int t = threadIdx.x;
    x[t] = gw[g * NHID + t];
    x[t + 128] = gm[g * NHID + t];
    __syncthreads();
    float acc = b1[t];
    for (int k = 0; k < 256; k++) acc += x[k] * W1[k * NHID + t];
    acc = fmaxf(acc, 0.f);
    red[t] = acc * W2[t];
    __syncthreads();
    for (int off = 64; off; off >>= 1) {
        if (t < off) red[t] += red[t + off];
        __syncthreads();
    }
    if (t == 0) out[g] = red[0] + b2[0];
}

// ==================================================================== launch
extern "C" void kernel_launch(void* const* d_in, const int* in_sizes, int n_in,
                              void* d_out, int out_size, void* d_ws, size_t ws_size,
                              hipStream_t stream) {
    const float* wl_x = (const float*)d_in[0];
    const float* mt_x = (const float*)d_in[1];
    const int* wl_ei = (const int*)d_in[2];
    const int* mt_ei = (const int*)d_in[3];
    const int* wl_batch = (const int*)d_in[4];
    const int* mt_batch = (const int*)d_in[5];
    const float* gin1_W1 = (const float*)d_in[6];
    const float* gin1_b1 = (const float*)d_in[7];
    const float* gin1_W2 = (const float*)d_in[8];
    const float* gin1_b2 = (const float*)d_in[9];
    const float* bn1_g = (const float*)d_in[10];
    const float* bn1_b = (const float*)d_in[11];
    const float* gin2_W1 = (const float*)d_in[12];
    const float* gin2_b1 = (const float*)d_in[13];
    const float* gin2_W2 = (const float*)d_in[14];
    const float* gin2_b2 = (const float*)d_in[15];
    const float* bn2_g = (const float*)d_in[16];
    const float* bn2_b = (const float*)d_in[17];
    const float* gat_W = (const float*)d_in[18];
    const float* gat_as = (const float*)d_in[19];
    const float* gat_ad = (const float*)d_in[20];
    const float* gat_bias = (const float*)d_in[21];
    const float* fc_W1 = (const float*)d_in[22];
    const float* fc_b1 = (const float*)d_in[23];
    const float* fc_bn_g = (const float*)d_in[24];
    const float* fc_bn_b = (const float*)d_in[25];
    const float* fc_W2 = (const float*)d_in[26];
    const float* fc_b2 = (const float*)d_in[27];
    const float* reg_W1 = (const float*)d_in[28];
    const float* reg_b1 = (const float*)d_in[29];
    const float* reg_W2 = (const float*)d_in[30];
    const float* reg_b2 = (const float*)d_in[31];
    float* out = (float*)d_out;

    char* ws = (char*)d_ws;
    size_t o = 0;
    auto alloc = [&](size_t bytes) {
        size_t r = o;
        o = (o + bytes + 255) & ~(size_t)255;
        return r;
    };
    float* f1 = (float*)(ws + alloc((size_t)NNODES * DD * 4));           // 61.4MB
    unsigned short* hbA = (unsigned short*)(ws + alloc((size_t)NNODES * DD * 2));
    unsigned short* hb1 = (unsigned short*)(ws + alloc((size_t)NNODES * DD * 2));
    unsigned short* hb2 = (unsigned short*)(ws + alloc((size_t)NNODES * DD * 2));
    float* bufA = (float*)(ws + alloc((size_t)NNODES * DIN * 4));
    int* cnt = (int*)(ws + alloc((size_t)NNODES * 4));
    int* rowptr = (int*)(ws + alloc((size_t)(NNODES + 1) * 4));
    int* cursor = (int*)(ws + alloc((size_t)NNODES * 4));
    int* colidx = (int*)(ws + alloc((size_t)NEDGES * 4));
    float* a_s = (float*)(ws + alloc((size_t)NNODES * NH * 4));
    float* a_d = (float*)(ws + alloc((size_t)NNODES * NH * 4));
    float* wbuf = (float*)(ws + alloc((size_t)NEDGES * NH * 4));         // 7.7MB
    float* wself = (float*)(ws + alloc((size_t)NNODES * NH * 4));
    float* dinv = (float*)(ws + alloc((size_t)NNODES * NH * 4));
    float* bnsums = (float*)(ws + alloc(2 * DD * 4));
    float* bnsc = (float*)(ws + alloc(2 * DD * 4));
    float* pool = (float*)(ws + alloc((size_t)NG * DD * 4));
    float* fch = (float*)(ws + alloc((size_t)NG * DD * 4));
    float* gout = (float*)(ws + alloc((size_t)2 * NG * NHID * 4));
    unsigned short* Wt1 = (unsigned short*)(ws + alloc((size_t)DD * DD * 2));
    unsigned short* Wt2 = (unsigned short*)(ws + alloc((size_t)DD * DD * 2));
    unsigned short* Wt3 = (unsigned short*)(ws + alloc((size_t)DD * DD * 2));
    unsigned short* Wt4 = (unsigned short*)(ws + alloc((size_t)DD * DD * 2));
    (void)ws_size; (void)in_sizes; (void)n_in; (void)out_size;

    // convert+transpose the four 512x512 weights to bf16 (shared by branches)
    k_wconv<<<DD, 256, 0, stream>>>(gin1_W2, Wt1);
    k_wconv<<<DD, 256, 0, stream>>>(gin2_W1, Wt2);
    k_wconv<<<DD, 256, 0, stream>>>(gin2_W2, Wt3);
    k_wconv<<<DD, 256, 0, stream>>>(gat_W, Wt4);

    dim3 gmm((NNODES + 127) / 128, DD / 128);
    dim3 g20((NNODES + 63) / 64, 4);

    auto bnpass = [&](const float* src, const float* g, const float* b,
                      unsigned short* dst) {
        hipMemsetAsync(bnsums, 0, 2 * DD * 4, stream);
        k_bn_stats<<<256, 512, 0, stream>>>(src, bnsums, bnsums + DD, NNODES);
        k_bn_fin<<<1, 512, 0, stream>>>(bnsums, bnsums + DD, g, b, bnsc, bnsc + DD,
                                        NNODES);
        k_bn_apply_b<<<2048, 256, 0, stream>>>(src, bnsc, bnsc + DD, dst, NNODES);
    };

    for (int br = 0; br < 2; ++br) {
        const float* x = br ? mt_x : wl_x;
        const int* ei = br ? mt_ei : wl_ei;
        const int* batch = br ? mt_batch : wl_batch;
        const int* srcp = ei;
        const int* dstp = ei + NEDGES;

        // CSR by destination
        hipMemsetAsync(cnt, 0, (size_t)NNODES * 4, stream);
        k_hist<<<512, 256, 0, stream>>>(dstp, cnt, NEDGES);
        k_scan2<<<1, 512, 0, stream>>>(cnt, rowptr, cursor, NNODES);
        k_scatter<<<512, 256, 0, stream>>>(srcp, dstp, cursor, colidx, NEDGES);

        // GIN1
        k_gin1_agg<<<7500, 256, 0, stream>>>(x, rowptr, colidx, bufA);
        k_gemm20<<<g20, 256, 0, stream>>>(bufA, gin1_W1, gin1_b1, hbA);
        k_gemm_mfma<0><<<gmm, 256, 0, stream>>>(hbA, Wt1, gin1_b2, f1, nullptr,
                                                NNODES);
        bnpass(f1, bn1_g, bn1_b, hb1);

        // GIN2
        k_agg512b<<<7500, 256, 0, stream>>>(hb1, rowptr, colidx, hb2);
        k_gemm_mfma<1><<<gmm, 256, 0, stream>>>(hb2, Wt2, gin2_b1, nullptr, hbA,
                                                NNODES);
        k_gemm_mfma<0><<<gmm, 256, 0, stream>>>(hbA, Wt3, gin2_b2, f1, nullptr,
                                                NNODES);
        bnpass(f1, bn2_g, bn2_b, hb1);

        // GAT
        k_gemm_mfma<2><<<gmm, 256, 0, stream>>>(hb1, Wt4, nullptr, f1, hb2,
                                                NNODES);
        k_attn_coef<<<NNODES, 256, 0, stream>>>(f1, gat_as, gat_ad, a_s, a_d);
        k_gat_w<<<512, 256, 0, stream>>>(a_s, a_d, rowptr, colidx, wbuf, wself,
                                         dinv);
        hipMemsetAsync(pool, 0, (size_t)NG * DD * 4, stream);
        k_gat_gather<<<7500, 256, 0, stream>>>(hb2, wbuf, wself, dinv, gat_bias,
                                               rowptr, colidx, batch, pool);

        // fc head
        k_fc1<<<NG, 256, 0, stream>>>(pool, fc_W1, fc_b1, fch);
        k_bn64<<<1, 512, 0, stream>>>(fch, fc_bn_g, fc_bn_b);
        k_fc2<<<NG, 128, 0, stream>>>(fch, fc_W2, fc_b2, gout + br * NG * NHID);
    }

    k_reg<<<NG, 128, 0, stream>>>(gout, gout + NG * NHID, reg_W1, reg_b1, reg_W2,
                                  reg_b2, out);
}

// Round 5
// 2163.626 us; speedup vs baseline: 1.6250x; 1.3125x over previous
//
#include <hip/hip_runtime.h>
#include <hip/hip_bf16.h>
#include <math.h>

#define NNODES 30000
#define NEDGES 480000
#define NG     64
#define DIN    20
#define DD     512
#define NH     4
#define CH     128
#define NHID   128
#define BN_EPS 1e-5f

typedef __attribute__((ext_vector_type(8))) short bf16x8;
typedef __attribute__((ext_vector_type(4))) float f32x4;

__device__ inline unsigned short f2b(float f) {
    __hip_bfloat16 h = __float2bfloat16(f);
    return *(unsigned short*)&h;
}
__device__ inline float b2f(unsigned short u) {
    return __uint_as_float(((unsigned)u) << 16);
}

// ---------------------------------------------------------------- CSR build
__global__ __launch_bounds__(256) void k_hist(const int* __restrict__ dst,
                                              int* __restrict__ cnt, int E) {
    for (int e = blockIdx.x * blockDim.x + threadIdx.x; e < E;
         e += gridDim.x * blockDim.x)
        atomicAdd(&cnt[dst[e]], 1);
}

__global__ __launch_bounds__(512) void k_scan2(const int* __restrict__ cnt,
                                               int* __restrict__ rowptr,
                                               int* __restrict__ cursor, int n) {
    __shared__ int sd[512];
    int t = threadIdx.x;
    int per = (n + 511) / 512;
    int lo = t * per, hi = lo + per;
    if (hi > n) hi = n;
    int s = 0;
    for (int i = lo; i < hi; ++i) s += cnt[i];
    sd[t] = s;
    __syncthreads();
    for (int off = 1; off < 512; off <<= 1) {
        int v = (t >= off) ? sd[t - off] : 0;
        __syncthreads();
        sd[t] += v;
        __syncthreads();
    }
    int run = sd[t] - s;  // exclusive prefix
    for (int i = lo; i < hi; ++i) {
        rowptr[i] = run;
        cursor[i] = run;
        run += cnt[i];
    }
    if (t == 511) rowptr[n] = sd[511];
}

__global__ __launch_bounds__(256) void k_scatter(const int* __restrict__ src,
                                                 const int* __restrict__ dst,
                                                 int* __restrict__ cursor,
                                                 int* __restrict__ col, int E) {
    for (int e = blockIdx.x * blockDim.x + threadIdx.x; e < E;
         e += gridDim.x * blockDim.x) {
        int d = dst[e];
        int off = atomicAdd(&cursor[d], 1);
        col[off] = src[e];
    }
}

// ---------------------------------------------------------- weight conv+transp
__global__ __launch_bounds__(256) void k_wconv(const float* __restrict__ W,
                                               unsigned short* __restrict__ Wt) {
    int n = blockIdx.x;
    for (int k = threadIdx.x; k < DD; k += 256)
        Wt[n * DD + k] = f2b(W[k * DD + n]);
}

// ------------------------------------------------------------- GIN1 agg (20)
__global__ __launch_bounds__(256) void k_gin1_agg(const float* __restrict__ x,
                                                  const int* __restrict__ rowptr,
                                                  const int* __restrict__ col,
                                                  float* __restrict__ out) {
    int wave = threadIdx.x >> 6;
    int lane = threadIdx.x & 63;
    int node = blockIdx.x * 4 + wave;
    if (node >= NNODES) return;
    int p0 = rowptr[node], p1 = rowptr[node + 1];
    float acc = 0.f;
    if (lane < DIN) acc = x[(size_t)node * DIN + lane];
    for (int j = p0; j < p1; ++j) {
        int s = col[j];
        if (lane < DIN) acc += x[(size_t)s * DIN + lane];
    }
    if (lane < DIN) out[(size_t)node * DIN + lane] = acc;
}

// ------------------------------------- GEMM [N,20]@[20,512]+relu -> bf16 out
__global__ __launch_bounds__(256) void k_gemm20(const float* __restrict__ A,
                                                const float* __restrict__ W,
                                                const float* __restrict__ bias,
                                                unsigned short* __restrict__ C) {
    __shared__ float Ws[DIN][128];
    __shared__ float As[64][DIN + 1];
    int t = threadIdx.x;
    int row0 = blockIdx.x * 64;
    int col0 = blockIdx.y * 128;
    for (int i = t; i < DIN * 128; i += 256) {
        int k = i >> 7, c = i & 127;
        Ws[k][c] = W[k * DD + col0 + c];
    }
    for (int i = t; i < 64 * DIN; i += 256) {
        int r = i / DIN, k = i % DIN;
        int rr = row0 + r;
        if (rr >= NNODES) rr = NNODES - 1;
        As[r][k] = A[(size_t)rr * DIN + k];
    }
    __syncthreads();
    int c4 = (t & 31) * 4;
    int r0 = (t >> 5) * 8;
    float acc[8][4];
#pragma unroll
    for (int i = 0; i < 8; i++)
#pragma unroll
        for (int j = 0; j < 4; j++) acc[i][j] = 0.f;
    for (int k = 0; k < DIN; k++) {
        float4 b = *(const float4*)&Ws[k][c4];
#pragma unroll
        for (int i = 0; i < 8; i++) {
            float a = As[r0 + i][k];
            acc[i][0] += a * b.x; acc[i][1] += a * b.y;
            acc[i][2] += a * b.z; acc[i][3] += a * b.w;
        }
    }
    float4 bb = *(const float4*)&bias[col0 + c4];
#pragma unroll
    for (int i = 0; i < 8; i++) {
        int r = row0 + r0 + i;
        if (r < NNODES) {
            short4 o;
            o.x = (short)f2b(fmaxf(acc[i][0] + bb.x, 0.f));
            o.y = (short)f2b(fmaxf(acc[i][1] + bb.y, 0.f));
            o.z = (short)f2b(fmaxf(acc[i][2] + bb.z, 0.f));
            o.w = (short)f2b(fmaxf(acc[i][3] + bb.w, 0.f));
            *(short4*)&C[(size_t)r * DD + col0 + c4] = o;
        }
    }
}

// ------------------------------- MFMA GEMM [M,512](bf16) @ Wt[512,512](bf16^T)
// MODE: 0 = fp32 out (+bias)          (pre-BN)
//       1 = bf16 out (+bias, relu)    (mid-MLP)
//       2 = fp32 + bf16 out, no bias  (GAT)
template <int MODE>
__global__ __launch_bounds__(256) void k_gemm_mfma(
    const unsigned short* __restrict__ A, const unsigned short* __restrict__ Wt,
    const float* __restrict__ bias, float* __restrict__ Cf,
    unsigned short* __restrict__ Cb, int M) {
    __shared__ char smem[2 * 128 * 144];  // A tile | B tile, 144B padded rows
    char* AsB = smem;
    char* BsB = smem + 128 * 144;

    int t = threadIdx.x;
    int lane = t & 63;
    int w = t >> 6;
    int wm = (w >> 1) * 64, wn = (w & 1) * 64;
    int row0 = blockIdx.x * 128;
    int col0 = blockIdx.y * 128;

    int srow = t >> 3;   // 0..31
    int slot = t & 7;    // 0..7

    const char* Ab = (const char*)A;
    const char* Bb = (const char*)Wt;

    f32x4 acc[4][4];
#pragma unroll
    for (int i = 0; i < 4; i++)
#pragma unroll
        for (int j = 0; j < 4; j++) acc[i][j] = (f32x4){0.f, 0.f, 0.f, 0.f};

    int4 ra[4], rb[4];
    auto load_tiles = [&](int k0) {
#pragma unroll
        for (int p = 0; p < 4; p++) {
            int rA = row0 + srow + 32 * p;
            if (rA >= M) rA = M - 1;
            ra[p] = *(const int4*)(Ab + (size_t)rA * 1024 + k0 * 2 + slot * 16);
            int rB = col0 + srow + 32 * p;
            rb[p] = *(const int4*)(Bb + (size_t)rB * 1024 + k0 * 2 + slot * 16);
        }
    };

    load_tiles(0);
    const char* Aw = AsB + (wm + (lane & 15)) * 144 + (lane >> 4) * 16;
    const char* Bw = BsB + (wn + (lane & 15)) * 144 + (lane >> 4) * 16;

    for (int step = 0; step < 8; ++step) {
        __syncthreads();
#pragma unroll
        for (int p = 0; p < 4; p++) {
            *(int4*)(AsB + (srow + 32 * p) * 144 + slot * 16) = ra[p];
            *(int4*)(BsB + (srow + 32 * p) * 144 + slot * 16) = rb[p];
        }
        __syncthreads();
        if (step < 7) load_tiles((step + 1) * 64);
#pragma unroll
        for (int kx = 0; kx < 2; ++kx) {
            int kb = kx * 64;  // byte offset within row (k=0 / k=32)
            bf16x8 am[4], bn[4];
#pragma unroll
            for (int i = 0; i < 4; i++)
                am[i] = *(const bf16x8*)(Aw + i * 16 * 144 + kb);
#pragma unroll
            for (int j = 0; j < 4; j++)
                bn[j] = *(const bf16x8*)(Bw + j * 16 * 144 + kb);
#pragma unroll
            for (int i = 0; i < 4; i++)
#pragma unroll
                for (int j = 0; j < 4; j++)
                    acc[i][j] = __builtin_amdgcn_mfma_f32_16x16x32_bf16(
                        am[i], bn[j], acc[i][j], 0, 0, 0);
        }
    }

    int crow = row0 + wm + (lane >> 4) * 4;
    int ccol = col0 + wn + (lane & 15);
#pragma unroll
    for (int j = 0; j < 4; j++) {
        int colj = ccol + j * 16;
        float bv = (MODE == 2) ? 0.f : bias[colj];
#pragma unroll
        for (int i = 0; i < 4; i++) {
#pragma unroll
            for (int r = 0; r < 4; r++) {
                int row = crow + i * 16 + r;
                if (row < M) {
                    float v = acc[i][j][r] + bv;
                    if (MODE == 1) v = fmaxf(v, 0.f);
                    if (MODE == 0 || MODE == 2) Cf[(size_t)row * DD + colj] = v;
                    if (MODE == 1 || MODE == 2)
                        Cb[(size_t)row * DD + colj] = f2b(v);
                }
            }
        }
    }
}

// ------------------------------------------------------------------ BatchNorm
__global__ __launch_bounds__(512) void k_bn_stats(const float* __restrict__ h,
                                                  float* __restrict__ gsum,
                                                  float* __restrict__ gsq, int M) {
    int c = threadIdx.x;
    float s = 0.f, q = 0.f;
    for (int r = blockIdx.x; r < M; r += gridDim.x) {
        float v = h[(size_t)r * DD + c];
        s += v; q += v * v;
    }
    atomicAdd(&gsum[c], s);
    atomicAdd(&gsq[c], q);
}

__global__ __launch_bounds__(512) void k_bn_fin(const float* __restrict__ gsum,
                                                const float* __restrict__ gsq,
                                                const float* __restrict__ g,
                                                const float* __restrict__ b,
                                                float* __restrict__ scale,
                                                float* __restrict__ shift, int M) {
    int c = threadIdx.x;
    float mean = gsum[c] / (float)M;
    float var = gsq[c] / (float)M - mean * mean;
    float rs = rsqrtf(var + BN_EPS);
    float sc = g[c] * rs;
    scale[c] = sc;
    shift[c] = b[c] - mean * sc;
}

// BN apply + relu, fp32 in -> bf16 out
__global__ __launch_bounds__(256) void k_bn_apply_b(const float* __restrict__ h,
                                                    const float* __restrict__ scale,
                                                    const float* __restrict__ shift,
                                                    unsigned short* __restrict__ out,
                                                    int M) {
    int total = M * (DD / 4);
    for (int i = blockIdx.x * blockDim.x + threadIdx.x; i < total;
         i += gridDim.x * blockDim.x) {
        float4 v = ((const float4*)h)[i];
        int c = (i & 127) * 4;
        short4 o;
        o.x = (short)f2b(fmaxf(v.x * scale[c + 0] + shift[c + 0], 0.f));
        o.y = (short)f2b(fmaxf(v.y * scale[c + 1] + shift[c + 1], 0.f));
        o.z = (short)f2b(fmaxf(v.z * scale[c + 2] + shift[c + 2], 0.f));
        o.w = (short)f2b(fmaxf(v.w * scale[c + 3] + shift[c + 3], 0.f));
        ((short4*)out)[i] = o;
    }
}

// ------------------------------------------- D=512 neighborhood sum (bf16 io)
__global__ __launch_bounds__(256) void k_agg512b(const unsigned short* __restrict__ h,
                                                 const int* __restrict__ rowptr,
                                                 const int* __restrict__ col,
                                                 unsigned short* __restrict__ out) {
    int node = blockIdx.x * 4 + (threadIdx.x >> 6);
    int lane = threadIdx.x & 63;
    if (node >= NNODES) return;
    size_t base = (size_t)node * DD + lane * 8;
    float acc[8];
    {
        int4 v = *(const int4*)&h[base];
        const unsigned short* u = (const unsigned short*)&v;
#pragma unroll
        for (int i = 0; i < 8; i++) acc[i] = b2f(u[i]);
    }
    int p0 = rowptr[node], p1 = rowptr[node + 1];
    int j = p0;
    for (; j + 1 < p1; j += 2) {
        int s0 = col[j], s1 = col[j + 1];
        int4 v0 = *(const int4*)&h[(size_t)s0 * DD + lane * 8];
        int4 v1 = *(const int4*)&h[(size_t)s1 * DD + lane * 8];
        const unsigned short* u0 = (const unsigned short*)&v0;
        const unsigned short* u1 = (const unsigned short*)&v1;
#pragma unroll
        for (int i = 0; i < 8; i++) acc[i] += b2f(u0[i]) + b2f(u1[i]);
    }
    if (j < p1) {
        int4 v0 = *(const int4*)&h[(size_t)col[j] * DD + lane * 8];
        const unsigned short* u0 = (const unsigned short*)&v0;
#pragma unroll
        for (int i = 0; i < 8; i++) acc[i] += b2f(u0[i]);
    }
    int4 o;
    unsigned short* uo = (unsigned short*)&o;
#pragma unroll
    for (int i = 0; i < 8; i++) uo[i] = f2b(acc[i]);
    *(int4*)&out[base] = o;
}

// ------------------------------------------------------------- GAT coefficients
__global__ __launch_bounds__(256) void k_attn_coef(const float* __restrict__ hh,
                                                   const float* __restrict__ as_,
                                                   const float* __restrict__ ad_,
                                                   float* __restrict__ a_s,
                                                   float* __restrict__ a_d) {
    int node = blockIdx.x;
    int h = threadIdx.x >> 6;
    int lane = threadIdx.x & 63;
    const float* row = hh + (size_t)node * DD + h * CH;
    float v0 = row[lane], v1 = row[lane + 64];
    float ps = v0 * as_[h * CH + lane] + v1 * as_[h * CH + lane + 64];
    float pd = v0 * ad_[h * CH + lane] + v1 * ad_[h * CH + lane + 64];
    for (int off = 32; off; off >>= 1) {
        ps += __shfl_down(ps, off);
        pd += __shfl_down(pd, off);
    }
    if (lane == 0) {
        a_s[node * NH + h] = ps;
        a_d[node * NH + h] = pd;
    }
}

// ------- GAT gather: inline softmax weights, streamed fp32 per-node output
__global__ __launch_bounds__(256) void k_gat_gather(
    const unsigned short* __restrict__ hh, const float* __restrict__ a_s,
    const float* __restrict__ a_d, const int* __restrict__ rowptr,
    const int* __restrict__ col, float* __restrict__ outF) {
    int node = blockIdx.x * 4 + (threadIdx.x >> 6);
    int lane = threadIdx.x & 63;
    if (node >= NNODES) return;
    int h = lane >> 4;
    int idx4 = node * NH + h;
    float adi = a_d[idx4];
    float e = a_s[idx4] + adi;
    e = (e > 0.f) ? e : 0.2f * e;
    float ws = __expf(e);
    float den = ws;
    float acc[8];
    {
        int4 v = *(const int4*)&hh[(size_t)node * DD + lane * 8];
        const unsigned short* u = (const unsigned short*)&v;
#pragma unroll
        for (int i = 0; i < 8; i++) acc[i] = ws * b2f(u[i]);
    }
    int p0 = rowptr[node], p1 = rowptr[node + 1];
    int j = p0;
    for (; j + 1 < p1; j += 2) {
        int s0 = col[j], s1 = col[j + 1];
        float e0 = a_s[s0 * NH + h] + adi;
        float e1 = a_s[s1 * NH + h] + adi;
        e0 = (e0 > 0.f) ? e0 : 0.2f * e0;
        e1 = (e1 > 0.f) ? e1 : 0.2f * e1;
        float w0 = __expf(e0), w1 = __expf(e1);
        int4 v0 = *(const int4*)&hh[(size_t)s0 * DD + lane * 8];
        int4 v1 = *(const int4*)&hh[(size_t)s1 * DD + lane * 8];
        const unsigned short* u0 = (const unsigned short*)&v0;
        const unsigned short* u1 = (const unsigned short*)&v1;
#pragma unroll
        for (int i = 0; i < 8; i++) acc[i] += w0 * b2f(u0[i]) + w1 * b2f(u1[i]);
        den += w0 + w1;
    }
    if (j < p1) {
        int s0 = col[j];
        float e0 = a_s[s0 * NH + h] + adi;
        e0 = (e0 > 0.f) ? e0 : 0.2f * e0;
        float w0 = __expf(e0);
        int4 v0 = *(const int4*)&hh[(size_t)s0 * DD + lane * 8];
        const unsigned short* u0 = (const unsigned short*)&v0;
#pragma unroll
        for (int i = 0; i < 8; i++) acc[i] += w0 * b2f(u0[i]);
        den += w0;
    }
    float inv = 1.f / den;
    float4 o0 = make_float4(acc[0] * inv, acc[1] * inv, acc[2] * inv, acc[3] * inv);
    float4 o1 = make_float4(acc[4] * inv, acc[5] * inv, acc[6] * inv, acc[7] * inv);
    size_t base = (size_t)node * DD + lane * 8;
    *(float4*)&outF[base] = o0;
    *(float4*)&outF[base + 4] = o1;
}

// -------------------- segmented add-pool over sorted batch (+ count * bias)
__global__ __launch_bounds__(512) void k_pool(const float* __restrict__ gatout,
                                              const int* __restrict__ batch,
                                              const float* __restrict__ bias,
                                              float* __restrict__ pool) {
    int g = blockIdx.x;
    int c = threadIdx.x;
    int lo = 0, hi = NNODES;
    while (lo < hi) { int m = (lo + hi) >> 1; if (batch[m] < g) lo = m + 1; else hi = m; }
    int start = lo;
    lo = start; hi = NNODES;
    while (lo < hi) { int m = (lo + hi) >> 1; if (batch[m] < g + 1) lo = m + 1; else hi = m; }
    int end = lo;
    float acc = 0.f;
    for (int n = start; n < end; ++n) acc += gatout[(size_t)n * DD + c];
    pool[g * DD + c] = acc + (float)(end - start) * bias[c];
}

// ------------------------------------------------------------------- fc head
__global__ __launch_bounds__(256) void k_fc1(const float* __restrict__ gin,
                                             const float* __restrict__ W,
                                             const float* __restrict__ bias,
                                             float* __restrict__ out) {
    __shared__ float row[DD];
    int g = blockIdx.x;
    int t = threadIdx.x;
    row[t] = gin[g * DD + t];
    row[t + 256] = gin[g * DD + t + 256];
    __syncthreads();
    for (int cc = 0; cc < 2; ++cc) {
        int c = t + cc * 256;
        float acc = 0.f;
        for (int k = 0; k < DD; k++) acc += row[k] * W[k * DD + c];
        out[g * DD + c] = acc + bias[c];
    }
}

__global__ __launch_bounds__(512) void k_bn64(float* __restrict__ h,
                                              const float* __restrict__ g_,
                                              const float* __restrict__ b_) {
    int c = threadIdx.x;
    float s = 0.f, q = 0.f;
    for (int r = 0; r < NG; r++) {
        float v = h[r * DD + c];
        s += v; q += v * v;
    }
    float mean = s / (float)NG;
    float var = q / (float)NG - mean * mean;
    float rs = rsqrtf(var + BN_EPS);
    float sc = g_[c] * rs, sh = b_[c] - mean * sc;
    for (int r = 0; r < NG; r++) {
        float v = h[r * DD + c];
        h[r * DD + c] = fmaxf(v * sc + sh, 0.f);
    }
}

__global__ __launch_bounds__(128) void k_fc2(const float* __restrict__ h,
                                             const float* __restrict__ W,
                                             const float* __restrict__ bias,
                                             float* __restrict__ out) {
    __shared__ float row[DD];
    int g = blockIdx.x;
    int t = threadIdx.x;
    for (int i = t; i < DD; i += 128) row[i] = h[g * DD + i];
    __syncthreads();
    float acc = 0.f;
    for (int k = 0; k < DD; k++) acc += row[k] * W[k * NHID + t];
    out[g * NHID + t] = acc + bias[t];
}

// ------------------------------------------------------------------ regressor
__global__ __launch_bounds__(128) void k_reg(const float* __restrict__ gw,
                                             const float* __restrict__ gm,
                                             const float* __restrict__ W1,
                                             const float* __restrict__ b1,
                                             const float* __restrict__ W2,
                                             const float* __restrict__ b2,
                                             float* __restrict__ out) {
    __shared__ float x[256];
    __shared__ float red[128];
    int g = blockIdx.x;
    int t = threadIdx.x;
    x[t] = gw[g * NHID + t];
    x[t + 128] = gm[g * NHID + t];
    __syncthreads();
    float acc = b1[t];
    for (int k = 0; k < 256; k++) acc += x[k] * W1[k * NHID + t];
    acc = fmaxf(acc, 0.f);
    red[t] = acc * W2[t];
    __syncthreads();
    for (int off = 64; off; off >>= 1) {
        if (t < off) red[t] += red[t + off];
        __syncthreads();
    }
    if (t == 0) out[g] = red[0] + b2[0];
}

// ==================================================================== launch
extern "C" void kernel_launch(void* const* d_in, const int* in_sizes, int n_in,
                              void* d_out, int out_size, void* d_ws, size_t ws_size,
                              hipStream_t stream) {
    const float* wl_x = (const float*)d_in[0];
    const float* mt_x = (const float*)d_in[1];
    const int* wl_ei = (const int*)d_in[2];
    const int* mt_ei = (const int*)d_in[3];
    const int* wl_batch = (const int*)d_in[4];
    const int* mt_batch = (const int*)d_in[5];
    const float* gin1_W1 = (const float*)d_in[6];
    const float* gin1_b1 = (const float*)d_in[7];
    const float* gin1_W2 = (const float*)d_in[8];
    const float* gin1_b2 = (const float*)d_in[9];
    const float* bn1_g = (const float*)d_in[10];
    const float* bn1_b = (const float*)d_in[11];
    const float* gin2_W1 = (const float*)d_in[12];
    const float* gin2_b1 = (const float*)d_in[13];
    const float* gin2_W2 = (const float*)d_in[14];
    const float* gin2_b2 = (const float*)d_in[15];
    const float* bn2_g = (const float*)d_in[16];
    const float* bn2_b = (const float*)d_in[17];
    const float* gat_W = (const float*)d_in[18];
    const float* gat_as = (const float*)d_in[19];
    const float* gat_ad = (const float*)d_in[20];
    const float* gat_bias = (const float*)d_in[21];
    const float* fc_W1 = (const float*)d_in[22];
    const float* fc_b1 = (const float*)d_in[23];
    const float* fc_bn_g = (const float*)d_in[24];
    const float* fc_bn_b = (const float*)d_in[25];
    const float* fc_W2 = (const float*)d_in[26];
    const float* fc_b2 = (const float*)d_in[27];
    const float* reg_W1 = (const float*)d_in[28];
    const float* reg_b1 = (const float*)d_in[29];
    const float* reg_W2 = (const float*)d_in[30];
    const float* reg_b2 = (const float*)d_in[31];
    float* out = (float*)d_out;

    char* ws = (char*)d_ws;
    size_t o = 0;
    auto alloc = [&](size_t bytes) {
        size_t r = o;
        o = (o + bytes + 255) & ~(size_t)255;
        return r;
    };
    float* f1 = (float*)(ws + alloc((size_t)NNODES * DD * 4));
    unsigned short* hbA = (unsigned short*)(ws + alloc((size_t)NNODES * DD * 2));
    unsigned short* hb1 = (unsigned short*)(ws + alloc((size_t)NNODES * DD * 2));
    unsigned short* hb2 = (unsigned short*)(ws + alloc((size_t)NNODES * DD * 2));
    float* bufA = (float*)(ws + alloc((size_t)NNODES * DIN * 4));
    int* cnt = (int*)(ws + alloc((size_t)NNODES * 4));
    int* rowptr = (int*)(ws + alloc((size_t)(NNODES + 1) * 4));
    int* cursor = (int*)(ws + alloc((size_t)NNODES * 4));
    int* colidx = (int*)(ws + alloc((size_t)NEDGES * 4));
    float* a_s = (float*)(ws + alloc((size_t)NNODES * NH * 4));
    float* a_d = (float*)(ws + alloc((size_t)NNODES * NH * 4));
    float* bnsums = (float*)(ws + alloc(2 * DD * 4));
    float* bnsc = (float*)(ws + alloc(2 * DD * 4));
    float* pool = (float*)(ws + alloc((size_t)NG * DD * 4));
    float* fch = (float*)(ws + alloc((size_t)NG * DD * 4));
    float* gout = (float*)(ws + alloc((size_t)2 * NG * NHID * 4));
    unsigned short* Wt1 = (unsigned short*)(ws + alloc((size_t)DD * DD * 2));
    unsigned short* Wt2 = (unsigned short*)(ws + alloc((size_t)DD * DD * 2));
    unsigned short* Wt3 = (unsigned short*)(ws + alloc((size_t)DD * DD * 2));
    unsigned short* Wt4 = (unsigned short*)(ws + alloc((size_t)DD * DD * 2));
    (void)ws_size; (void)in_sizes; (void)n_in; (void)out_size;

    k_wconv<<<DD, 256, 0, stream>>>(gin1_W2, Wt1);
    k_wconv<<<DD, 256, 0, stream>>>(gin2_W1, Wt2);
    k_wconv<<<DD, 256, 0, stream>>>(gin2_W2, Wt3);
    k_wconv<<<DD, 256, 0, stream>>>(gat_W, Wt4);

    dim3 gmm((NNODES + 127) / 128, DD / 128);
    dim3 g20((NNODES + 63) / 64, 4);

    auto bnpass = [&](const float* src, const float* g, const float* b,
                      unsigned short* dst) {
        hipMemsetAsync(bnsums, 0, 2 * DD * 4, stream);
        k_bn_stats<<<256, 512, 0, stream>>>(src, bnsums, bnsums + DD, NNODES);
        k_bn_fin<<<1, 512, 0, stream>>>(bnsums, bnsums + DD, g, b, bnsc, bnsc + DD,
                                        NNODES);
        k_bn_apply_b<<<2048, 256, 0, stream>>>(src, bnsc, bnsc + DD, dst, NNODES);
    };

    for (int br = 0; br < 2; ++br) {
        const float* x = br ? mt_x : wl_x;
        const int* ei = br ? mt_ei : wl_ei;
        const int* batch = br ? mt_batch : wl_batch;
        const int* srcp = ei;
        const int* dstp = ei + NEDGES;

        // CSR by destination
        hipMemsetAsync(cnt, 0, (size_t)NNODES * 4, stream);
        k_hist<<<512, 256, 0, stream>>>(dstp, cnt, NEDGES);
        k_scan2<<<1, 512, 0, stream>>>(cnt, rowptr, cursor, NNODES);
        k_scatter<<<512, 256, 0, stream>>>(srcp, dstp, cursor, colidx, NEDGES);

        // GIN1
        k_gin1_agg<<<7500, 256, 0, stream>>>(x, rowptr, colidx, bufA);
        k_gemm20<<<g20, 256, 0, stream>>>(bufA, gin1_W1, gin1_b1, hbA);
        k_gemm_mfma<0><<<gmm, 256, 0, stream>>>(hbA, Wt1, gin1_b2, f1, nullptr,
                                                NNODES);
        bnpass(f1, bn1_g, bn1_b, hb1);

        // GIN2
        k_agg512b<<<7500, 256, 0, stream>>>(hb1, rowptr, colidx, hb2);
        k_gemm_mfma<1><<<gmm, 256, 0, stream>>>(hb2, Wt2, gin2_b1, nullptr, hbA,
                                                NNODES);
        k_gemm_mfma<0><<<gmm, 256, 0, stream>>>(hbA, Wt3, gin2_b2, f1, nullptr,
                                                NNODES);
        bnpass(f1, bn2_g, bn2_b, hb1);

        // GAT
        k_gemm_mfma<2><<<gmm, 256, 0, stream>>>(hb1, Wt4, nullptr, f1, hb2,
                                                NNODES);
        k_attn_coef<<<NNODES, 256, 0, stream>>>(f1, gat_as, gat_ad, a_s, a_d);
        k_gat_gather<<<7500, 256, 0, stream>>>(hb2, a_s, a_d, rowptr, colidx, f1);
        k_pool<<<NG, 512, 0, stream>>>(f1, batch, gat_bias, pool);

        // fc head
        k_fc1<<<NG, 256, 0, stream>>>(pool, fc_W1, fc_b1, fch);
        k_bn64<<<1, 512, 0, stream>>>(fch, fc_bn_g, fc_bn_b);
        k_fc2<<<NG, 128, 0, stream>>>(fch, fc_W2, fc_b2, gout + br * NG * NHID);
    }

    k_reg<<<NG, 128, 0, stream>>>(gout, gout + NG * NHID, reg_W1, reg_b1, reg_W2,
                                  reg_b2, out);
}

// Round 8
// 1891.136 us; speedup vs baseline: 1.8592x; 1.1441x over previous
//
#include <hip/hip_runtime.h>
#include <hip/hip_bf16.h>
#include <math.h>

#define N1     30000          // nodes per branch
#define NT     60000          // merged nodes
#define E1     480000
#define NG     64             // graphs per branch
#define NGT    128            // merged graphs
#define DIN    20
#define DD     512
#define NH     4
#define CH     128
#define NHID   128
#define PSPLIT 8
#define BN_EPS 1e-5f

typedef __attribute__((ext_vector_type(8))) short bf16x8;
typedef __attribute__((ext_vector_type(4))) float f32x4;

__device__ inline unsigned short f2b(float f) {
    __hip_bfloat16 h = __float2bfloat16(f);
    return *(unsigned short*)&h;
}
__device__ inline float b2f(unsigned short u) {
    return __uint_as_float(((unsigned)u) << 16);
}

// ------------------------------------------------------------ merge helpers
__global__ __launch_bounds__(256) void k_xmerge(const float* __restrict__ a,
                                                const float* __restrict__ b,
                                                float* __restrict__ xm) {
    int i = blockIdx.x * 256 + threadIdx.x;
    int tot = NT * DIN;
    if (i < tot) xm[i] = (i < N1 * DIN) ? a[i] : b[i - N1 * DIN];
}

__global__ __launch_bounds__(256) void k_bmerge(const int* __restrict__ a,
                                                const int* __restrict__ b,
                                                int* __restrict__ bm) {
    int i = blockIdx.x * 256 + threadIdx.x;
    if (i < NT) bm[i] = (i < N1) ? a[i] : b[i - N1] + NG;
}

// ---------------------------------------------------------------- CSR build
__global__ __launch_bounds__(256) void k_hist2(const int* __restrict__ dwl,
                                               const int* __restrict__ dmt,
                                               int* __restrict__ cnt) {
    for (int e = blockIdx.x * blockDim.x + threadIdx.x; e < E1;
         e += gridDim.x * blockDim.x) {
        atomicAdd(&cnt[dwl[e]], 1);
        atomicAdd(&cnt[dmt[e] + N1], 1);
    }
}

__global__ __launch_bounds__(512) void k_scan2(const int* __restrict__ cnt,
                                               int* __restrict__ rowptr,
                                               int* __restrict__ cursor, int n) {
    __shared__ int sd[512];
    int t = threadIdx.x;
    int per = (n + 511) / 512;
    int lo = t * per, hi = lo + per;
    if (hi > n) hi = n;
    int s = 0;
    for (int i = lo; i < hi; ++i) s += cnt[i];
    sd[t] = s;
    __syncthreads();
    for (int off = 1; off < 512; off <<= 1) {
        int v = (t >= off) ? sd[t - off] : 0;
        __syncthreads();
        sd[t] += v;
        __syncthreads();
    }
    int run = sd[t] - s;
    for (int i = lo; i < hi; ++i) {
        rowptr[i] = run;
        cursor[i] = run;
        run += cnt[i];
    }
    if (t == 511) rowptr[n] = sd[511];
}

__global__ __launch_bounds__(256) void k_scatter2(const int* __restrict__ swl,
                                                  const int* __restrict__ dwl,
                                                  const int* __restrict__ smt,
                                                  const int* __restrict__ dmt,
                                                  int* __restrict__ cursor,
                                                  int* __restrict__ col) {
    for (int e = blockIdx.x * blockDim.x + threadIdx.x; e < E1;
         e += gridDim.x * blockDim.x) {
        int d0 = dwl[e];
        col[atomicAdd(&cursor[d0], 1)] = swl[e];
        int d1 = dmt[e] + N1;
        col[atomicAdd(&cursor[d1], 1)] = smt[e] + N1;
    }
}

// ---------------------------------------------------------- weight conv+transp
__global__ __launch_bounds__(256) void k_wconv(const float* __restrict__ W,
                                               unsigned short* __restrict__ Wt) {
    int n = blockIdx.x;
    for (int k = threadIdx.x; k < DD; k += 256)
        Wt[n * DD + k] = f2b(W[k * DD + n]);
}

// ------------------------------------------------------------- GIN1 agg (20)
__global__ __launch_bounds__(256) void k_gin1_agg(const float* __restrict__ x,
                                                  const int* __restrict__ rowptr,
                                                  const int* __restrict__ col,
                                                  float* __restrict__ out) {
    int node = blockIdx.x * 4 + (threadIdx.x >> 6);
    int lane = threadIdx.x & 63;
    if (node >= NT) return;
    int p0 = rowptr[node], p1 = rowptr[node + 1];
    float acc = 0.f;
    if (lane < DIN) acc = x[(size_t)node * DIN + lane];
    for (int j = p0; j < p1; ++j) {
        int s = col[j];
        if (lane < DIN) acc += x[(size_t)s * DIN + lane];
    }
    if (lane < DIN) out[(size_t)node * DIN + lane] = acc;
}

// ------------------------------------- GEMM [NT,20]@[20,512]+relu -> bf16 out
__global__ __launch_bounds__(256) void k_gemm20(const float* __restrict__ A,
                                                const float* __restrict__ W,
                                                const float* __restrict__ bias,
                                                unsigned short* __restrict__ C) {
    __shared__ float Ws[DIN][128];
    __shared__ float As[64][DIN + 1];
    int t = threadIdx.x;
    int row0 = blockIdx.x * 64;
    int col0 = blockIdx.y * 128;
    for (int i = t; i < DIN * 128; i += 256) {
        int k = i >> 7, c = i & 127;
        Ws[k][c] = W[k * DD + col0 + c];
    }
    for (int i = t; i < 64 * DIN; i += 256) {
        int r = i / DIN, k = i % DIN;
        int rr = row0 + r;
        if (rr >= NT) rr = NT - 1;
        As[r][k] = A[(size_t)rr * DIN + k];
    }
    __syncthreads();
    int c4 = (t & 31) * 4;
    int r0 = (t >> 5) * 8;
    float acc[8][4];
#pragma unroll
    for (int i = 0; i < 8; i++)
#pragma unroll
        for (int j = 0; j < 4; j++) acc[i][j] = 0.f;
    for (int k = 0; k < DIN; k++) {
        float4 b = *(const float4*)&Ws[k][c4];
#pragma unroll
        for (int i = 0; i < 8; i++) {
            float a = As[r0 + i][k];
            acc[i][0] += a * b.x; acc[i][1] += a * b.y;
            acc[i][2] += a * b.z; acc[i][3] += a * b.w;
        }
    }
    float4 bb = *(const float4*)&bias[col0 + c4];
#pragma unroll
    for (int i = 0; i < 8; i++) {
        int r = row0 + r0 + i;
        if (r < NT) {
            short4 o;
            o.x = (short)f2b(fmaxf(acc[i][0] + bb.x, 0.f));
            o.y = (short)f2b(fmaxf(acc[i][1] + bb.y, 0.f));
            o.z = (short)f2b(fmaxf(acc[i][2] + bb.z, 0.f));
            o.w = (short)f2b(fmaxf(acc[i][3] + bb.w, 0.f));
            *(short4*)&C[(size_t)r * DD + col0 + c4] = o;
        }
    }
}

// ------------------------------- MFMA GEMM [M,512](bf16) @ Wt[512,512](bf16^T)
// MODE: 0 = bf16 out + bias            (pre-BN)
//       1 = bf16 out + bias + relu     (mid-MLP)
//       2 = bf16 out, no bias, and a_s/a_d computed in epilogue (GAT)
template <int MODE>
__global__ __launch_bounds__(256) void k_gemm_mfma(
    const unsigned short* __restrict__ A, const unsigned short* __restrict__ Wt,
    const float* __restrict__ bias, unsigned short* __restrict__ Cb,
    const float* __restrict__ att_s, const float* __restrict__ att_d,
    float* __restrict__ as_o, float* __restrict__ ad_o, int M) {
    __shared__ char smem[2 * 128 * 144];
    __shared__ float s_att[2 * 128];   // MODE 2 only
    char* AsB = smem;
    char* BsB = smem + 128 * 144;

    int t = threadIdx.x;
    int lane = t & 63;
    int w = t >> 6;
    int wm = (w >> 1) * 64, wn = (w & 1) * 64;
    int row0 = blockIdx.x * 128;
    int col0 = blockIdx.y * 128;

    int srow = t >> 3;
    int slot = t & 7;

    const char* Ab = (const char*)A;
    const char* Bb = (const char*)Wt;

    f32x4 acc[4][4];
#pragma unroll
    for (int i = 0; i < 4; i++)
#pragma unroll
        for (int j = 0; j < 4; j++) acc[i][j] = (f32x4){0.f, 0.f, 0.f, 0.f};

    int4 ra[4], rb[4];
    auto load_tiles = [&](int k0) {
#pragma unroll
        for (int p = 0; p < 4; p++) {
            int rA = row0 + srow + 32 * p;
            if (rA >= M) rA = M - 1;
            ra[p] = *(const int4*)(Ab + (size_t)rA * 1024 + k0 * 2 + slot * 16);
            int rB = col0 + srow + 32 * p;
            rb[p] = *(const int4*)(Bb + (size_t)rB * 1024 + k0 * 2 + slot * 16);
        }
    };

    load_tiles(0);
    const char* Aw = AsB + (wm + (lane & 15)) * 144 + (lane >> 4) * 16;
    const char* Bw = BsB + (wn + (lane & 15)) * 144 + (lane >> 4) * 16;

    for (int step = 0; step < 8; ++step) {
        __syncthreads();
#pragma unroll
        for (int p = 0; p < 4; p++) {
            *(int4*)(AsB + (srow + 32 * p) * 144 + slot * 16) = ra[p];
            *(int4*)(BsB + (srow + 32 * p) * 144 + slot * 16) = rb[p];
        }
        __syncthreads();
        if (step < 7) load_tiles((step + 1) * 64);
#pragma unroll
        for (int kx = 0; kx < 2; ++kx) {
            int kb = kx * 64;
            bf16x8 am[4], bn[4];
#pragma unroll
            for (int i = 0; i < 4; i++)
                am[i] = *(const bf16x8*)(Aw + i * 16 * 144 + kb);
#pragma unroll
            for (int j = 0; j < 4; j++)
                bn[j] = *(const bf16x8*)(Bw + j * 16 * 144 + kb);
#pragma unroll
            for (int i = 0; i < 4; i++)
#pragma unroll
                for (int j = 0; j < 4; j++)
                    acc[i][j] = __builtin_amdgcn_mfma_f32_16x16x32_bf16(
                        am[i], bn[j], acc[i][j], 0, 0, 0);
        }
    }

    int c0 = wn + (lane & 15);      // col within 128-wide tile
    int ccol = col0 + c0;
    if (MODE == 2) {
        // epilogue: bf16 store + per-row attention logits for head blockIdx.y
        if (t < 128) { s_att[t] = 0.f; s_att[128 + t] = 0.f; }
        __syncthreads();
        float fa[4], fd[4];
#pragma unroll
        for (int j = 0; j < 4; j++) {
            fa[j] = att_s[blockIdx.y * CH + c0 + j * 16];
            fd[j] = att_d[blockIdx.y * CH + c0 + j * 16];
        }
#pragma unroll
        for (int i = 0; i < 4; i++) {
#pragma unroll
            for (int r = 0; r < 4; r++) {
                int lrow = wm + (lane >> 4) * 4 + i * 16 + r;
                int row = row0 + lrow;
                float ss = 0.f, sd = 0.f;
#pragma unroll
                for (int j = 0; j < 4; j++) {
                    float v = acc[i][j][r];
                    ss += v * fa[j];
                    sd += v * fd[j];
                    if (row < M) Cb[(size_t)row * DD + ccol + j * 16] = f2b(v);
                }
                atomicAdd(&s_att[lrow], ss);
                atomicAdd(&s_att[128 + lrow], sd);
            }
        }
        __syncthreads();
        if (t < 128) {
            int row = row0 + t;
            if (row < M) {
                as_o[row * NH + blockIdx.y] = s_att[t];
                ad_o[row * NH + blockIdx.y] = s_att[128 + t];
            }
        }
    } else {
        int crow = row0 + wm + (lane >> 4) * 4;
#pragma unroll
        for (int j = 0; j < 4; j++) {
            int colj = ccol + j * 16;
            float bv = bias[colj];
#pragma unroll
            for (int i = 0; i < 4; i++) {
#pragma unroll
                for (int r = 0; r < 4; r++) {
                    int row = crow + i * 16 + r;
                    if (row < M) {
                        float v = acc[i][j][r] + bv;
                        if (MODE == 1) v = fmaxf(v, 0.f);
                        Cb[(size_t)row * DD + colj] = f2b(v);
                    }
                }
            }
        }
    }
}

// --------------------------- BatchNorm over bf16, two branch segments
__global__ __launch_bounds__(256) void k_bn_stats2b(const unsigned short* __restrict__ h,
                                                    float* __restrict__ sums) {
    int t = threadIdx.x;                 // channels 2t, 2t+1
    float sa[2] = {0.f, 0.f}, qa[2] = {0.f, 0.f};
    float sb[2] = {0.f, 0.f}, qb[2] = {0.f, 0.f};
    for (int r = blockIdx.x; r < NT; r += gridDim.x) {
        unsigned u = ((const unsigned*)(h + (size_t)r * DD))[t];
        float va = b2f((unsigned short)(u & 0xffff));
        float vb = b2f((unsigned short)(u >> 16));
        int seg = (r >= N1);
        sa[seg] += va; qa[seg] += va * va;
        sb[seg] += vb; qb[seg] += vb * vb;
    }
    int c = 2 * t;
#pragma unroll
    for (int seg = 0; seg < 2; ++seg) {
        atomicAdd(&sums[seg * DD + c], sa[seg]);
        atomicAdd(&sums[seg * DD + c + 1], sb[seg]);
        atomicAdd(&sums[2 * DD + seg * DD + c], qa[seg]);
        atomicAdd(&sums[2 * DD + seg * DD + c + 1], qb[seg]);
    }
}

__global__ __launch_bounds__(512) void k_bn_fin2(const float* __restrict__ sums,
                                                 const float* __restrict__ g,
                                                 const float* __restrict__ b,
                                                 float* __restrict__ sc) {
    int c = threadIdx.x;
#pragma unroll
    for (int seg = 0; seg < 2; ++seg) {
        float mean = sums[seg * DD + c] / (float)N1;
        float var = sums[2 * DD + seg * DD + c] / (float)N1 - mean * mean;
        float rs = rsqrtf(var + BN_EPS);
        float s = g[c] * rs;
        sc[seg * DD + c] = s;
        sc[2 * DD + seg * DD + c] = b[c] - mean * s;
    }
}

// BN apply + relu, in-place on bf16 buffer
__global__ __launch_bounds__(256) void k_bn_apply_ip(unsigned short* __restrict__ h,
                                                     const float* __restrict__ sc) {
    int total = NT * (DD / 8);
    for (int i = blockIdx.x * blockDim.x + threadIdx.x; i < total;
         i += gridDim.x * blockDim.x) {
        int4 v = ((int4*)h)[i];
        unsigned short* u = (unsigned short*)&v;
        int row = i >> 6;
        int seg = (row >= N1);
        int c = (i & 63) * 8;
        const float* scale = sc + seg * DD;
        const float* shift = sc + 2 * DD + seg * DD;
#pragma unroll
        for (int k = 0; k < 8; k++) {
            float f = b2f(u[k]) * scale[c + k] + shift[c + k];
            u[k] = f2b(fmaxf(f, 0.f));
        }
        ((int4*)h)[i] = v;
    }
}

// ------------------------------------------- D=512 neighborhood sum (bf16 io)
__global__ __launch_bounds__(256) void k_agg512b(const unsigned short* __restrict__ h,
                                                 const int* __restrict__ rowptr,
                                                 const int* __restrict__ col,
                                                 unsigned short* __restrict__ out) {
    int node = blockIdx.x * 4 + (threadIdx.x >> 6);
    int lane = threadIdx.x & 63;
    if (node >= NT) return;
    size_t base = (size_t)node * DD + lane * 8;
    float acc[8];
    {
        int4 v = *(const int4*)&h[base];
        const unsigned short* u = (const unsigned short*)&v;
#pragma unroll
        for (int i = 0; i < 8; i++) acc[i] = b2f(u[i]);
    }
    int p0 = rowptr[node], p1 = rowptr[node + 1];
    int j = p0;
    for (; j + 1 < p1; j += 2) {
        int s0 = col[j], s1 = col[j + 1];
        int4 v0 = *(const int4*)&h[(size_t)s0 * DD + lane * 8];
        int4 v1 = *(const int4*)&h[(size_t)s1 * DD + lane * 8];
        const unsigned short* u0 = (const unsigned short*)&v0;
        const unsigned short* u1 = (const unsigned short*)&v1;
#pragma unroll
        for (int i = 0; i < 8; i++) acc[i] += b2f(u0[i]) + b2f(u1[i]);
    }
    if (j < p1) {
        int4 v0 = *(const int4*)&h[(size_t)col[j] * DD + lane * 8];
        const unsigned short* u0 = (const unsigned short*)&v0;
#pragma unroll
        for (int i = 0; i < 8; i++) acc[i] += b2f(u0[i]);
    }
    int4 o;
    unsigned short* uo = (unsigned short*)&o;
#pragma unroll
    for (int i = 0; i < 8; i++) uo[i] = f2b(acc[i]);
    *(int4*)&out[base] = o;
}

// ------- GAT gather: inline softmax weights, bf16 per-node output
__global__ __launch_bounds__(256) void k_gat_gather(
    const unsigned short* __restrict__ hh, const float* __restrict__ a_s,
    const float* __restrict__ a_d, const int* __restrict__ rowptr,
    const int* __restrict__ col, unsigned short* __restrict__ outB) {
    int node = blockIdx.x * 4 + (threadIdx.x >> 6);
    int lane = threadIdx.x & 63;
    if (node >= NT) return;
    int h = lane >> 4;
    int idx4 = node * NH + h;
    float adi = a_d[idx4];
    float e = a_s[idx4] + adi;
    e = (e > 0.f) ? e : 0.2f * e;
    float ws = __expf(e);
    float den = ws;
    float acc[8];
    {
        int4 v = *(const int4*)&hh[(size_t)node * DD + lane * 8];
        const unsigned short* u = (const unsigned short*)&v;
#pragma unroll
        for (int i = 0; i < 8; i++) acc[i] = ws * b2f(u[i]);
    }
    int p0 = rowptr[node], p1 = rowptr[node + 1];
    int j = p0;
    for (; j + 1 < p1; j += 2) {
        int s0 = col[j], s1 = col[j + 1];
        float e0 = a_s[s0 * NH + h] + adi;
        float e1 = a_s[s1 * NH + h] + adi;
        e0 = (e0 > 0.f) ? e0 : 0.2f * e0;
        e1 = (e1 > 0.f) ? e1 : 0.2f * e1;
        float w0 = __expf(e0), w1 = __expf(e1);
        int4 v0 = *(const int4*)&hh[(size_t)s0 * DD + lane * 8];
        int4 v1 = *(const int4*)&hh[(size_t)s1 * DD + lane * 8];
        const unsigned short* u0 = (const unsigned short*)&v0;
        const unsigned short* u1 = (const unsigned short*)&v1;
#pragma unroll
        for (int i = 0; i < 8; i++) acc[i] += w0 * b2f(u0[i]) + w1 * b2f(u1[i]);
        den += w0 + w1;
    }
    if (j < p1) {
        int s0 = col[j];
        float e0 = a_s[s0 * NH + h] + adi;
        e0 = (e0 > 0.f) ? e0 : 0.2f * e0;
        float w0 = __expf(e0);
        int4 v0 = *(const int4*)&hh[(size_t)s0 * DD + lane * 8];
        const unsigned short* u0 = (const unsigned short*)&v0;
#pragma unroll
        for (int i = 0; i < 8; i++) acc[i] += w0 * b2f(u0[i]);
        den += w0;
    }
    float inv = 1.f / den;
    int4 o;
    unsigned short* uo = (unsigned short*)&o;
#pragma unroll
    for (int i = 0; i < 8; i++) uo[i] = f2b(acc[i] * inv);
    *(int4*)&outB[(size_t)node * DD + lane * 8] = o;
}

// ------------------------- two-stage segmented add-pool (sorted merged batch)
__device__ inline void graph_range(const int* __restrict__ bm, int g,
                                   int& start, int& end) {
    int lo = 0, hi = NT;
    while (lo < hi) { int m = (lo + hi) >> 1; if (bm[m] < g) lo = m + 1; else hi = m; }
    start = lo;
    hi = NT;
    while (lo < hi) { int m = (lo + hi) >> 1; if (bm[m] < g + 1) lo = m + 1; else hi = m; }
    end = lo;
}

__global__ __launch_bounds__(256) void k_pool1(const unsigned short* __restrict__ gatout,
                                               const int* __restrict__ bm,
                                               float* __restrict__ partial) {
    int g = blockIdx.x;
    int s = blockIdx.y;
    int t = threadIdx.x;                 // channels 2t, 2t+1
    int start, end;
    graph_range(bm, g, start, end);
    float a0 = 0.f, a1 = 0.f;
    for (int n = start + s; n < end; n += PSPLIT) {
        unsigned u = ((const unsigned*)(gatout + (size_t)n * DD))[t];
        a0 += b2f((unsigned short)(u & 0xffff));
        a1 += b2f((unsigned short)(u >> 16));
    }
    float* p = partial + ((size_t)g * PSPLIT + s) * DD;
    p[2 * t] = a0;
    p[2 * t + 1] = a1;
}

__global__ __launch_bounds__(512) void k_pool2(const float* __restrict__ partial,
                                               const int* __restrict__ bm,
                                               const float* __restrict__ bias,
                                               float* __restrict__ pool) {
    int g = blockIdx.x;
    int c = threadIdx.x;
    int start, end;
    graph_range(bm, g, start, end);
    float acc = 0.f;
#pragma unroll
    for (int s = 0; s < PSPLIT; ++s)
        acc += partial[((size_t)g * PSPLIT + s) * DD + c];
    pool[g * DD + c] = acc + (float)(end - start) * bias[c];
}

// ------------------------------------------------------------------- fc head
__global__ __launch_bounds__(256) void k_fc1(const float* __restrict__ gin,
                                             const float* __restrict__ W,
                                             const float* __restrict__ bias,
                                             float* __restrict__ out) {
    __shared__ float row[DD];
    int g = blockIdx.x;
    int t = threadIdx.x;
    row[t] = gin[g * DD + t];
    row[t + 256] = gin[g * DD + t + 256];
    __syncthreads();
    for (int cc = 0; cc < 2; ++cc) {
        int c = t + cc * 256;
        float acc = 0.f;
        for (int k = 0; k < DD; k++) acc += row[k] * W[k * DD + c];
        out[g * DD + c] = acc + bias[c];
    }
}

__global__ __launch_bounds__(512) void k_bn64_2(float* __restrict__ h,
                                                const float* __restrict__ g_,
                                                const float* __restrict__ b_) {
    int c = threadIdx.x;
#pragma unroll
    for (int seg = 0; seg < 2; ++seg) {
        float s = 0.f, q = 0.f;
        for (int r = 0; r < NG; r++) {
            float v = h[(seg * NG + r) * DD + c];
            s += v; q += v * v;
        }
        float mean = s / (float)NG;
        float var = q / (float)NG - mean * mean;
        float rs = rsqrtf(var + BN_EPS);
        float sc = g_[c] * rs, sh = b_[c] - mean * sc;
        for (int r = 0; r < NG; r++) {
            float v = h[(seg * NG + r) * DD + c];
            h[(seg * NG + r) * DD + c] = fmaxf(v * sc + sh, 0.f);
        }
    }
}

__global__ __launch_bounds__(128) void k_fc2(const float* __restrict__ h,
                                             const float* __restrict__ W,
                                             const float* __restrict__ bias,
                                             float* __restrict__ out) {
    __shared__ float row[DD];
    int g = blockIdx.x;
    int t = threadIdx.x;
    for (int i = t; i < DD; i += 128) row[i] = h[g * DD + i];
    __syncthreads();
    float acc = 0.f;
    for (int k = 0; k < DD; k++) acc += row[k] * W[k * NHID + t];
    out[g * NHID + t] = acc + bias[t];
}

// ------------------------------------------------------------------ regressor
__global__ __launch_bounds__(128) void k_reg(const float* __restrict__ gout,
                                             const float* __restrict__ W1,
                                             const float* __restrict__ b1,
                                             const float* __restrict__ W2,
                                             const float* __restrict__ b2,
                                             float* __restrict__ out) {
    __shared__ float x[256];
    __shared__ float red[128];
    int g = blockIdx.x;
    int t = threadIdx.x;
    x[t] = gout[g * NHID + t];
    x[t + 128] = gout[(NG + g) * NHID + t];
    __syncthreads();
    float acc = b1[t];
    for (int k = 0; k < 256; k++) acc += x[k] * W1[k * NHID + t];
    acc = fmaxf(acc, 0.f);
    red[t] = acc * W2[t];
    __syncthreads();
    for (int off = 64; off; off >>= 1) {
        if (t < off) red[t] += red[t + off];
        __syncthreads();
    }
    if (t == 0) out[g] = red[0] + b2[0];
}

// ==================================================================== launch
extern "C" void kernel_launch(void* const* d_in, const int* in_sizes, int n_in,
                              void* d_out, int out_size, void* d_ws, size_t ws_size,
                              hipStream_t stream) {
    const float* wl_x = (const float*)d_in[0];
    const float* mt_x = (const float*)d_in[1];
    const int* wl_ei = (const int*)d_in[2];
    const int* mt_ei = (const int*)d_in[3];
    const int* wl_batch = (const int*)d_in[4];
    const int* mt_batch = (const int*)d_in[5];
    const float* gin1_W1 = (const float*)d_in[6];
    const float* gin1_b1 = (const float*)d_in[7];
    const float* gin1_W2 = (const float*)d_in[8];
    const float* gin1_b2 = (const float*)d_in[9];
    const float* bn1_g = (const float*)d_in[10];
    const float* bn1_b = (const float*)d_in[11];
    const float* gin2_W1 = (const float*)d_in[12];
    const float* gin2_b1 = (const float*)d_in[13];
    const float* gin2_W2 = (const float*)d_in[14];
    const float* gin2_b2 = (const float*)d_in[15];
    const float* bn2_g = (const float*)d_in[16];
    const float* bn2_b = (const float*)d_in[17];
    const float* gat_W = (const float*)d_in[18];
    const float* gat_as = (const float*)d_in[19];
    const float* gat_ad = (const float*)d_in[20];
    const float* gat_bias = (const float*)d_in[21];
    const float* fc_W1 = (const float*)d_in[22];
    const float* fc_b1 = (const float*)d_in[23];
    const float* fc_bn_g = (const float*)d_in[24];
    const float* fc_bn_b = (const float*)d_in[25];
    const float* fc_W2 = (const float*)d_in[26];
    const float* fc_b2 = (const float*)d_in[27];
    const float* reg_W1 = (const float*)d_in[28];
    const float* reg_b1 = (const float*)d_in[29];
    const float* reg_W2 = (const float*)d_in[30];
    const float* reg_b2 = (const float*)d_in[31];
    float* out = (float*)d_out;

    char* ws = (char*)d_ws;
    size_t o = 0;
    auto alloc = [&](size_t bytes) {
        size_t r = o;
        o = (o + bytes + 255) & ~(size_t)255;
        return r;
    };
    unsigned short* hbA = (unsigned short*)(ws + alloc((size_t)NT * DD * 2)); // 61.4 MB
    unsigned short* hbB = (unsigned short*)(ws + alloc((size_t)NT * DD * 2)); // 61.4 MB
    float* xm = (float*)(ws + alloc((size_t)NT * DIN * 4));
    float* bufA = (float*)(ws + alloc((size_t)NT * DIN * 4));
    int* bm = (int*)(ws + alloc((size_t)NT * 4));
    int* cnt = (int*)(ws + alloc((size_t)NT * 4));
    int* rowptr = (int*)(ws + alloc((size_t)(NT + 1) * 4));
    int* cursor = (int*)(ws + alloc((size_t)NT * 4));
    int* colidx = (int*)(ws + alloc((size_t)2 * E1 * 4));
    float* a_s = (float*)(ws + alloc((size_t)NT * NH * 4));
    float* a_d = (float*)(ws + alloc((size_t)NT * NH * 4));
    float* bnsums = (float*)(ws + alloc(4 * DD * 4));
    float* bnsc = (float*)(ws + alloc(4 * DD * 4));
    float* partial = (float*)(ws + alloc((size_t)NGT * PSPLIT * DD * 4));
    float* pool = (float*)(ws + alloc((size_t)NGT * DD * 4));
    float* fch = (float*)(ws + alloc((size_t)NGT * DD * 4));
    float* gout = (float*)(ws + alloc((size_t)NGT * NHID * 4));
    unsigned short* Wt1 = (unsigned short*)(ws + alloc((size_t)DD * DD * 2));
    unsigned short* Wt2 = (unsigned short*)(ws + alloc((size_t)DD * DD * 2));
    unsigned short* Wt3 = (unsigned short*)(ws + alloc((size_t)DD * DD * 2));
    unsigned short* Wt4 = (unsigned short*)(ws + alloc((size_t)DD * DD * 2));
    (void)ws_size; (void)in_sizes; (void)n_in; (void)out_size;

    // one-time per launch: weights + merged inputs
    k_wconv<<<DD, 256, 0, stream>>>(gin1_W2, Wt1);
    k_wconv<<<DD, 256, 0, stream>>>(gin2_W1, Wt2);
    k_wconv<<<DD, 256, 0, stream>>>(gin2_W2, Wt3);
    k_wconv<<<DD, 256, 0, stream>>>(gat_W, Wt4);
    k_xmerge<<<(NT * DIN + 255) / 256, 256, 0, stream>>>(wl_x, mt_x, xm);
    k_bmerge<<<(NT + 255) / 256, 256, 0, stream>>>(wl_batch, mt_batch, bm);

    // merged CSR (mt node ids offset by N1)
    hipMemsetAsync(cnt, 0, (size_t)NT * 4, stream);
    k_hist2<<<512, 256, 0, stream>>>(wl_ei + E1, mt_ei + E1, cnt);
    k_scan2<<<1, 512, 0, stream>>>(cnt, rowptr, cursor, NT);
    k_scatter2<<<512, 256, 0, stream>>>(wl_ei, wl_ei + E1, mt_ei, mt_ei + E1,
                                        cursor, colidx);

    dim3 gmm((NT + 127) / 128, DD / 128);
    dim3 g20((NT + 63) / 64, 4);

    auto bnpass = [&](unsigned short* buf, const float* g, const float* b) {
        hipMemsetAsync(bnsums, 0, 4 * DD * 4, stream);
        k_bn_stats2b<<<256, 256, 0, stream>>>(buf, bnsums);
        k_bn_fin2<<<1, 512, 0, stream>>>(bnsums, g, b, bnsc);
        k_bn_apply_ip<<<2048, 256, 0, stream>>>(buf, bnsc);
    };

    // GIN1
    k_gin1_agg<<<(NT + 3) / 4, 256, 0, stream>>>(xm, rowptr, colidx, bufA);
    k_gemm20<<<g20, 256, 0, stream>>>(bufA, gin1_W1, gin1_b1, hbA);
    k_gemm_mfma<0><<<gmm, 256, 0, stream>>>(hbA, Wt1, gin1_b2, hbB, nullptr,
                                            nullptr, nullptr, nullptr, NT);
    bnpass(hbB, bn1_g, bn1_b);                       // h1 in hbB

    // GIN2
    k_agg512b<<<(NT + 3) / 4, 256, 0, stream>>>(hbB, rowptr, colidx, hbA);
    k_gemm_mfma<1><<<gmm, 256, 0, stream>>>(hbA, Wt2, gin2_b1, hbB, nullptr,
                                            nullptr, nullptr, nullptr, NT);
    k_gemm_mfma<0><<<gmm, 256, 0, stream>>>(hbB, Wt3, gin2_b2, hbA, nullptr,
                                            nullptr, nullptr, nullptr, NT);
    bnpass(hbA, bn2_g, bn2_b);                       // h2 in hbA

    // GAT (features bf16 -> hbB, logits a_s/a_d from fp32 accumulators)
    k_gemm_mfma<2><<<gmm, 256, 0, stream>>>(hbA, Wt4, nullptr, hbB, gat_as,
                                            gat_ad, a_s, a_d, NT);
    k_gat_gather<<<(NT + 3) / 4, 256, 0, stream>>>(hbB, a_s, a_d, rowptr, colidx,
                                                   hbA);
    k_pool1<<<dim3(NGT, PSPLIT), 256, 0, stream>>>(hbA, bm, partial);
    k_pool2<<<NGT, 512, 0, stream>>>(partial, bm, gat_bias, pool);

    // fc head (both branches at once)
    k_fc1<<<NGT, 256, 0, stream>>>(pool, fc_W1, fc_b1, fch);
    k_bn64_2<<<1, 512, 0, stream>>>(fch, fc_bn_g, fc_bn_b);
    k_fc2<<<NGT, 128, 0, stream>>>(fch, fc_W2, fc_b2, gout);

    k_reg<<<NG, 128, 0, stream>>>(gout, reg_W1, reg_b1, reg_W2, reg_b2, out);
}

// Round 9
// 1804.538 us; speedup vs baseline: 1.9484x; 1.0480x over previous
//
#include <hip/hip_runtime.h>
#include <hip/hip_bf16.h>
#include <math.h>

#define N1     30000          // nodes per branch
#define NT     60000          // merged nodes
#define E1     480000
#define NG     64             // graphs per branch
#define NGT    128            // merged graphs
#define DIN    20
#define DD     512
#define NH     4
#define CH     128
#define NHID   128
#define PSPLIT 8
#define BN_EPS 1e-5f

typedef __attribute__((ext_vector_type(8))) short bf16x8;
typedef __attribute__((ext_vector_type(4))) float f32x4;

__device__ inline unsigned short f2b(float f) {
    __hip_bfloat16 h = __float2bfloat16(f);
    return *(unsigned short*)&h;
}
__device__ inline float b2f(unsigned short u) {
    return __uint_as_float(((unsigned)u) << 16);
}

// ------------------------------------------------------------ merge helpers
__global__ __launch_bounds__(256) void k_xmerge(const float* __restrict__ a,
                                                const float* __restrict__ b,
                                                float* __restrict__ xm) {
    int i = blockIdx.x * 256 + threadIdx.x;
    int tot = NT * DIN;
    if (i < tot) xm[i] = (i < N1 * DIN) ? a[i] : b[i - N1 * DIN];
}

__global__ __launch_bounds__(256) void k_bmerge(const int* __restrict__ a,
                                                const int* __restrict__ b,
                                                int* __restrict__ bm) {
    int i = blockIdx.x * 256 + threadIdx.x;
    if (i < NT) bm[i] = (i < N1) ? a[i] : b[i - N1] + NG;
}

// ---------------------------------------------------------------- CSR build
__global__ __launch_bounds__(256) void k_hist2(const int* __restrict__ dwl,
                                               const int* __restrict__ dmt,
                                               int* __restrict__ cnt) {
    for (int e = blockIdx.x * blockDim.x + threadIdx.x; e < E1;
         e += gridDim.x * blockDim.x) {
        atomicAdd(&cnt[dwl[e]], 1);
        atomicAdd(&cnt[dmt[e] + N1], 1);
    }
}

__global__ __launch_bounds__(512) void k_scan2(const int* __restrict__ cnt,
                                               int* __restrict__ rowptr,
                                               int* __restrict__ cursor, int n) {
    __shared__ int sd[512];
    int t = threadIdx.x;
    int per = (n + 511) / 512;
    int lo = t * per, hi = lo + per;
    if (hi > n) hi = n;
    int s = 0;
    for (int i = lo; i < hi; ++i) s += cnt[i];
    sd[t] = s;
    __syncthreads();
    for (int off = 1; off < 512; off <<= 1) {
        int v = (t >= off) ? sd[t - off] : 0;
        __syncthreads();
        sd[t] += v;
        __syncthreads();
    }
    int run = sd[t] - s;
    for (int i = lo; i < hi; ++i) {
        rowptr[i] = run;
        cursor[i] = run;
        run += cnt[i];
    }
    if (t == 511) rowptr[n] = sd[511];
}

__global__ __launch_bounds__(256) void k_scatter2(const int* __restrict__ swl,
                                                  const int* __restrict__ dwl,
                                                  const int* __restrict__ smt,
                                                  const int* __restrict__ dmt,
                                                  int* __restrict__ cursor,
                                                  int* __restrict__ col) {
    for (int e = blockIdx.x * blockDim.x + threadIdx.x; e < E1;
         e += gridDim.x * blockDim.x) {
        int d0 = dwl[e];
        col[atomicAdd(&cursor[d0], 1)] = swl[e];
        int d1 = dmt[e] + N1;
        col[atomicAdd(&cursor[d1], 1)] = smt[e] + N1;
    }
}

// ---------------------------------------------------------- weight conv+transp
__global__ __launch_bounds__(256) void k_wconv(const float* __restrict__ W,
                                               unsigned short* __restrict__ Wt) {
    int n = blockIdx.x;
    for (int k = threadIdx.x; k < DD; k += 256)
        Wt[n * DD + k] = f2b(W[k * DD + n]);
}

// ------------------------------------------------------------- GIN1 agg (20)
__global__ __launch_bounds__(256) void k_gin1_agg(const float* __restrict__ x,
                                                  const int* __restrict__ rowptr,
                                                  const int* __restrict__ col,
                                                  float* __restrict__ out) {
    int node = blockIdx.x * 4 + (threadIdx.x >> 6);
    int lane = threadIdx.x & 63;
    if (node >= NT) return;
    int p0 = rowptr[node], p1 = rowptr[node + 1];
    float acc = 0.f;
    if (lane < DIN) acc = x[(size_t)node * DIN + lane];
    for (int j = p0; j < p1; ++j) {
        int s = col[j];
        if (lane < DIN) acc += x[(size_t)s * DIN + lane];
    }
    if (lane < DIN) out[(size_t)node * DIN + lane] = acc;
}

// ------------------------------------- GEMM [NT,20]@[20,512]+relu -> bf16 out
__global__ __launch_bounds__(256) void k_gemm20(const float* __restrict__ A,
                                                const float* __restrict__ W,
                                                const float* __restrict__ bias,
                                                unsigned short* __restrict__ C) {
    __shared__ float Ws[DIN][128];
    __shared__ float As[64][DIN + 1];
    int t = threadIdx.x;
    int row0 = blockIdx.x * 64;
    int col0 = blockIdx.y * 128;
    for (int i = t; i < DIN * 128; i += 256) {
        int k = i >> 7, c = i & 127;
        Ws[k][c] = W[k * DD + col0 + c];
    }
    for (int i = t; i < 64 * DIN; i += 256) {
        int r = i / DIN, k = i % DIN;
        int rr = row0 + r;
        if (rr >= NT) rr = NT - 1;
        As[r][k] = A[(size_t)rr * DIN + k];
    }
    __syncthreads();
    int c4 = (t & 31) * 4;
    int r0 = (t >> 5) * 8;
    float acc[8][4];
#pragma unroll
    for (int i = 0; i < 8; i++)
#pragma unroll
        for (int j = 0; j < 4; j++) acc[i][j] = 0.f;
    for (int k = 0; k < DIN; k++) {
        float4 b = *(const float4*)&Ws[k][c4];
#pragma unroll
        for (int i = 0; i < 8; i++) {
            float a = As[r0 + i][k];
            acc[i][0] += a * b.x; acc[i][1] += a * b.y;
            acc[i][2] += a * b.z; acc[i][3] += a * b.w;
        }
    }
    float4 bb = *(const float4*)&bias[col0 + c4];
#pragma unroll
    for (int i = 0; i < 8; i++) {
        int r = row0 + r0 + i;
        if (r < NT) {
            short4 o;
            o.x = (short)f2b(fmaxf(acc[i][0] + bb.x, 0.f));
            o.y = (short)f2b(fmaxf(acc[i][1] + bb.y, 0.f));
            o.z = (short)f2b(fmaxf(acc[i][2] + bb.z, 0.f));
            o.w = (short)f2b(fmaxf(acc[i][3] + bb.w, 0.f));
            *(short4*)&C[(size_t)r * DD + col0 + c4] = o;
        }
    }
}

// ------------------------------- MFMA GEMM [M,512](bf16) @ Wt[512,512](bf16^T)
// 1-D grid: bid>>2 = row block, bid&3 = col block (adjacent for A locality).
// MODE: 0 = bf16 out + bias; 1 = + relu; 2 = no bias + a_s/a_d epilogue (GAT)
template <int MODE>
__global__ __launch_bounds__(256) void k_gemm_mfma(
    const unsigned short* __restrict__ A, const unsigned short* __restrict__ Wt,
    const float* __restrict__ bias, unsigned short* __restrict__ Cb,
    const float* __restrict__ att_s, const float* __restrict__ att_d,
    float* __restrict__ as_o, float* __restrict__ ad_o, int M) {
    __shared__ char smem[2 * 128 * 144];   // staging; reused as 128x144 ushort out
    __shared__ float s_att[2 * 128];       // MODE 2 only
    char* AsB = smem;
    char* BsB = smem + 128 * 144;

    int t = threadIdx.x;
    int lane = t & 63;
    int w = t >> 6;
    int wm = (w >> 1) * 64, wn = (w & 1) * 64;
    int bid = blockIdx.x;
    int row0 = (bid >> 2) * 128;
    int ct = bid & 3;
    int col0 = ct * 128;

    int srow = t >> 3;
    int slot = t & 7;

    const char* Ab = (const char*)A;
    const char* Bb = (const char*)Wt;

    f32x4 acc[4][4];
#pragma unroll
    for (int i = 0; i < 4; i++)
#pragma unroll
        for (int j = 0; j < 4; j++) acc[i][j] = (f32x4){0.f, 0.f, 0.f, 0.f};

    int4 ra[4], rb[4];
    auto load_tiles = [&](int k0) {
#pragma unroll
        for (int p = 0; p < 4; p++) {
            int rA = row0 + srow + 32 * p;
            if (rA >= M) rA = M - 1;
            ra[p] = *(const int4*)(Ab + (size_t)rA * 1024 + k0 * 2 + slot * 16);
            int rB = col0 + srow + 32 * p;
            rb[p] = *(const int4*)(Bb + (size_t)rB * 1024 + k0 * 2 + slot * 16);
        }
    };

    load_tiles(0);
    const char* Aw = AsB + (wm + (lane & 15)) * 144 + (lane >> 4) * 16;
    const char* Bw = BsB + (wn + (lane & 15)) * 144 + (lane >> 4) * 16;

    for (int step = 0; step < 8; ++step) {
        __syncthreads();
#pragma unroll
        for (int p = 0; p < 4; p++) {
            *(int4*)(AsB + (srow + 32 * p) * 144 + slot * 16) = ra[p];
            *(int4*)(BsB + (srow + 32 * p) * 144 + slot * 16) = rb[p];
        }
        __syncthreads();
        if (step < 7) load_tiles((step + 1) * 64);
#pragma unroll
        for (int kx = 0; kx < 2; ++kx) {
            int kb = kx * 64;
            bf16x8 am[4], bn[4];
#pragma unroll
            for (int i = 0; i < 4; i++)
                am[i] = *(const bf16x8*)(Aw + i * 16 * 144 + kb);
#pragma unroll
            for (int j = 0; j < 4; j++)
                bn[j] = *(const bf16x8*)(Bw + j * 16 * 144 + kb);
#pragma unroll
            for (int i = 0; i < 4; i++)
#pragma unroll
                for (int j = 0; j < 4; j++)
                    acc[i][j] = __builtin_amdgcn_mfma_f32_16x16x32_bf16(
                        am[i], bn[j], acc[i][j], 0, 0, 0);
        }
    }

    // ---- epilogue: deposit bf16 results into LDS, then coalesced store ----
    __syncthreads();                       // staging reads done; reuse smem
    unsigned short* so = (unsigned short*)smem;   // [128][144] ushort
    int c0 = wn + (lane & 15);             // col within 128-wide tile
    if (MODE == 2 && t < 128) { s_att[t] = 0.f; s_att[128 + t] = 0.f; }
    __syncthreads();

    float fa[4], fd[4], bv[4];
#pragma unroll
    for (int j = 0; j < 4; j++) {
        if (MODE == 2) {
            fa[j] = att_s[ct * CH + c0 + j * 16];
            fd[j] = att_d[ct * CH + c0 + j * 16];
            bv[j] = 0.f;
        } else {
            bv[j] = bias[col0 + c0 + j * 16];
        }
    }
    int rbase = wm + (lane >> 4) * 4;
#pragma unroll
    for (int i = 0; i < 4; i++) {
#pragma unroll
        for (int r = 0; r < 4; r++) {
            int lrow = rbase + i * 16 + r;
            float ss = 0.f, sd = 0.f;
#pragma unroll
            for (int j = 0; j < 4; j++) {
                float v = acc[i][j][r] + bv[j];
                if (MODE == 1) v = fmaxf(v, 0.f);
                if (MODE == 2) { ss += v * fa[j]; sd += v * fd[j]; }
                so[lrow * 144 + c0 + j * 16] = f2b(v);
            }
            if (MODE == 2) {
                atomicAdd(&s_att[lrow], ss);
                atomicAdd(&s_att[128 + lrow], sd);
            }
        }
    }
    __syncthreads();
    // coalesced readout: 16 lanes cover one 256B row segment
#pragma unroll
    for (int rr = 0; rr < 8; rr++) {
        int row = rr * 16 + (t >> 4);
        int grow = row0 + row;
        if (grow < M) {
            int4 v = *(const int4*)&so[row * 144 + (t & 15) * 8];
            *(int4*)&Cb[(size_t)grow * DD + col0 + (t & 15) * 8] = v;
        }
    }
    if (MODE == 2 && t < 128) {
        int row = row0 + t;
        if (row < M) {
            as_o[row * NH + ct] = s_att[t];
            ad_o[row * NH + ct] = s_att[128 + t];
        }
    }
}

// --------------------------- BatchNorm over bf16, two branch segments
__global__ __launch_bounds__(256) void k_bn_stats2b(const unsigned short* __restrict__ h,
                                                    float* __restrict__ sums) {
    int t = threadIdx.x;                 // channels 2t, 2t+1
    float sa[2] = {0.f, 0.f}, qa[2] = {0.f, 0.f};
    float sb[2] = {0.f, 0.f}, qb[2] = {0.f, 0.f};
    for (int r = blockIdx.x; r < NT; r += gridDim.x) {
        unsigned u = ((const unsigned*)(h + (size_t)r * DD))[t];
        float va = b2f((unsigned short)(u & 0xffff));
        float vb = b2f((unsigned short)(u >> 16));
        int seg = (r >= N1);
        sa[seg] += va; qa[seg] += va * va;
        sb[seg] += vb; qb[seg] += vb * vb;
    }
    int c = 2 * t;
#pragma unroll
    for (int seg = 0; seg < 2; ++seg) {
        atomicAdd(&sums[seg * DD + c], sa[seg]);
        atomicAdd(&sums[seg * DD + c + 1], sb[seg]);
        atomicAdd(&sums[2 * DD + seg * DD + c], qa[seg]);
        atomicAdd(&sums[2 * DD + seg * DD + c + 1], qb[seg]);
    }
}

__global__ __launch_bounds__(512) void k_bn_fin2(const float* __restrict__ sums,
                                                 const float* __restrict__ g,
                                                 const float* __restrict__ b,
                                                 float* __restrict__ sc) {
    int c = threadIdx.x;
#pragma unroll
    for (int seg = 0; seg < 2; ++seg) {
        float mean = sums[seg * DD + c] / (float)N1;
        float var = sums[2 * DD + seg * DD + c] / (float)N1 - mean * mean;
        float rs = rsqrtf(var + BN_EPS);
        float s = g[c] * rs;
        sc[seg * DD + c] = s;
        sc[2 * DD + seg * DD + c] = b[c] - mean * s;
    }
}

// BN apply + relu, in-place on bf16 buffer
__global__ __launch_bounds__(256) void k_bn_apply_ip(unsigned short* __restrict__ h,
                                                     const float* __restrict__ sc) {
    int total = NT * (DD / 8);
    for (int i = blockIdx.x * blockDim.x + threadIdx.x; i < total;
         i += gridDim.x * blockDim.x) {
        int4 v = ((int4*)h)[i];
        unsigned short* u = (unsigned short*)&v;
        int row = i >> 6;
        int seg = (row >= N1);
        int c = (i & 63) * 8;
        const float* scale = sc + seg * DD;
        const float* shift = sc + 2 * DD + seg * DD;
#pragma unroll
        for (int k = 0; k < 8; k++) {
            float f = b2f(u[k]) * scale[c + k] + shift[c + k];
            u[k] = f2b(fmaxf(f, 0.f));
        }
        ((int4*)h)[i] = v;
    }
}

// ------------------------------------------- D=512 neighborhood sum (bf16 io)
__global__ __launch_bounds__(256) void k_agg512b(const unsigned short* __restrict__ h,
                                                 const int* __restrict__ rowptr,
                                                 const int* __restrict__ col,
                                                 unsigned short* __restrict__ out) {
    int node = blockIdx.x * 4 + (threadIdx.x >> 6);
    int lane = threadIdx.x & 63;
    if (node >= NT) return;
    size_t base = (size_t)node * DD + lane * 8;
    float acc[8];
    {
        int4 v = *(const int4*)&h[base];
        const unsigned short* u = (const unsigned short*)&v;
#pragma unroll
        for (int i = 0; i < 8; i++) acc[i] = b2f(u[i]);
    }
    int p0 = rowptr[node], p1 = rowptr[node + 1];
    int j = p0;
    for (; j + 1 < p1; j += 2) {
        int s0 = col[j], s1 = col[j + 1];
        int4 v0 = *(const int4*)&h[(size_t)s0 * DD + lane * 8];
        int4 v1 = *(const int4*)&h[(size_t)s1 * DD + lane * 8];
        const unsigned short* u0 = (const unsigned short*)&v0;
        const unsigned short* u1 = (const unsigned short*)&v1;
#pragma unroll
        for (int i = 0; i < 8; i++) acc[i] += b2f(u0[i]) + b2f(u1[i]);
    }
    if (j < p1) {
        int4 v0 = *(const int4*)&h[(size_t)col[j] * DD + lane * 8];
        const unsigned short* u0 = (const unsigned short*)&v0;
#pragma unroll
        for (int i = 0; i < 8; i++) acc[i] += b2f(u0[i]);
    }
    int4 o;
    unsigned short* uo = (unsigned short*)&o;
#pragma unroll
    for (int i = 0; i < 8; i++) uo[i] = f2b(acc[i]);
    *(int4*)&out[base] = o;
}

// ------- GAT gather: inline softmax weights, bf16 per-node output
__global__ __launch_bounds__(256) void k_gat_gather(
    const unsigned short* __restrict__ hh, const float* __restrict__ a_s,
    const float* __restrict__ a_d, const int* __restrict__ rowptr,
    const int* __restrict__ col, unsigned short* __restrict__ outB) {
    int node = blockIdx.x * 4 + (threadIdx.x >> 6);
    int lane = threadIdx.x & 63;
    if (node >= NT) return;
    int h = lane >> 4;
    int idx4 = node * NH + h;
    float adi = a_d[idx4];
    float e = a_s[idx4] + adi;
    e = (e > 0.f) ? e : 0.2f * e;
    float ws = __expf(e);
    float den = ws;
    float acc[8];
    {
        int4 v = *(const int4*)&hh[(size_t)node * DD + lane * 8];
        const unsigned short* u = (const unsigned short*)&v;
#pragma unroll
        for (int i = 0; i < 8; i++) acc[i] = ws * b2f(u[i]);
    }
    int p0 = rowptr[node], p1 = rowptr[node + 1];
    int j = p0;
    for (; j + 1 < p1; j += 2) {
        int s0 = col[j], s1 = col[j + 1];
        float e0 = a_s[s0 * NH + h] + adi;
        float e1 = a_s[s1 * NH + h] + adi;
        e0 = (e0 > 0.f) ? e0 : 0.2f * e0;
        e1 = (e1 > 0.f) ? e1 : 0.2f * e1;
        float w0 = __expf(e0), w1 = __expf(e1);
        int4 v0 = *(const int4*)&hh[(size_t)s0 * DD + lane * 8];
        int4 v1 = *(const int4*)&hh[(size_t)s1 * DD + lane * 8];
        const unsigned short* u0 = (const unsigned short*)&v0;
        const unsigned short* u1 = (const unsigned short*)&v1;
#pragma unroll
        for (int i = 0; i < 8; i++) acc[i] += w0 * b2f(u0[i]) + w1 * b2f(u1[i]);
        den += w0 + w1;
    }
    if (j < p1) {
        int s0 = col[j];
        float e0 = a_s[s0 * NH + h] + adi;
        e0 = (e0 > 0.f) ? e0 : 0.2f * e0;
        float w0 = __expf(e0);
        int4 v0 = *(const int4*)&hh[(size_t)s0 * DD + lane * 8];
        const unsigned short* u0 = (const unsigned short*)&v0;
#pragma unroll
        for (int i = 0; i < 8; i++) acc[i] += w0 * b2f(u0[i]);
        den += w0;
    }
    float inv = 1.f / den;
    int4 o;
    unsigned short* uo = (unsigned short*)&o;
#pragma unroll
    for (int i = 0; i < 8; i++) uo[i] = f2b(acc[i] * inv);
    *(int4*)&outB[(size_t)node * DD + lane * 8] = o;
}

// ------------------------- two-stage segmented add-pool (sorted merged batch)
__device__ inline void graph_range(const int* __restrict__ bm, int g,
                                   int& start, int& end) {
    int lo = 0, hi = NT;
    while (lo < hi) { int m = (lo + hi) >> 1; if (bm[m] < g) lo = m + 1; else hi = m; }
    start = lo;
    hi = NT;
    while (lo < hi) { int m = (lo + hi) >> 1; if (bm[m] < g + 1) lo = m + 1; else hi = m; }
    end = lo;
}

__global__ __launch_bounds__(256) void k_pool1(const unsigned short* __restrict__ gatout,
                                               const int* __restrict__ bm,
                                               float* __restrict__ partial) {
    int g = blockIdx.x;
    int s = blockIdx.y;
    int t = threadIdx.x;                 // channels 2t, 2t+1
    int start, end;
    graph_range(bm, g, start, end);
    float a0 = 0.f, a1 = 0.f;
    for (int n = start + s; n < end; n += PSPLIT) {
        unsigned u = ((const unsigned*)(gatout + (size_t)n * DD))[t];
        a0 += b2f((unsigned short)(u & 0xffff));
        a1 += b2f((unsigned short)(u >> 16));
    }
    float* p = partial + ((size_t)g * PSPLIT + s) * DD;
    p[2 * t] = a0;
    p[2 * t + 1] = a1;
}

__global__ __launch_bounds__(512) void k_pool2(const float* __restrict__ partial,
                                               const int* __restrict__ bm,
                                               const float* __restrict__ bias,
                                               float* __restrict__ pool) {
    int g = blockIdx.x;
    int c = threadIdx.x;
    int start, end;
    graph_range(bm, g, start, end);
    float acc = 0.f;
#pragma unroll
    for (int s = 0; s < PSPLIT; ++s)
        acc += partial[((size_t)g * PSPLIT + s) * DD + c];
    pool[g * DD + c] = acc + (float)(end - start) * bias[c];
}

// ------------------------------------------------------------------- fc head
__global__ __launch_bounds__(256) void k_fc1(const float* __restrict__ gin,
                                             const float* __restrict__ W,
                                             const float* __restrict__ bias,
                                             float* __restrict__ out) {
    __shared__ float row[DD];
    int g = blockIdx.x;
    int t = threadIdx.x;
    row[t] = gin[g * DD + t];
    row[t + 256] = gin[g * DD + t + 256];
    __syncthreads();
    for (int cc = 0; cc < 2; ++cc) {
        int c = t + cc * 256;
        float acc = 0.f;
        for (int k = 0; k < DD; k++) acc += row[k] * W[k * DD + c];
        out[g * DD + c] = acc + bias[c];
    }
}

__global__ __launch_bounds__(512) void k_bn64_2(float* __restrict__ h,
                                                const float* __restrict__ g_,
                                                const float* __restrict__ b_) {
    int c = threadIdx.x;
#pragma unroll
    for (int seg = 0; seg < 2; ++seg) {
        float s = 0.f, q = 0.f;
        for (int r = 0; r < NG; r++) {
            float v = h[(seg * NG + r) * DD + c];
            s += v; q += v * v;
        }
        float mean = s / (float)NG;
        float var = q / (float)NG - mean * mean;
        float rs = rsqrtf(var + BN_EPS);
        float sc = g_[c] * rs, sh = b_[c] - mean * sc;
        for (int r = 0; r < NG; r++) {
            float v = h[(seg * NG + r) * DD + c];
            h[(seg * NG + r) * DD + c] = fmaxf(v * sc + sh, 0.f);
        }
    }
}

__global__ __launch_bounds__(128) void k_fc2(const float* __restrict__ h,
                                             const float* __restrict__ W,
                                             const float* __restrict__ bias,
                                             float* __restrict__ out) {
    __shared__ float row[DD];
    int g = blockIdx.x;
    int t = threadIdx.x;
    for (int i = t; i < DD; i += 128) row[i] = h[g * DD + i];
    __syncthreads();
    float acc = 0.f;
    for (int k = 0; k < DD; k++) acc += row[k] * W[k * NHID + t];
    out[g * NHID + t] = acc + bias[t];
}

// ------------------------------------------------------------------ regressor
__global__ __launch_bounds__(128) void k_reg(const float* __restrict__ gout,
                                             const float* __restrict__ W1,
                                             const float* __restrict__ b1,
                                             const float* __restrict__ W2,
                                             const float* __restrict__ b2,
                                             float* __restrict__ out) {
    __shared__ float x[256];
    __shared__ float red[128];
    int g = blockIdx.x;
    int t = threadIdx.x;
    x[t] = gout[g * NHID + t];
    x[t + 128] = gout[(NG + g) * NHID + t];
    __syncthreads();
    float acc = b1[t];
    for (int k = 0; k < 256; k++) acc += x[k] * W1[k * NHID + t];
    acc = fmaxf(acc, 0.f);
    red[t] = acc * W2[t];
    __syncthreads();
    for (int off = 64; off; off >>= 1) {
        if (t < off) red[t] += red[t + off];
        __syncthreads();
    }
    if (t == 0) out[g] = red[0] + b2[0];
}

// ==================================================================== launch
extern "C" void kernel_launch(void* const* d_in, const int* in_sizes, int n_in,
                              void* d_out, int out_size, void* d_ws, size_t ws_size,
                              hipStream_t stream) {
    const float* wl_x = (const float*)d_in[0];
    const float* mt_x = (const float*)d_in[1];
    const int* wl_ei = (const int*)d_in[2];
    const int* mt_ei = (const int*)d_in[3];
    const int* wl_batch = (const int*)d_in[4];
    const int* mt_batch = (const int*)d_in[5];
    const float* gin1_W1 = (const float*)d_in[6];
    const float* gin1_b1 = (const float*)d_in[7];
    const float* gin1_W2 = (const float*)d_in[8];
    const float* gin1_b2 = (const float*)d_in[9];
    const float* bn1_g = (const float*)d_in[10];
    const float* bn1_b = (const float*)d_in[11];
    const float* gin2_W1 = (const float*)d_in[12];
    const float* gin2_b1 = (const float*)d_in[13];
    const float* gin2_W2 = (const float*)d_in[14];
    const float* gin2_b2 = (const float*)d_in[15];
    const float* bn2_g = (const float*)d_in[16];
    const float* bn2_b = (const float*)d_in[17];
    const float* gat_W = (const float*)d_in[18];
    const float* gat_as = (const float*)d_in[19];
    const float* gat_ad = (const float*)d_in[20];
    const float* gat_bias = (const float*)d_in[21];
    const float* fc_W1 = (const float*)d_in[22];
    const float* fc_b1 = (const float*)d_in[23];
    const float* fc_bn_g = (const float*)d_in[24];
    const float* fc_bn_b = (const float*)d_in[25];
    const float* fc_W2 = (const float*)d_in[26];
    const float* fc_b2 = (const float*)d_in[27];
    const float* reg_W1 = (const float*)d_in[28];
    const float* reg_b1 = (const float*)d_in[29];
    const float* reg_W2 = (const float*)d_in[30];
    const float* reg_b2 = (const float*)d_in[31];
    float* out = (float*)d_out;

    char* ws = (char*)d_ws;
    size_t o = 0;
    auto alloc = [&](size_t bytes) {
        size_t r = o;
        o = (o + bytes + 255) & ~(size_t)255;
        return r;
    };
    unsigned short* hbA = (unsigned short*)(ws + alloc((size_t)NT * DD * 2)); // 61.4 MB
    unsigned short* hbB = (unsigned short*)(ws + alloc((size_t)NT * DD * 2)); // 61.4 MB
    float* xm = (float*)(ws + alloc((size_t)NT * DIN * 4));
    float* bufA = (float*)(ws + alloc((size_t)NT * DIN * 4));
    int* bm = (int*)(ws + alloc((size_t)NT * 4));
    int* cnt = (int*)(ws + alloc((size_t)NT * 4));
    int* rowptr = (int*)(ws + alloc((size_t)(NT + 1) * 4));
    int* cursor = (int*)(ws + alloc((size_t)NT * 4));
    int* colidx = (int*)(ws + alloc((size_t)2 * E1 * 4));
    float* a_s = (float*)(ws + alloc((size_t)NT * NH * 4));
    float* a_d = (float*)(ws + alloc((size_t)NT * NH * 4));
    float* bnsums = (float*)(ws + alloc(4 * DD * 4));
    float* bnsc = (float*)(ws + alloc(4 * DD * 4));
    float* partial = (float*)(ws + alloc((size_t)NGT * PSPLIT * DD * 4));
    float* pool = (float*)(ws + alloc((size_t)NGT * DD * 4));
    float* fch = (float*)(ws + alloc((size_t)NGT * DD * 4));
    float* gout = (float*)(ws + alloc((size_t)NGT * NHID * 4));
    unsigned short* Wt1 = (unsigned short*)(ws + alloc((size_t)DD * DD * 2));
    unsigned short* Wt2 = (unsigned short*)(ws + alloc((size_t)DD * DD * 2));
    unsigned short* Wt3 = (unsigned short*)(ws + alloc((size_t)DD * DD * 2));
    unsigned short* Wt4 = (unsigned short*)(ws + alloc((size_t)DD * DD * 2));
    (void)ws_size; (void)in_sizes; (void)n_in; (void)out_size;

    // one-time per launch: weights + merged inputs
    k_wconv<<<DD, 256, 0, stream>>>(gin1_W2, Wt1);
    k_wconv<<<DD, 256, 0, stream>>>(gin2_W1, Wt2);
    k_wconv<<<DD, 256, 0, stream>>>(gin2_W2, Wt3);
    k_wconv<<<DD, 256, 0, stream>>>(gat_W, Wt4);
    k_xmerge<<<(NT * DIN + 255) / 256, 256, 0, stream>>>(wl_x, mt_x, xm);
    k_bmerge<<<(NT + 255) / 256, 256, 0, stream>>>(wl_batch, mt_batch, bm);

    // merged CSR (mt node ids offset by N1)
    hipMemsetAsync(cnt, 0, (size_t)NT * 4, stream);
    k_hist2<<<512, 256, 0, stream>>>(wl_ei + E1, mt_ei + E1, cnt);
    k_scan2<<<1, 512, 0, stream>>>(cnt, rowptr, cursor, NT);
    k_scatter2<<<512, 256, 0, stream>>>(wl_ei, wl_ei + E1, mt_ei, mt_ei + E1,
                                        cursor, colidx);

    int gmm = ((NT + 127) / 128) * 4;   // 1-D grid: 4 col tiles adjacent
    dim3 g20((NT + 63) / 64, 4);

    auto bnpass = [&](unsigned short* buf, const float* g, const float* b) {
        hipMemsetAsync(bnsums, 0, 4 * DD * 4, stream);
        k_bn_stats2b<<<256, 256, 0, stream>>>(buf, bnsums);
        k_bn_fin2<<<1, 512, 0, stream>>>(bnsums, g, b, bnsc);
        k_bn_apply_ip<<<2048, 256, 0, stream>>>(buf, bnsc);
    };

    // GIN1
    k_gin1_agg<<<(NT + 3) / 4, 256, 0, stream>>>(xm, rowptr, colidx, bufA);
    k_gemm20<<<g20, 256, 0, stream>>>(bufA, gin1_W1, gin1_b1, hbA);
    k_gemm_mfma<0><<<gmm, 256, 0, stream>>>(hbA, Wt1, gin1_b2, hbB, nullptr,
                                            nullptr, nullptr, nullptr, NT);
    bnpass(hbB, bn1_g, bn1_b);                       // h1 in hbB

    // GIN2
    k_agg512b<<<(NT + 3) / 4, 256, 0, stream>>>(hbB, rowptr, colidx, hbA);
    k_gemm_mfma<1><<<gmm, 256, 0, stream>>>(hbA, Wt2, gin2_b1, hbB, nullptr,
                                            nullptr, nullptr, nullptr, NT);
    k_gemm_mfma<0><<<gmm, 256, 0, stream>>>(hbB, Wt3, gin2_b2, hbA, nullptr,
                                            nullptr, nullptr, nullptr, NT);
    bnpass(hbA, bn2_g, bn2_b);                       // h2 in hbA

    // GAT (features bf16 -> hbB, logits a_s/a_d from fp32 accumulators)
    k_gemm_mfma<2><<<gmm, 256, 0, stream>>>(hbA, Wt4, nullptr, hbB, gat_as,
                                            gat_ad, a_s, a_d, NT);
    k_gat_gather<<<(NT + 3) / 4, 256, 0, stream>>>(hbB, a_s, a_d, rowptr, colidx,
                                                   hbA);
    k_pool1<<<dim3(NGT, PSPLIT), 256, 0, stream>>>(hbA, bm, partial);
    k_pool2<<<NGT, 512, 0, stream>>>(partial, bm, gat_bias, pool);

    // fc head (both branches at once)
    k_fc1<<<NGT, 256, 0, stream>>>(pool, fc_W1, fc_b1, fch);
    k_bn64_2<<<1, 512, 0, stream>>>(fch, fc_bn_g, fc_bn_b);
    k_fc2<<<NGT, 128, 0, stream>>>(fch, fc_W2, fc_b2, gout);

    k_reg<<<NG, 128, 0, stream>>>(gout, reg_W1, reg_b1, reg_W2, reg_b2, out);
}

// Round 11
// 1782.797 us; speedup vs baseline: 1.9722x; 1.0122x over previous
//
#include <hip/hip_runtime.h>
#include <hip/hip_bf16.h>
#include <math.h>

#define N1     30000          // nodes per branch
#define NT     60000          // merged nodes
#define E1     480000
#define NG     64             // graphs per branch
#define NGT    128            // merged graphs
#define DIN    20
#define DD     512
#define NH     4
#define CH     128
#define NHID   128
#define PSPLIT 8
#define BN_EPS 1e-5f

typedef __attribute__((ext_vector_type(8))) short bf16x8;
typedef __attribute__((ext_vector_type(4))) float f32x4;

__device__ inline unsigned short f2b(float f) {
    __hip_bfloat16 h = __float2bfloat16(f);
    return *(unsigned short*)&h;
}
__device__ inline float b2f(unsigned short u) {
    return __uint_as_float(((unsigned)u) << 16);
}

// ------------------------------------------------------------ merge helpers
__global__ __launch_bounds__(256) void k_xmerge(const float* __restrict__ a,
                                                const float* __restrict__ b,
                                                float* __restrict__ xm) {
    int i = blockIdx.x * 256 + threadIdx.x;
    int tot = NT * DIN;
    if (i < tot) xm[i] = (i < N1 * DIN) ? a[i] : b[i - N1 * DIN];
}

__global__ __launch_bounds__(256) void k_bmerge(const int* __restrict__ a,
                                                const int* __restrict__ b,
                                                int* __restrict__ bm) {
    int i = blockIdx.x * 256 + threadIdx.x;
    if (i < NT) bm[i] = (i < N1) ? a[i] : b[i - N1] + NG;
}

// ---------------------------------------------------------------- CSR build
__global__ __launch_bounds__(256) void k_hist2(const int* __restrict__ dwl,
                                               const int* __restrict__ dmt,
                                               int* __restrict__ cnt) {
    for (int e = blockIdx.x * blockDim.x + threadIdx.x; e < E1;
         e += gridDim.x * blockDim.x) {
        atomicAdd(&cnt[dwl[e]], 1);
        atomicAdd(&cnt[dmt[e] + N1], 1);
    }
}

__global__ __launch_bounds__(512) void k_scan2(const int* __restrict__ cnt,
                                               int* __restrict__ rowptr,
                                               int* __restrict__ cursor, int n) {
    __shared__ int sd[512];
    int t = threadIdx.x;
    int per = (n + 511) / 512;
    int lo = t * per, hi = lo + per;
    if (hi > n) hi = n;
    int s = 0;
    for (int i = lo; i < hi; ++i) s += cnt[i];
    sd[t] = s;
    __syncthreads();
    for (int off = 1; off < 512; off <<= 1) {
        int v = (t >= off) ? sd[t - off] : 0;
        __syncthreads();
        sd[t] += v;
        __syncthreads();
    }
    int run = sd[t] - s;
    for (int i = lo; i < hi; ++i) {
        rowptr[i] = run;
        cursor[i] = run;
        run += cnt[i];
    }
    if (t == 511) rowptr[n] = sd[511];
}

__global__ __launch_bounds__(256) void k_scatter2(const int* __restrict__ swl,
                                                  const int* __restrict__ dwl,
                                                  const int* __restrict__ smt,
                                                  const int* __restrict__ dmt,
                                                  int* __restrict__ cursor,
                                                  int* __restrict__ col) {
    for (int e = blockIdx.x * blockDim.x + threadIdx.x; e < E1;
         e += gridDim.x * blockDim.x) {
        int d0 = dwl[e];
        col[atomicAdd(&cursor[d0], 1)] = swl[e];
        int d1 = dmt[e] + N1;
        col[atomicAdd(&cursor[d1], 1)] = smt[e] + N1;
    }
}

// ---------------------------------------------------------- weight conv+transp
__global__ __launch_bounds__(256) void k_wconv(const float* __restrict__ W,
                                               unsigned short* __restrict__ Wt) {
    int n = blockIdx.x;
    for (int k = threadIdx.x; k < DD; k += 256)
        Wt[n * DD + k] = f2b(W[k * DD + n]);
}

// ------------------------------------------------------------- GIN1 agg (20)
__global__ __launch_bounds__(256) void k_gin1_agg(const float* __restrict__ x,
                                                  const int* __restrict__ rowptr,
                                                  const int* __restrict__ col,
                                                  float* __restrict__ out) {
    int node = blockIdx.x * 4 + (threadIdx.x >> 6);
    int lane = threadIdx.x & 63;
    if (node >= NT) return;
    int p0 = rowptr[node], p1 = rowptr[node + 1];
    float acc = 0.f;
    if (lane < DIN) acc = x[(size_t)node * DIN + lane];
    for (int j = p0; j < p1; ++j) {
        int s = col[j];
        if (lane < DIN) acc += x[(size_t)s * DIN + lane];
    }
    if (lane < DIN) out[(size_t)node * DIN + lane] = acc;
}

// ------------------------------------- GEMM [NT,20]@[20,512]+relu -> bf16 out
__global__ __launch_bounds__(256) void k_gemm20(const float* __restrict__ A,
                                                const float* __restrict__ W,
                                                const float* __restrict__ bias,
                                                unsigned short* __restrict__ C) {
    __shared__ float Ws[DIN][128];
    __shared__ float As[64][DIN + 1];
    int t = threadIdx.x;
    int row0 = blockIdx.x * 64;
    int col0 = blockIdx.y * 128;
    for (int i = t; i < DIN * 128; i += 256) {
        int k = i >> 7, c = i & 127;
        Ws[k][c] = W[k * DD + col0 + c];
    }
    for (int i = t; i < 64 * DIN; i += 256) {
        int r = i / DIN, k = i % DIN;
        int rr = row0 + r;
        if (rr >= NT) rr = NT - 1;
        As[r][k] = A[(size_t)rr * DIN + k];
    }
    __syncthreads();
    int c4 = (t & 31) * 4;
    int r0 = (t >> 5) * 8;
    float acc[8][4];
#pragma unroll
    for (int i = 0; i < 8; i++)
#pragma unroll
        for (int j = 0; j < 4; j++) acc[i][j] = 0.f;
    for (int k = 0; k < DIN; k++) {
        float4 b = *(const float4*)&Ws[k][c4];
#pragma unroll
        for (int i = 0; i < 8; i++) {
            float a = As[r0 + i][k];
            acc[i][0] += a * b.x; acc[i][1] += a * b.y;
            acc[i][2] += a * b.z; acc[i][3] += a * b.w;
        }
    }
    float4 bb = *(const float4*)&bias[col0 + c4];
#pragma unroll
    for (int i = 0; i < 8; i++) {
        int r = row0 + r0 + i;
        if (r < NT) {
            short4 o;
            o.x = (short)f2b(fmaxf(acc[i][0] + bb.x, 0.f));
            o.y = (short)f2b(fmaxf(acc[i][1] + bb.y, 0.f));
            o.z = (short)f2b(fmaxf(acc[i][2] + bb.z, 0.f));
            o.w = (short)f2b(fmaxf(acc[i][3] + bb.w, 0.f));
            *(short4*)&C[(size_t)r * DD + col0 + c4] = o;
        }
    }
}

// ------------------------------- MFMA GEMM [M,512](bf16) @ Wt[512,512](bf16^T)
// Block = 64 rows x 512 cols. A staged in LDS ONCE; 4 col-tiles sequential.
// 4 waves, wave w owns rows [w*16, w*16+16). acc[8] = 8 col frags of 16.
// MODE: 0 = bf16 out + bias; 1 = + relu; 2 = no bias + a_s/a_d epilogue (GAT)
template <int MODE>
__global__ __launch_bounds__(256) void k_gemm_mfma(
    const unsigned short* __restrict__ A, const unsigned short* __restrict__ Wt,
    const float* __restrict__ bias, unsigned short* __restrict__ Cb,
    const float* __restrict__ att_s, const float* __restrict__ att_d,
    float* __restrict__ as_o, float* __restrict__ ad_o, int M) {
    __shared__ unsigned short Al[64][520];    // 66560 B, row stride 1040B (16-mult)
    __shared__ unsigned short Bl[128 * 40];   // 10240 B; reused as [32][136] C staging
    __shared__ float s_att[2 * 64];           // MODE 2 only

    int t = threadIdx.x;
    int lane = t & 63;
    int w = t >> 6;
    int row0 = blockIdx.x * 64;

    // ---- stage A once: 4096 int4, 16 per thread, coalesced
#pragma unroll
    for (int i = 0; i < 16; i++) {
        int idx = i * 256 + t;
        int row = idx >> 6, kp = idx & 63;       // 64 int4 per row
        int rA = row0 + row;
        if (rA >= M) rA = M - 1;
        int4 v = *(const int4*)&A[(size_t)rA * DD + kp * 8];
        *(int4*)&Al[row][kp * 8] = v;
    }

    f32x4 acc[8];
#pragma unroll
    for (int j = 0; j < 8; j++) acc[j] = (f32x4){0.f, 0.f, 0.f, 0.f};

    int4 pb[2];
    int brow = t >> 1;
    int pbase = (t & 1) * 2;
    auto issueB = [&](int s) {    // stage s: ct = s>>4, k0 = (s&15)*32
        int ct = s >> 4, k0 = (s & 15) * 32;
#pragma unroll
        for (int i = 0; i < 2; i++)
            pb[i] = *(const int4*)&Wt[(size_t)(ct * 128 + brow) * DD + k0 +
                                      (pbase + i) * 8];
    };

    auto epilogue = [&](int ct) {
        __syncthreads();                         // Bl reads of last stage done
        unsigned short* st = Bl;                 // reuse as [32][136]
        float bv[8], fa[8], fd[8];
#pragma unroll
        for (int j = 0; j < 8; j++) {
            int c = j * 16 + (lane & 15);
            if (MODE == 2) {
                fa[j] = att_s[ct * CH + c];
                fd[j] = att_d[ct * CH + c];
            } else {
                bv[j] = bias[ct * 128 + c];
            }
        }
        if (MODE == 2) {
            if (t < 128) s_att[t] = 0.f;
            __syncthreads();
        }
#pragma unroll
        for (int h = 0; h < 2; h++) {
            if ((w >> 1) == h) {
                int lr0 = (w & 1) * 16 + (lane >> 4) * 4;  // local row in half
#pragma unroll
                for (int r = 0; r < 4; r++) {
#pragma unroll
                    for (int j = 0; j < 8; j++) {
                        float v = acc[j][r];
                        if (MODE != 2) {
                            v += bv[j];
                            if (MODE == 1) v = fmaxf(v, 0.f);
                        }
                        st[(lr0 + r) * 136 + j * 16 + (lane & 15)] = f2b(v);
                    }
                }
            }
            if (MODE == 2 && h == 0) {           // attention partials, once
                int lrow = w * 16 + (lane >> 4) * 4;
#pragma unroll
                for (int r = 0; r < 4; r++) {
                    float ss = 0.f, sd = 0.f;
#pragma unroll
                    for (int j = 0; j < 8; j++) {
                        ss += acc[j][r] * fa[j];
                        sd += acc[j][r] * fd[j];
                    }
                    atomicAdd(&s_att[lrow + r], ss);
                    atomicAdd(&s_att[64 + lrow + r], sd);
                }
            }
            __syncthreads();
            // coalesced readout: 32 rows x 256B
#pragma unroll
            for (int i = 0; i < 2; i++) {
                int idx = i * 256 + t;
                int lr = idx >> 4, seg = idx & 15;
                int grow = row0 + h * 32 + lr;
                if (grow < M) {
                    int4 v = *(const int4*)&st[lr * 136 + seg * 8];
                    *(int4*)&Cb[(size_t)grow * DD + ct * 128 + seg * 8] = v;
                }
            }
            __syncthreads();
        }
        if (MODE == 2) {
            if (t < 64) {
                int grow = row0 + t;
                if (grow < M) {
                    as_o[grow * NH + ct] = s_att[t];
                    ad_o[grow * NH + ct] = s_att[64 + t];
                }
            }
        }
#pragma unroll
        for (int j = 0; j < 8; j++) acc[j] = (f32x4){0.f, 0.f, 0.f, 0.f};
    };

    issueB(0);
    int arow = w * 16 + (lane & 15);
    int koff = (lane >> 4) * 8;

    for (int s = 0; s < 64; ++s) {
        if ((s & 15) == 0 && s > 0) epilogue((s >> 4) - 1);
        __syncthreads();          // prev-stage Bl reads done (or A stage done)
        {                          // write prefetched B chunk to LDS
#pragma unroll
            for (int i = 0; i < 2; i++)
                *(int4*)&Bl[brow * 40 + (pbase + i) * 8] = pb[i];
        }
        __syncthreads();
        if (s < 63) issueB(s + 1);
        int k0 = (s & 15) * 32;
        bf16x8 am = *(const bf16x8*)&Al[arow][k0 + koff];
#pragma unroll
        for (int j = 0; j < 8; j++) {
            bf16x8 bn = *(const bf16x8*)&Bl[((lane & 15) + j * 16) * 40 + koff];
            acc[j] = __builtin_amdgcn_mfma_f32_16x16x32_bf16(am, bn, acc[j],
                                                             0, 0, 0);
        }
    }
    epilogue(3);
}

// --------------------------- BatchNorm over bf16, two branch segments
__global__ __launch_bounds__(256) void k_bn_stats2b(const unsigned short* __restrict__ h,
                                                    float* __restrict__ sums) {
    int t = threadIdx.x;                 // channels 2t, 2t+1
    float sa[2] = {0.f, 0.f}, qa[2] = {0.f, 0.f};
    float sb[2] = {0.f, 0.f}, qb[2] = {0.f, 0.f};
    for (int r = blockIdx.x; r < NT; r += gridDim.x) {
        unsigned u = ((const unsigned*)(h + (size_t)r * DD))[t];
        float va = b2f((unsigned short)(u & 0xffff));
        float vb = b2f((unsigned short)(u >> 16));
        int seg = (r >= N1);
        sa[seg] += va; qa[seg] += va * va;
        sb[seg] += vb; qb[seg] += vb * vb;
    }
    int c = 2 * t;
#pragma unroll
    for (int seg = 0; seg < 2; ++seg) {
        atomicAdd(&sums[seg * DD + c], sa[seg]);
        atomicAdd(&sums[seg * DD + c + 1], sb[seg]);
        atomicAdd(&sums[2 * DD + seg * DD + c], qa[seg]);
        atomicAdd(&sums[2 * DD + seg * DD + c + 1], qb[seg]);
    }
}

__global__ __launch_bounds__(512) void k_bn_fin2(const float* __restrict__ sums,
                                                 const float* __restrict__ g,
                                                 const float* __restrict__ b,
                                                 float* __restrict__ sc) {
    int c = threadIdx.x;
#pragma unroll
    for (int seg = 0; seg < 2; ++seg) {
        float mean = sums[seg * DD + c] / (float)N1;
        float var = sums[2 * DD + seg * DD + c] / (float)N1 - mean * mean;
        float rs = rsqrtf(var + BN_EPS);
        float s = g[c] * rs;
        sc[seg * DD + c] = s;
        sc[2 * DD + seg * DD + c] = b[c] - mean * s;
    }
}

// BN apply + relu, in-place on bf16 buffer
__global__ __launch_bounds__(256) void k_bn_apply_ip(unsigned short* __restrict__ h,
                                                     const float* __restrict__ sc) {
    int total = NT * (DD / 8);
    for (int i = blockIdx.x * blockDim.x + threadIdx.x; i < total;
         i += gridDim.x * blockDim.x) {
        int4 v = ((int4*)h)[i];
        unsigned short* u = (unsigned short*)&v;
        int row = i >> 6;
        int seg = (row >= N1);
        int c = (i & 63) * 8;
        const float* scale = sc + seg * DD;
        const float* shift = sc + 2 * DD + seg * DD;
#pragma unroll
        for (int k = 0; k < 8; k++) {
            float f = b2f(u[k]) * scale[c + k] + shift[c + k];
            u[k] = f2b(fmaxf(f, 0.f));
        }
        ((int4*)h)[i] = v;
    }
}

// ------------------------------------------- D=512 neighborhood sum (bf16 io)
__global__ __launch_bounds__(256) void k_agg512b(const unsigned short* __restrict__ h,
                                                 const int* __restrict__ rowptr,
                                                 const int* __restrict__ col,
                                                 unsigned short* __restrict__ out) {
    int node = blockIdx.x * 4 + (threadIdx.x >> 6);
    int lane = threadIdx.x & 63;
    if (node >= NT) return;
    size_t base = (size_t)node * DD + lane * 8;
    float acc[8];
    {
        int4 v = *(const int4*)&h[base];
        const unsigned short* u = (const unsigned short*)&v;
#pragma unroll
        for (int i = 0; i < 8; i++) acc[i] = b2f(u[i]);
    }
    int p0 = rowptr[node], p1 = rowptr[node + 1];
    int j = p0;
    for (; j + 1 < p1; j += 2) {
        int s0 = col[j], s1 = col[j + 1];
        int4 v0 = *(const int4*)&h[(size_t)s0 * DD + lane * 8];
        int4 v1 = *(const int4*)&h[(size_t)s1 * DD + lane * 8];
        const unsigned short* u0 = (const unsigned short*)&v0;
        const unsigned short* u1 = (const unsigned short*)&v1;
#pragma unroll
        for (int i = 0; i < 8; i++) acc[i] += b2f(u0[i]) + b2f(u1[i]);
    }
    if (j < p1) {
        int4 v0 = *(const int4*)&h[(size_t)col[j] * DD + lane * 8];
        const unsigned short* u0 = (const unsigned short*)&v0;
#pragma unroll
        for (int i = 0; i < 8; i++) acc[i] += b2f(u0[i]);
    }
    int4 o;
    unsigned short* uo = (unsigned short*)&o;
#pragma unroll
    for (int i = 0; i < 8; i++) uo[i] = f2b(acc[i]);
    *(int4*)&out[base] = o;
}

// ------- GAT gather: inline softmax weights, bf16 per-node output
__global__ __launch_bounds__(256) void k_gat_gather(
    const unsigned short* __restrict__ hh, const float* __restrict__ a_s,
    const float* __restrict__ a_d, const int* __restrict__ rowptr,
    const int* __restrict__ col, unsigned short* __restrict__ outB) {
    int node = blockIdx.x * 4 + (threadIdx.x >> 6);
    int lane = threadIdx.x & 63;
    if (node >= NT) return;
    int h = lane >> 4;
    int idx4 = node * NH + h;
    float adi = a_d[idx4];
    float e = a_s[idx4] + adi;
    e = (e > 0.f) ? e : 0.2f * e;
    float ws = __expf(e);
    float den = ws;
    float acc[8];
    {
        int4 v = *(const int4*)&hh[(size_t)node * DD + lane * 8];
        const unsigned short* u = (const unsigned short*)&v;
#pragma unroll
        for (int i = 0; i < 8; i++) acc[i] = ws * b2f(u[i]);
    }
    int p0 = rowptr[node], p1 = rowptr[node + 1];
    int j = p0;
    for (; j + 1 < p1; j += 2) {
        int s0 = col[j], s1 = col[j + 1];
        float e0 = a_s[s0 * NH + h] + adi;
        float e1 = a_s[s1 * NH + h] + adi;
        e0 = (e0 > 0.f) ? e0 : 0.2f * e0;
        e1 = (e1 > 0.f) ? e1 : 0.2f * e1;
        float w0 = __expf(e0), w1 = __expf(e1);
        int4 v0 = *(const int4*)&hh[(size_t)s0 * DD + lane * 8];
        int4 v1 = *(const int4*)&hh[(size_t)s1 * DD + lane * 8];
        const unsigned short* u0 = (const unsigned short*)&v0;
        const unsigned short* u1 = (const unsigned short*)&v1;
#pragma unroll
        for (int i = 0; i < 8; i++) acc[i] += w0 * b2f(u0[i]) + w1 * b2f(u1[i]);
        den += w0 + w1;
    }
    if (j < p1) {
        int s0 = col[j];
        float e0 = a_s[s0 * NH + h] + adi;
        e0 = (e0 > 0.f) ? e0 : 0.2f * e0;
        float w0 = __expf(e0);
        int4 v0 = *(const int4*)&hh[(size_t)s0 * DD + lane * 8];
        const unsigned short* u0 = (const unsigned short*)&v0;
#pragma unroll
        for (int i = 0; i < 8; i++) acc[i] += w0 * b2f(u0[i]);
        den += w0;
    }
    float inv = 1.f / den;
    int4 o;
    unsigned short* uo = (unsigned short*)&o;
#pragma unroll
    for (int i = 0; i < 8; i++) uo[i] = f2b(acc[i] * inv);
    *(int4*)&outB[(size_t)node * DD + lane * 8] = o;
}

// ------------------------- two-stage segmented add-pool (sorted merged batch)
__device__ inline void graph_range(const int* __restrict__ bm, int g,
                                   int& start, int& end) {
    int lo = 0, hi = NT;
    while (lo < hi) { int m = (lo + hi) >> 1; if (bm[m] < g) lo = m + 1; else hi = m; }
    start = lo;
    hi = NT;
    while (lo < hi) { int m = (lo + hi) >> 1; if (bm[m] < g + 1) lo = m + 1; else hi = m; }
    end = lo;
}

__global__ __launch_bounds__(256) void k_pool1(const unsigned short* __restrict__ gatout,
                                               const int* __restrict__ bm,
                                               float* __restrict__ partial) {
    int g = blockIdx.x;
    int s = blockIdx.y;
    int t = threadIdx.x;                 // channels 2t, 2t+1
    int start, end;
    graph_range(bm, g, start, end);
    float a0 = 0.f, a1 = 0.f;
    for (int n = start + s; n < end; n += PSPLIT) {
        unsigned u = ((const unsigned*)(gatout + (size_t)n * DD))[t];
        a0 += b2f((unsigned short)(u & 0xffff));
        a1 += b2f((unsigned short)(u >> 16));
    }
    float* p = partial + ((size_t)g * PSPLIT + s) * DD;
    p[2 * t] = a0;
    p[2 * t + 1] = a1;
}

__global__ __launch_bounds__(512) void k_pool2(const float* __restrict__ partial,
                                               const int* __restrict__ bm,
                                               const float* __restrict__ bias,
                                               float* __restrict__ pool) {
    int g = blockIdx.x;
    int c = threadIdx.x;
    int start, end;
    graph_range(bm, g, start, end);
    float acc = 0.f;
#pragma unroll
    for (int s = 0; s < PSPLIT; ++s)
        acc += partial[((size_t)g * PSPLIT + s) * DD + c];
    pool[g * DD + c] = acc + (float)(end - start) * bias[c];
}

// ------------------------------------------------------------------- fc head
__global__ __launch_bounds__(256) void k_fc1(const float* __restrict__ gin,
                                             const float* __restrict__ W,
                                             const float* __restrict__ bias,
                                             float* __restrict__ out) {
    __shared__ float row[DD];
    int g = blockIdx.x;
    int t = threadIdx.x;
    row[t] = gin[g * DD + t];
    row[t + 256] = gin[g * DD + t + 256];
    __syncthreads();
    for (int cc = 0; cc < 2; ++cc) {
        int c = t + cc * 256;
        float acc = 0.f;
        for (int k = 0; k < DD; k++) acc += row[k] * W[k * DD + c];
        out[g * DD + c] = acc + bias[c];
    }
}

__global__ __launch_bounds__(512) void k_bn64_2(float* __restrict__ h,
                                                const float* __restrict__ g_,
                                                const float* __restrict__ b_) {
    int c = threadIdx.x;
#pragma unroll
    for (int seg = 0; seg < 2; ++seg) {
        float s = 0.f, q = 0.f;
        for (int r = 0; r < NG; r++) {
            float v = h[(seg * NG + r) * DD + c];
            s += v; q += v * v;
        }
        float mean = s / (float)NG;
        float var = q / (float)NG - mean * mean;
        float rs = rsqrtf(var + BN_EPS);
        float sc = g_[c] * rs, sh = b_[c] - mean * sc;
        for (int r = 0; r < NG; r++) {
            float v = h[(seg * NG + r) * DD + c];
            h[(seg * NG + r) * DD + c] = fmaxf(v * sc + sh, 0.f);
        }
    }
}

__global__ __launch_bounds__(128) void k_fc2(const float* __restrict__ h,
                                             const float* __restrict__ W,
                                             const float* __restrict__ bias,
                                             float* __restrict__ out) {
    __shared__ float row[DD];
    int g = blockIdx.x;
    int t = threadIdx.x;
    for (int i = t; i < DD; i += 128) row[i] = h[g * DD + i];
    __syncthreads();
    float acc = 0.f;
    for (int k = 0; k < DD; k++) acc += row[k] * W[k * NHID + t];
    out[g * NHID + t] = acc + bias[t];
}

// ------------------------------------------------------------------ regressor
__global__ __launch_bounds__(128) void k_reg(const float* __restrict__ gout,
                                             const float* __restrict__ W1,
                                             const float* __restrict__ b1,
                                             const float* __restrict__ W2,
                                             const float* __restrict__ b2,
                                             float* __restrict__ out) {
    __shared__ float x[256];
    __shared__ float red[128];
    int g = blockIdx.x;
    int t = threadIdx.x;
    x[t] = gout[g * NHID + t];
    x[t + 128] = gout[(NG + g) * NHID + t];
    __syncthreads();
    float acc = b1[t];
    for (int k = 0; k < 256; k++) acc += x[k] * W1[k * NHID + t];
    acc = fmaxf(acc, 0.f);
    red[t] = acc * W2[t];
    __syncthreads();
    for (int off = 64; off; off >>= 1) {
        if (t < off) red[t] += red[t + off];
        __syncthreads();
    }
    if (t == 0) out[g] = red[0] + b2[0];
}

// ==================================================================== launch
extern "C" void kernel_launch(void* const* d_in, const int* in_sizes, int n_in,
                              void* d_out, int out_size, void* d_ws, size_t ws_size,
                              hipStream_t stream) {
    const float* wl_x = (const float*)d_in[0];
    const float* mt_x = (const float*)d_in[1];
    const int* wl_ei = (const int*)d_in[2];
    const int* mt_ei = (const int*)d_in[3];
    const int* wl_batch = (const int*)d_in[4];
    const int* mt_batch = (const int*)d_in[5];
    const float* gin1_W1 = (const float*)d_in[6];
    const float* gin1_b1 = (const float*)d_in[7];
    const float* gin1_W2 = (const float*)d_in[8];
    const float* gin1_b2 = (const float*)d_in[9];
    const float* bn1_g = (const float*)d_in[10];
    const float* bn1_b = (const float*)d_in[11];
    const float* gin2_W1 = (const float*)d_in[12];
    const float* gin2_b1 = (const float*)d_in[13];
    const float* gin2_W2 = (const float*)d_in[14];
    const float* gin2_b2 = (const float*)d_in[15];
    const float* bn2_g = (const float*)d_in[16];
    const float* bn2_b = (const float*)d_in[17];
    const float* gat_W = (const float*)d_in[18];
    const float* gat_as = (const float*)d_in[19];
    const float* gat_ad = (const float*)d_in[20];
    const float* gat_bias = (const float*)d_in[21];
    const float* fc_W1 = (const float*)d_in[22];
    const float* fc_b1 = (const float*)d_in[23];
    const float* fc_bn_g = (const float*)d_in[24];
    const float* fc_bn_b = (const float*)d_in[25];
    const float* fc_W2 = (const float*)d_in[26];
    const float* fc_b2 = (const float*)d_in[27];
    const float* reg_W1 = (const float*)d_in[28];
    const float* reg_b1 = (const float*)d_in[29];
    const float* reg_W2 = (const float*)d_in[30];
    const float* reg_b2 = (const float*)d_in[31];
    float* out = (float*)d_out;

    char* ws = (char*)d_ws;
    size_t o = 0;
    auto alloc = [&](size_t bytes) {
        size_t r = o;
        o = (o + bytes + 255) & ~(size_t)255;
        return r;
    };
    unsigned short* hbA = (unsigned short*)(ws + alloc((size_t)NT * DD * 2)); // 61.4 MB
    unsigned short* hbB = (unsigned short*)(ws + alloc((size_t)NT * DD * 2)); // 61.4 MB
    float* xm = (float*)(ws + alloc((size_t)NT * DIN * 4));
    float* bufA = (float*)(ws + alloc((size_t)NT * DIN * 4));
    int* bm = (int*)(ws + alloc((size_t)NT * 4));
    int* cnt = (int*)(ws + alloc((size_t)NT * 4));
    int* rowptr = (int*)(ws + alloc((size_t)(NT + 1) * 4));
    int* cursor = (int*)(ws + alloc((size_t)NT * 4));
    int* colidx = (int*)(ws + alloc((size_t)2 * E1 * 4));
    float* a_s = (float*)(ws + alloc((size_t)NT * NH * 4));
    float* a_d = (float*)(ws + alloc((size_t)NT * NH * 4));
    float* bnsums = (float*)(ws + alloc(4 * DD * 4));
    float* bnsc = (float*)(ws + alloc(4 * DD * 4));
    float* partial = (float*)(ws + alloc((size_t)NGT * PSPLIT * DD * 4));
    float* pool = (float*)(ws + alloc((size_t)NGT * DD * 4));
    float* fch = (float*)(ws + alloc((size_t)NGT * DD * 4));
    float* gout = (float*)(ws + alloc((size_t)NGT * NHID * 4));
    unsigned short* Wt1 = (unsigned short*)(ws + alloc((size_t)DD * DD * 2));
    unsigned short* Wt2 = (unsigned short*)(ws + alloc((size_t)DD * DD * 2));
    unsigned short* Wt3 = (unsigned short*)(ws + alloc((size_t)DD * DD * 2));
    unsigned short* Wt4 = (unsigned short*)(ws + alloc((size_t)DD * DD * 2));
    (void)ws_size; (void)in_sizes; (void)n_in; (void)out_size;

    // one-time per launch: weights + merged inputs
    k_wconv<<<DD, 256, 0, stream>>>(gin1_W2, Wt1);
    k_wconv<<<DD, 256, 0, stream>>>(gin2_W1, Wt2);
    k_wconv<<<DD, 256, 0, stream>>>(gin2_W2, Wt3);
    k_wconv<<<DD, 256, 0, stream>>>(gat_W, Wt4);
    k_xmerge<<<(NT * DIN + 255) / 256, 256, 0, stream>>>(wl_x, mt_x, xm);
    k_bmerge<<<(NT + 255) / 256, 256, 0, stream>>>(wl_batch, mt_batch, bm);

    // merged CSR (mt node ids offset by N1)
    hipMemsetAsync(cnt, 0, (size_t)NT * 4, stream);
    k_hist2<<<512, 256, 0, stream>>>(wl_ei + E1, mt_ei + E1, cnt);
    k_scan2<<<1, 512, 0, stream>>>(cnt, rowptr, cursor, NT);
    k_scatter2<<<512, 256, 0, stream>>>(wl_ei, wl_ei + E1, mt_ei, mt_ei + E1,
                                        cursor, colidx);

    int gmm = (NT + 63) / 64;      // 938 blocks, 64 full rows each
    dim3 g20((NT + 63) / 64, 4);

    auto bnpass = [&](unsigned short* buf, const float* g, const float* b) {
        hipMemsetAsync(bnsums, 0, 4 * DD * 4, stream);
        k_bn_stats2b<<<256, 256, 0, stream>>>(buf, bnsums);
        k_bn_fin2<<<1, 512, 0, stream>>>(bnsums, g, b, bnsc);
        k_bn_apply_ip<<<2048, 256, 0, stream>>>(buf, bnsc);
    };

    // GIN1
    k_gin1_agg<<<(NT + 3) / 4, 256, 0, stream>>>(xm, rowptr, colidx, bufA);
    k_gemm20<<<g20, 256, 0, stream>>>(bufA, gin1_W1, gin1_b1, hbA);
    k_gemm_mfma<0><<<gmm, 256, 0, stream>>>(hbA, Wt1, gin1_b2, hbB, nullptr,
                                            nullptr, nullptr, nullptr, NT);
    bnpass(hbB, bn1_g, bn1_b);                       // h1 in hbB

    // GIN2
    k_agg512b<<<(NT + 3) / 4, 256, 0, stream>>>(hbB, rowptr, colidx, hbA);
    k_gemm_mfma<1><<<gmm, 256, 0, stream>>>(hbA, Wt2, gin2_b1, hbB, nullptr,
                                            nullptr, nullptr, nullptr, NT);
    k_gemm_mfma<0><<<gmm, 256, 0, stream>>>(hbB, Wt3, gin2_b2, hbA, nullptr,
                                            nullptr, nullptr, nullptr, NT);
    bnpass(hbA, bn2_g, bn2_b);                       // h2 in hbA

    // GAT (features bf16 -> hbB, logits a_s/a_d from fp32 accumulators)
    k_gemm_mfma<2><<<gmm, 256, 0, stream>>>(hbA, Wt4, nullptr, hbB, gat_as,
                                            gat_ad, a_s, a_d, NT);
    k_gat_gather<<<(NT + 3) / 4, 256, 0, stream>>>(hbB, a_s, a_d, rowptr, colidx,
                                                   hbA);
    k_pool1<<<dim3(NGT, PSPLIT), 256, 0, stream>>>(hbA, bm, partial);
    k_pool2<<<NGT, 512, 0, stream>>>(partial, bm, gat_bias, pool);

    // fc head (both branches at once)
    k_fc1<<<NGT, 256, 0, stream>>>(pool, fc_W1, fc_b1, fch);
    k_bn64_2<<<1, 512, 0, stream>>>(fch, fc_bn_g, fc_bn_b);
    k_fc2<<<NGT, 128, 0, stream>>>(fch, fc_W2, fc_b2, gout);

    k_reg<<<NG, 128, 0, stream>>>(gout, reg_W1, reg_b1, reg_W2, reg_b2, out);
}

// Round 12
// 1416.609 us; speedup vs baseline: 2.4820x; 1.2585x over previous
//
#include <hip/hip_runtime.h>
#include <hip/hip_bf16.h>
#include <math.h>

#define N1     30000          // nodes per branch
#define NT     60000          // merged nodes
#define E1     480000
#define NG     64             // graphs per branch
#define NGT    128            // merged graphs
#define DIN    20
#define DD     512
#define NH     4
#define CH     128
#define NHID   128
#define PSPLIT 8
#define BN_EPS 1e-5f

typedef __attribute__((ext_vector_type(8))) short bf16x8;
typedef __attribute__((ext_vector_type(4))) float f32x4;
typedef __attribute__((address_space(1))) const void cg_void;
typedef __attribute__((address_space(3))) void lds_void;

__device__ inline unsigned short f2b(float f) {
    __hip_bfloat16 h = __float2bfloat16(f);
    return *(unsigned short*)&h;
}
__device__ inline float b2f(unsigned short u) {
    return __uint_as_float(((unsigned)u) << 16);
}

// ------------------------------------------------------------ merge helpers
__global__ __launch_bounds__(256) void k_xmerge(const float* __restrict__ a,
                                                const float* __restrict__ b,
                                                float* __restrict__ xm) {
    int i = blockIdx.x * 256 + threadIdx.x;
    int tot = NT * DIN;
    if (i < tot) xm[i] = (i < N1 * DIN) ? a[i] : b[i - N1 * DIN];
}

__global__ __launch_bounds__(256) void k_bmerge(const int* __restrict__ a,
                                                const int* __restrict__ b,
                                                int* __restrict__ bm) {
    int i = blockIdx.x * 256 + threadIdx.x;
    if (i < NT) bm[i] = (i < N1) ? a[i] : b[i - N1] + NG;
}

// ---------------------------------------------------------------- CSR build
__global__ __launch_bounds__(256) void k_hist2(const int* __restrict__ dwl,
                                               const int* __restrict__ dmt,
                                               int* __restrict__ cnt) {
    for (int e = blockIdx.x * blockDim.x + threadIdx.x; e < E1;
         e += gridDim.x * blockDim.x) {
        atomicAdd(&cnt[dwl[e]], 1);
        atomicAdd(&cnt[dmt[e] + N1], 1);
    }
}

__global__ __launch_bounds__(512) void k_scan2(const int* __restrict__ cnt,
                                               int* __restrict__ rowptr,
                                               int* __restrict__ cursor, int n) {
    __shared__ int sd[512];
    int t = threadIdx.x;
    int per = (n + 511) / 512;
    int lo = t * per, hi = lo + per;
    if (hi > n) hi = n;
    int s = 0;
    for (int i = lo; i < hi; ++i) s += cnt[i];
    sd[t] = s;
    __syncthreads();
    for (int off = 1; off < 512; off <<= 1) {
        int v = (t >= off) ? sd[t - off] : 0;
        __syncthreads();
        sd[t] += v;
        __syncthreads();
    }
    int run = sd[t] - s;
    for (int i = lo; i < hi; ++i) {
        rowptr[i] = run;
        cursor[i] = run;
        run += cnt[i];
    }
    if (t == 511) rowptr[n] = sd[511];
}

__global__ __launch_bounds__(256) void k_scatter2(const int* __restrict__ swl,
                                                  const int* __restrict__ dwl,
                                                  const int* __restrict__ smt,
                                                  const int* __restrict__ dmt,
                                                  int* __restrict__ cursor,
                                                  int* __restrict__ col) {
    for (int e = blockIdx.x * blockDim.x + threadIdx.x; e < E1;
         e += gridDim.x * blockDim.x) {
        int d0 = dwl[e];
        col[atomicAdd(&cursor[d0], 1)] = swl[e];
        int d1 = dmt[e] + N1;
        col[atomicAdd(&cursor[d1], 1)] = smt[e] + N1;
    }
}

// ---------------------------------------------------------- weight conv+transp
__global__ __launch_bounds__(256) void k_wconv(const float* __restrict__ W,
                                               unsigned short* __restrict__ Wt) {
    int n = blockIdx.x;
    for (int k = threadIdx.x; k < DD; k += 256)
        Wt[n * DD + k] = f2b(W[k * DD + n]);
}

// ------------------------------------------------------------- GIN1 agg (20)
__global__ __launch_bounds__(256) void k_gin1_agg(const float* __restrict__ x,
                                                  const int* __restrict__ rowptr,
                                                  const int* __restrict__ col,
                                                  float* __restrict__ out) {
    int node = blockIdx.x * 4 + (threadIdx.x >> 6);
    int lane = threadIdx.x & 63;
    if (node >= NT) return;
    int p0 = rowptr[node], p1 = rowptr[node + 1];
    float acc = 0.f;
    if (lane < DIN) acc = x[(size_t)node * DIN + lane];
    for (int j = p0; j < p1; ++j) {
        int s = col[j];
        if (lane < DIN) acc += x[(size_t)s * DIN + lane];
    }
    if (lane < DIN) out[(size_t)node * DIN + lane] = acc;
}

// ------------------------------------- GEMM [NT,20]@[20,512]+relu -> bf16 out
__global__ __launch_bounds__(256) void k_gemm20(const float* __restrict__ A,
                                                const float* __restrict__ W,
                                                const float* __restrict__ bias,
                                                unsigned short* __restrict__ C) {
    __shared__ float Ws[DIN][128];
    __shared__ float As[64][DIN + 1];
    int t = threadIdx.x;
    int row0 = blockIdx.x * 64;
    int col0 = blockIdx.y * 128;
    for (int i = t; i < DIN * 128; i += 256) {
        int k = i >> 7, c = i & 127;
        Ws[k][c] = W[k * DD + col0 + c];
    }
    for (int i = t; i < 64 * DIN; i += 256) {
        int r = i / DIN, k = i % DIN;
        int rr = row0 + r;
        if (rr >= NT) rr = NT - 1;
        As[r][k] = A[(size_t)rr * DIN + k];
    }
    __syncthreads();
    int c4 = (t & 31) * 4;
    int r0 = (t >> 5) * 8;
    float acc[8][4];
#pragma unroll
    for (int i = 0; i < 8; i++)
#pragma unroll
        for (int j = 0; j < 4; j++) acc[i][j] = 0.f;
    for (int k = 0; k < DIN; k++) {
        float4 b = *(const float4*)&Ws[k][c4];
#pragma unroll
        for (int i = 0; i < 8; i++) {
            float a = As[r0 + i][k];
            acc[i][0] += a * b.x; acc[i][1] += a * b.y;
            acc[i][2] += a * b.z; acc[i][3] += a * b.w;
        }
    }
    float4 bb = *(const float4*)&bias[col0 + c4];
#pragma unroll
    for (int i = 0; i < 8; i++) {
        int r = row0 + r0 + i;
        if (r < NT) {
            short4 o;
            o.x = (short)f2b(fmaxf(acc[i][0] + bb.x, 0.f));
            o.y = (short)f2b(fmaxf(acc[i][1] + bb.y, 0.f));
            o.z = (short)f2b(fmaxf(acc[i][2] + bb.z, 0.f));
            o.w = (short)f2b(fmaxf(acc[i][3] + bb.w, 0.f));
            *(short4*)&C[(size_t)r * DD + col0 + c4] = o;
        }
    }
}

// ------------------------------- MFMA GEMM [M,512](bf16) @ Wt[512,512](bf16^T)
// m97-style: 128x128 tile, BK=64, global_load_lds staging with source-side XOR
// swizzle (slot ^= row&7) so ds_read_b128 fragment reads are conflict-free.
// 4 waves 2x2; wave (wr,wc) owns 64x64 = 4x4 fragments of 16x16x32.
// MODE: 0 = bf16 out + bias; 1 = + relu; 2 = no bias + a_s/a_d epilogue (GAT)
template <int MODE>
__global__ __launch_bounds__(256) void k_gemm_mfma(
    const unsigned short* __restrict__ A, const unsigned short* __restrict__ Wt,
    const float* __restrict__ bias, unsigned short* __restrict__ Cb,
    const float* __restrict__ att_s, const float* __restrict__ att_d,
    float* __restrict__ as_o, float* __restrict__ ad_o, int M) {
    __shared__ unsigned short lds[2 * 128 * 64];   // A | B tiles; reused as st[128][128]
    __shared__ float s_att[2 * 128];               // MODE 2 only
    unsigned short* AsU = lds;                     // [128][64] swizzled
    unsigned short* BsU = lds + 128 * 64;

    int t = threadIdx.x;
    int lane = t & 63;
    int w = t >> 6;
    int wr = w >> 1, wc = w & 1;
    int bid = blockIdx.x;
    int row0 = (bid >> 2) * 128;
    int ct = bid & 3;
    int col0 = ct * 128;

    int l8 = lane >> 3;                 // 0..7 = row within 8-row group
    int swz = (lane & 7) ^ l8;          // source k-slot permutation

    f32x4 acc[4][4];
#pragma unroll
    for (int i = 0; i < 4; i++)
#pragma unroll
        for (int j = 0; j < 4; j++) acc[i][j] = (f32x4){0.f, 0.f, 0.f, 0.f};

    int fr = lane & 15, fq = lane >> 4, f7 = lane & 7;

    for (int s = 0; s < 8; ++s) {
        int k0 = s * 64;
        __syncthreads();                 // prev-step fragment reads done
        // ---- stage A (rows) and B (Wt rows = cols), 8 gload_lds per wave
#pragma unroll
        for (int q = 0; q < 4; q++) {
            int rl = w * 32 + q * 8 + l8;
            int gr = row0 + rl;
            if (gr >= M) gr = M - 1;
            const unsigned short* srcA = A + (size_t)gr * DD + k0 + swz * 8;
            unsigned short* dstA = AsU + (w * 32 + q * 8) * 64;   // wave-uniform
            __builtin_amdgcn_global_load_lds((cg_void*)srcA, (lds_void*)dstA,
                                             16, 0, 0);
            int cl = w * 32 + q * 8 + l8;
            const unsigned short* srcB = Wt + (size_t)(col0 + cl) * DD + k0 +
                                         swz * 8;
            unsigned short* dstB = BsU + (w * 32 + q * 8) * 64;
            __builtin_amdgcn_global_load_lds((cg_void*)srcB, (lds_void*)dstB,
                                             16, 0, 0);
        }
        __syncthreads();                 // vmcnt(0) drained by compiler
        // ---- fragments + MFMA (reads swizzled: slot = ks ^ (row&7))
#pragma unroll
        for (int kk = 0; kk < 2; kk++) {
            bf16x8 am[4], bn[4];
#pragma unroll
            for (int i = 0; i < 4; i++) {
                int row = wr * 64 + i * 16 + fr;        // row&7 == lane&7
                int ks = (kk * 4 + fq) ^ f7;
                am[i] = *(const bf16x8*)&AsU[row * 64 + ks * 8];
            }
#pragma unroll
            for (int j = 0; j < 4; j++) {
                int row = wc * 64 + j * 16 + fr;
                int ks = (kk * 4 + fq) ^ f7;
                bn[j] = *(const bf16x8*)&BsU[row * 64 + ks * 8];
            }
#pragma unroll
            for (int i = 0; i < 4; i++)
#pragma unroll
                for (int j = 0; j < 4; j++)
                    acc[i][j] = __builtin_amdgcn_mfma_f32_16x16x32_bf16(
                        am[i], bn[j], acc[i][j], 0, 0, 0);
        }
    }

    // ---------------- epilogue: LDS-staged coalesced store ----------------
    __syncthreads();                     // all fragment reads done; reuse lds
    unsigned short* st = lds;            // [128][128] ushort = 32KB exactly
    if (MODE == 2) {
        if (t < 128) { s_att[t] = 0.f; s_att[128 + t] = 0.f; }
    }
    __syncthreads();

    float bv[4], fa[4], fd[4];
#pragma unroll
    for (int j = 0; j < 4; j++) {
        int c = wc * 64 + j * 16 + fr;
        if (MODE == 2) {
            fa[j] = att_s[ct * CH + c];
            fd[j] = att_d[ct * CH + c];
        } else {
            bv[j] = bias[col0 + c];
        }
    }
#pragma unroll
    for (int i = 0; i < 4; i++) {
#pragma unroll
        for (int r = 0; r < 4; r++) {
            int lrow = wr * 64 + i * 16 + fq * 4 + r;
            float ss = 0.f, sd = 0.f;
#pragma unroll
            for (int j = 0; j < 4; j++) {
                float v = acc[i][j][r];
                if (MODE != 2) {
                    v += bv[j];
                    if (MODE == 1) v = fmaxf(v, 0.f);
                } else {
                    ss += v * fa[j];
                    sd += v * fd[j];
                }
                st[lrow * 128 + wc * 64 + j * 16 + fr] = f2b(v);
            }
            if (MODE == 2) {
                atomicAdd(&s_att[lrow], ss);
                atomicAdd(&s_att[128 + lrow], sd);
            }
        }
    }
    __syncthreads();
    // coalesced readout: each 16-lane group covers one full 256B row
#pragma unroll
    for (int i = 0; i < 8; i++) {
        int idx = i * 256 + t;
        int row = idx >> 4, seg = idx & 15;
        int grow = row0 + row;
        if (grow < M) {
            int4 v = *(const int4*)&st[row * 128 + seg * 8];
            *(int4*)&Cb[(size_t)grow * DD + col0 + seg * 8] = v;
        }
    }
    if (MODE == 2 && t < 128) {
        int grow = row0 + t;
        if (grow < M) {
            as_o[grow * NH + ct] = s_att[t];
            ad_o[grow * NH + ct] = s_att[128 + t];
        }
    }
}

// --------------------------- BatchNorm over bf16, two branch segments
__global__ __launch_bounds__(256) void k_bn_stats2b(const unsigned short* __restrict__ h,
                                                    float* __restrict__ sums) {
    int t = threadIdx.x;                 // channels 2t, 2t+1
    float sa[2] = {0.f, 0.f}, qa[2] = {0.f, 0.f};
    float sb[2] = {0.f, 0.f}, qb[2] = {0.f, 0.f};
    for (int r = blockIdx.x; r < NT; r += gridDim.x) {
        unsigned u = ((const unsigned*)(h + (size_t)r * DD))[t];
        float va = b2f((unsigned short)(u & 0xffff));
        float vb = b2f((unsigned short)(u >> 16));
        int seg = (r >= N1);
        sa[seg] += va; qa[seg] += va * va;
        sb[seg] += vb; qb[seg] += vb * vb;
    }
    int c = 2 * t;
#pragma unroll
    for (int seg = 0; seg < 2; ++seg) {
        atomicAdd(&sums[seg * DD + c], sa[seg]);
        atomicAdd(&sums[seg * DD + c + 1], sb[seg]);
        atomicAdd(&sums[2 * DD + seg * DD + c], qa[seg]);
        atomicAdd(&sums[2 * DD + seg * DD + c + 1], qb[seg]);
    }
}

__global__ __launch_bounds__(512) void k_bn_fin2(const float* __restrict__ sums,
                                                 const float* __restrict__ g,
                                                 const float* __restrict__ b,
                                                 float* __restrict__ sc) {
    int c = threadIdx.x;
#pragma unroll
    for (int seg = 0; seg < 2; ++seg) {
        float mean = sums[seg * DD + c] / (float)N1;
        float var = sums[2 * DD + seg * DD + c] / (float)N1 - mean * mean;
        float rs = rsqrtf(var + BN_EPS);
        float s = g[c] * rs;
        sc[seg * DD + c] = s;
        sc[2 * DD + seg * DD + c] = b[c] - mean * s;
    }
}

// BN apply + relu, in-place on bf16 buffer
__global__ __launch_bounds__(256) void k_bn_apply_ip(unsigned short* __restrict__ h,
                                                     const float* __restrict__ sc) {
    int total = NT * (DD / 8);
    for (int i = blockIdx.x * blockDim.x + threadIdx.x; i < total;
         i += gridDim.x * blockDim.x) {
        int4 v = ((int4*)h)[i];
        unsigned short* u = (unsigned short*)&v;
        int row = i >> 6;
        int seg = (row >= N1);
        int c = (i & 63) * 8;
        const float* scale = sc + seg * DD;
        const float* shift = sc + 2 * DD + seg * DD;
#pragma unroll
        for (int k = 0; k < 8; k++) {
            float f = b2f(u[k]) * scale[c + k] + shift[c + k];
            u[k] = f2b(fmaxf(f, 0.f));
        }
        ((int4*)h)[i] = v;
    }
}

// ------------------------------------------- D=512 neighborhood sum (bf16 io)
__global__ __launch_bounds__(256) void k_agg512b(const unsigned short* __restrict__ h,
                                                 const int* __restrict__ rowptr,
                                                 const int* __restrict__ col,
                                                 unsigned short* __restrict__ out) {
    int node = blockIdx.x * 4 + (threadIdx.x >> 6);
    int lane = threadIdx.x & 63;
    if (node >= NT) return;
    size_t base = (size_t)node * DD + lane * 8;
    float acc[8];
    {
        int4 v = *(const int4*)&h[base];
        const unsigned short* u = (const unsigned short*)&v;
#pragma unroll
        for (int i = 0; i < 8; i++) acc[i] = b2f(u[i]);
    }
    int p0 = rowptr[node], p1 = rowptr[node + 1];
    int j = p0;
    for (; j + 1 < p1; j += 2) {
        int s0 = col[j], s1 = col[j + 1];
        int4 v0 = *(const int4*)&h[(size_t)s0 * DD + lane * 8];
        int4 v1 = *(const int4*)&h[(size_t)s1 * DD + lane * 8];
        const unsigned short* u0 = (const unsigned short*)&v0;
        const unsigned short* u1 = (const unsigned short*)&v1;
#pragma unroll
        for (int i = 0; i < 8; i++) acc[i] += b2f(u0[i]) + b2f(u1[i]);
    }
    if (j < p1) {
        int4 v0 = *(const int4*)&h[(size_t)col[j] * DD + lane * 8];
        const unsigned short* u0 = (const unsigned short*)&v0;
#pragma unroll
        for (int i = 0; i < 8; i++) acc[i] += b2f(u0[i]);
    }
    int4 o;
    unsigned short* uo = (unsigned short*)&o;
#pragma unroll
    for (int i = 0; i < 8; i++) uo[i] = f2b(acc[i]);
    *(int4*)&out[base] = o;
}

// ------- GAT gather: inline softmax weights, bf16 per-node output
__global__ __launch_bounds__(256) void k_gat_gather(
    const unsigned short* __restrict__ hh, const float* __restrict__ a_s,
    const float* __restrict__ a_d, const int* __restrict__ rowptr,
    const int* __restrict__ col, unsigned short* __restrict__ outB) {
    int node = blockIdx.x * 4 + (threadIdx.x >> 6);
    int lane = threadIdx.x & 63;
    if (node >= NT) return;
    int h = lane >> 4;
    int idx4 = node * NH + h;
    float adi = a_d[idx4];
    float e = a_s[idx4] + adi;
    e = (e > 0.f) ? e : 0.2f * e;
    float ws = __expf(e);
    float den = ws;
    float acc[8];
    {
        int4 v = *(const int4*)&hh[(size_t)node * DD + lane * 8];
        const unsigned short* u = (const unsigned short*)&v;
#pragma unroll
        for (int i = 0; i < 8; i++) acc[i] = ws * b2f(u[i]);
    }
    int p0 = rowptr[node], p1 = rowptr[node + 1];
    int j = p0;
    for (; j + 1 < p1; j += 2) {
        int s0 = col[j], s1 = col[j + 1];
        float e0 = a_s[s0 * NH + h] + adi;
        float e1 = a_s[s1 * NH + h] + adi;
        e0 = (e0 > 0.f) ? e0 : 0.2f * e0;
        e1 = (e1 > 0.f) ? e1 : 0.2f * e1;
        float w0 = __expf(e0), w1 = __expf(e1);
        int4 v0 = *(const int4*)&hh[(size_t)s0 * DD + lane * 8];
        int4 v1 = *(const int4*)&hh[(size_t)s1 * DD + lane * 8];
        const unsigned short* u0 = (const unsigned short*)&v0;
        const unsigned short* u1 = (const unsigned short*)&v1;
#pragma unroll
        for (int i = 0; i < 8; i++) acc[i] += w0 * b2f(u0[i]) + w1 * b2f(u1[i]);
        den += w0 + w1;
    }
    if (j < p1) {
        int s0 = col[j];
        float e0 = a_s[s0 * NH + h] + adi;
        e0 = (e0 > 0.f) ? e0 : 0.2f * e0;
        float w0 = __expf(e0);
        int4 v0 = *(const int4*)&hh[(size_t)s0 * DD + lane * 8];
        const unsigned short* u0 = (const unsigned short*)&v0;
#pragma unroll
        for (int i = 0; i < 8; i++) acc[i] += w0 * b2f(u0[i]);
        den += w0;
    }
    float inv = 1.f / den;
    int4 o;
    unsigned short* uo = (unsigned short*)&o;
#pragma unroll
    for (int i = 0; i < 8; i++) uo[i] = f2b(acc[i] * inv);
    *(int4*)&outB[(size_t)node * DD + lane * 8] = o;
}

// ------------------------- two-stage segmented add-pool (sorted merged batch)
__device__ inline void graph_range(const int* __restrict__ bm, int g,
                                   int& start, int& end) {
    int lo = 0, hi = NT;
    while (lo < hi) { int m = (lo + hi) >> 1; if (bm[m] < g) lo = m + 1; else hi = m; }
    start = lo;
    hi = NT;
    while (lo < hi) { int m = (lo + hi) >> 1; if (bm[m] < g + 1) lo = m + 1; else hi = m; }
    end = lo;
}

__global__ __launch_bounds__(256) void k_pool1(const unsigned short* __restrict__ gatout,
                                               const int* __restrict__ bm,
                                               float* __restrict__ partial) {
    int g = blockIdx.x;
    int s = blockIdx.y;
    int t = threadIdx.x;                 // channels 2t, 2t+1
    int start, end;
    graph_range(bm, g, start, end);
    float a0 = 0.f, a1 = 0.f;
    for (int n = start + s; n < end; n += PSPLIT) {
        unsigned u = ((const unsigned*)(gatout + (size_t)n * DD))[t];
        a0 += b2f((unsigned short)(u & 0xffff));
        a1 += b2f((unsigned short)(u >> 16));
    }
    float* p = partial + ((size_t)g * PSPLIT + s) * DD;
    p[2 * t] = a0;
    p[2 * t + 1] = a1;
}

__global__ __launch_bounds__(512) void k_pool2(const float* __restrict__ partial,
                                               const int* __restrict__ bm,
                                               const float* __restrict__ bias,
                                               float* __restrict__ pool) {
    int g = blockIdx.x;
    int c = threadIdx.x;
    int start, end;
    graph_range(bm, g, start, end);
    float acc = 0.f;
#pragma unroll
    for (int s = 0; s < PSPLIT; ++s)
        acc += partial[((size_t)g * PSPLIT + s) * DD + c];
    pool[g * DD + c] = acc + (float)(end - start) * bias[c];
}

// ------------------------------------------------------------------- fc head
__global__ __launch_bounds__(256) void k_fc1(const float* __restrict__ gin,
                                             const float* __restrict__ W,
                                             const float* __restrict__ bias,
                                             float* __restrict__ out) {
    __shared__ float row[DD];
    int g = blockIdx.x;
    int t = threadIdx.x;
    row[t] = gin[g * DD + t];
    row[t + 256] = gin[g * DD + t + 256];
    __syncthreads();
    for (int cc = 0; cc < 2; ++cc) {
        int c = t + cc * 256;
        float acc = 0.f;
        for (int k = 0; k < DD; k++) acc += row[k] * W[k * DD + c];
        out[g * DD + c] = acc + bias[c];
    }
}

__global__ __launch_bounds__(512) void k_bn64_2(float* __restrict__ h,
                                                const float* __restrict__ g_,
                                                const float* __restrict__ b_) {
    int c = threadIdx.x;
#pragma unroll
    for (int seg = 0; seg < 2; ++seg) {
        float s = 0.f, q = 0.f;
        for (int r = 0; r < NG; r++) {
            float v = h[(seg * NG + r) * DD + c];
            s += v; q += v * v;
        }
        float mean = s / (float)NG;
        float var = q / (float)NG - mean * mean;
        float rs = rsqrtf(var + BN_EPS);
        float sc = g_[c] * rs, sh = b_[c] - mean * sc;
        for (int r = 0; r < NG; r++) {
            float v = h[(seg * NG + r) * DD + c];
            h[(seg * NG + r) * DD + c] = fmaxf(v * sc + sh, 0.f);
        }
    }
}

__global__ __launch_bounds__(128) void k_fc2(const float* __restrict__ h,
                                             const float* __restrict__ W,
                                             const float* __restrict__ bias,
                                             float* __restrict__ out) {
    __shared__ float row[DD];
    int g = blockIdx.x;
    int t = threadIdx.x;
    for (int i = t; i < DD; i += 128) row[i] = h[g * DD + i];
    __syncthreads();
    float acc = 0.f;
    for (int k = 0; k < DD; k++) acc += row[k] * W[k * NHID + t];
    out[g * NHID + t] = acc + bias[t];
}

// ------------------------------------------------------------------ regressor
__global__ __launch_bounds__(128) void k_reg(const float* __restrict__ gout,
                                             const float* __restrict__ W1,
                                             const float* __restrict__ b1,
                                             const float* __restrict__ W2,
                                             const float* __restrict__ b2,
                                             float* __restrict__ out) {
    __shared__ float x[256];
    __shared__ float red[128];
    int g = blockIdx.x;
    int t = threadIdx.x;
    x[t] = gout[g * NHID + t];
    x[t + 128] = gout[(NG + g) * NHID + t];
    __syncthreads();
    float acc = b1[t];
    for (int k = 0; k < 256; k++) acc += x[k] * W1[k * NHID + t];
    acc = fmaxf(acc, 0.f);
    red[t] = acc * W2[t];
    __syncthreads();
    for (int off = 64; off; off >>= 1) {
        if (t < off) red[t] += red[t + off];
        __syncthreads();
    }
    if (t == 0) out[g] = red[0] + b2[0];
}

// ==================================================================== launch
extern "C" void kernel_launch(void* const* d_in, const int* in_sizes, int n_in,
                              void* d_out, int out_size, void* d_ws, size_t ws_size,
                              hipStream_t stream) {
    const float* wl_x = (const float*)d_in[0];
    const float* mt_x = (const float*)d_in[1];
    const int* wl_ei = (const int*)d_in[2];
    const int* mt_ei = (const int*)d_in[3];
    const int* wl_batch = (const int*)d_in[4];
    const int* mt_batch = (const int*)d_in[5];
    const float* gin1_W1 = (const float*)d_in[6];
    const float* gin1_b1 = (const float*)d_in[7];
    const float* gin1_W2 = (const float*)d_in[8];
    const float* gin1_b2 = (const float*)d_in[9];
    const float* bn1_g = (const float*)d_in[10];
    const float* bn1_b = (const float*)d_in[11];
    const float* gin2_W1 = (const float*)d_in[12];
    const float* gin2_b1 = (const float*)d_in[13];
    const float* gin2_W2 = (const float*)d_in[14];
    const float* gin2_b2 = (const float*)d_in[15];
    const float* bn2_g = (const float*)d_in[16];
    const float* bn2_b = (const float*)d_in[17];
    const float* gat_W = (const float*)d_in[18];
    const float* gat_as = (const float*)d_in[19];
    const float* gat_ad = (const float*)d_in[20];
    const float* gat_bias = (const float*)d_in[21];
    const float* fc_W1 = (const float*)d_in[22];
    const float* fc_b1 = (const float*)d_in[23];
    const float* fc_bn_g = (const float*)d_in[24];
    const float* fc_bn_b = (const float*)d_in[25];
    const float* fc_W2 = (const float*)d_in[26];
    const float* fc_b2 = (const float*)d_in[27];
    const float* reg_W1 = (const float*)d_in[28];
    const float* reg_b1 = (const float*)d_in[29];
    const float* reg_W2 = (const float*)d_in[30];
    const float* reg_b2 = (const float*)d_in[31];
    float* out = (float*)d_out;

    char* ws = (char*)d_ws;
    size_t o = 0;
    auto alloc = [&](size_t bytes) {
        size_t r = o;
        o = (o + bytes + 255) & ~(size_t)255;
        return r;
    };
    unsigned short* hbA = (unsigned short*)(ws + alloc((size_t)NT * DD * 2)); // 61.4 MB
    unsigned short* hbB = (unsigned short*)(ws + alloc((size_t)NT * DD * 2)); // 61.4 MB
    float* xm = (float*)(ws + alloc((size_t)NT * DIN * 4));
    float* bufA = (float*)(ws + alloc((size_t)NT * DIN * 4));
    int* bm = (int*)(ws + alloc((size_t)NT * 4));
    int* cnt = (int*)(ws + alloc((size_t)NT * 4));
    int* rowptr = (int*)(ws + alloc((size_t)(NT + 1) * 4));
    int* cursor = (int*)(ws + alloc((size_t)NT * 4));
    int* colidx = (int*)(ws + alloc((size_t)2 * E1 * 4));
    float* a_s = (float*)(ws + alloc((size_t)NT * NH * 4));
    float* a_d = (float*)(ws + alloc((size_t)NT * NH * 4));
    float* bnsums = (float*)(ws + alloc(4 * DD * 4));
    float* bnsc = (float*)(ws + alloc(4 * DD * 4));
    float* partial = (float*)(ws + alloc((size_t)NGT * PSPLIT * DD * 4));
    float* pool = (float*)(ws + alloc((size_t)NGT * DD * 4));
    float* fch = (float*)(ws + alloc((size_t)NGT * DD * 4));
    float* gout = (float*)(ws + alloc((size_t)NGT * NHID * 4));
    unsigned short* Wt1 = (unsigned short*)(ws + alloc((size_t)DD * DD * 2));
    unsigned short* Wt2 = (unsigned short*)(ws + alloc((size_t)DD * DD * 2));
    unsigned short* Wt3 = (unsigned short*)(ws + alloc((size_t)DD * DD * 2));
    unsigned short* Wt4 = (unsigned short*)(ws + alloc((size_t)DD * DD * 2));
    (void)ws_size; (void)in_sizes; (void)n_in; (void)out_size;

    // one-time per launch: weights + merged inputs
    k_wconv<<<DD, 256, 0, stream>>>(gin1_W2, Wt1);
    k_wconv<<<DD, 256, 0, stream>>>(gin2_W1, Wt2);
    k_wconv<<<DD, 256, 0, stream>>>(gin2_W2, Wt3);
    k_wconv<<<DD, 256, 0, stream>>>(gat_W, Wt4);
    k_xmerge<<<(NT * DIN + 255) / 256, 256, 0, stream>>>(wl_x, mt_x, xm);
    k_bmerge<<<(NT + 255) / 256, 256, 0, stream>>>(wl_batch, mt_batch, bm);

    // merged CSR (mt node ids offset by N1)
    hipMemsetAsync(cnt, 0, (size_t)NT * 4, stream);
    k_hist2<<<512, 256, 0, stream>>>(wl_ei + E1, mt_ei + E1, cnt);
    k_scan2<<<1, 512, 0, stream>>>(cnt, rowptr, cursor, NT);
    k_scatter2<<<512, 256, 0, stream>>>(wl_ei, wl_ei + E1, mt_ei, mt_ei + E1,
                                        cursor, colidx);

    int gmm = ((NT + 127) / 128) * 4;   // 469 row blocks x 4 col tiles (adjacent)
    dim3 g20((NT + 63) / 64, 4);

    auto bnpass = [&](unsigned short* buf, const float* g, const float* b) {
        hipMemsetAsync(bnsums, 0, 4 * DD * 4, stream);
        k_bn_stats2b<<<256, 256, 0, stream>>>(buf, bnsums);
        k_bn_fin2<<<1, 512, 0, stream>>>(bnsums, g, b, bnsc);
        k_bn_apply_ip<<<2048, 256, 0, stream>>>(buf, bnsc);
    };

    // GIN1
    k_gin1_agg<<<(NT + 3) / 4, 256, 0, stream>>>(xm, rowptr, colidx, bufA);
    k_gemm20<<<g20, 256, 0, stream>>>(bufA, gin1_W1, gin1_b1, hbA);
    k_gemm_mfma<0><<<gmm, 256, 0, stream>>>(hbA, Wt1, gin1_b2, hbB, nullptr,
                                            nullptr, nullptr, nullptr, NT);
    bnpass(hbB, bn1_g, bn1_b);                       // h1 in hbB

    // GIN2
    k_agg512b<<<(NT + 3) / 4, 256, 0, stream>>>(hbB, rowptr, colidx, hbA);
    k_gemm_mfma<1><<<gmm, 256, 0, stream>>>(hbA, Wt2, gin2_b1, hbB, nullptr,
                                            nullptr, nullptr, nullptr, NT);
    k_gemm_mfma<0><<<gmm, 256, 0, stream>>>(hbB, Wt3, gin2_b2, hbA, nullptr,
                                            nullptr, nullptr, nullptr, NT);
    bnpass(hbA, bn2_g, bn2_b);                       // h2 in hbA

    // GAT (features bf16 -> hbB, logits a_s/a_d from fp32 accumulators)
    k_gemm_mfma<2><<<gmm, 256, 0, stream>>>(hbA, Wt4, nullptr, hbB, gat_as,
                                            gat_ad, a_s, a_d, NT);
    k_gat_gather<<<(NT + 3) / 4, 256, 0, stream>>>(hbB, a_s, a_d, rowptr, colidx,
                                                   hbA);
    k_pool1<<<dim3(NGT, PSPLIT), 256, 0, stream>>>(hbA, bm, partial);
    k_pool2<<<NGT, 512, 0, stream>>>(partial, bm, gat_bias, pool);

    // fc head (both branches at once)
    k_fc1<<<NGT, 256, 0, stream>>>(pool, fc_W1, fc_b1, fch);
    k_bn64_2<<<1, 512, 0, stream>>>(fch, fc_bn_g, fc_bn_b);
    k_fc2<<<NGT, 128, 0, stream>>>(fch, fc_W2, fc_b2, gout);

    k_reg<<<NG, 128, 0, stream>>>(gout, reg_W1, reg_b1, reg_W2, reg_b2, out);
}